// Round 1
// 1013.068 us; speedup vs baseline: 1.2558x; 1.2558x over previous
//
#include <hip/hip_runtime.h>
#include <hip/hip_bf16.h>

#define HID 256
#define NSPOT 20000
#define NCITY 2000
#define NWORD 20000

typedef __attribute__((ext_vector_type(8))) short bhalf8;
typedef __attribute__((ext_vector_type(4))) float floatx4;

// ---------------------------------------------------------------------------
// wq[h][i] = sum_o W_att[h][i][o] * q_att[h][o]
__global__ void wq_kernel(const float* __restrict__ W, const float* __restrict__ q,
                          float* __restrict__ wq) {
    int idx = blockIdx.x * 256 + threadIdx.x;   // 4*512 = 2048
    if (idx >= 2048) return;
    int h = idx >> 9, i = idx & 511;
    const float* Wr = W + ((size_t)h * 512 + i) * 128;
    const float* qr = q + h * 128;
    float s = 0.f;
    #pragma unroll 4
    for (int o = 0; o < 128; o++) s += Wr[o] * qr[o];
    wq[idx] = s;
}

// ---------------------------------------------------------------------------
// Per-node attention: scores via wave-reduction (conflict-free LDS), softmax,
// blend -> xbar bf16 [h][n][512].
__global__ __launch_bounds__(256) void attn_kernel(const float* __restrict__ x,
                                                   const float* __restrict__ wq,
                                                   __hip_bfloat16* __restrict__ xbar) {
    __shared__ float xl[2560];
    __shared__ float al[4][8];
    int n = blockIdx.x;
    int tid = threadIdx.x;
    int wave = tid >> 6, lane = tid & 63;
    const float4* xr4 = (const float4*)(x + (size_t)n * 2560);
    for (int i = tid; i < 640; i += 256) ((float4*)xl)[i] = xr4[i];
    __syncthreads();
    // wave w = head w; 5 dot-products of length 512 over 64 lanes
    const float* wqh = wq + wave * 512;
    for (int s = 0; s < 5; s++) {
        float a = 0.f;
        #pragma unroll
        for (int j = 0; j < 8; j++)
            a += xl[s * 512 + lane + j * 64] * wqh[lane + j * 64];
        #pragma unroll
        for (int off = 32; off > 0; off >>= 1) a += __shfl_down(a, off, 64);
        if (lane == 0) al[wave][s] = a;
    }
    __syncthreads();
    if (tid < 4) {
        float z[5]; float m = -1e30f;
        #pragma unroll
        for (int s = 0; s < 5; s++) {
            float v = al[tid][s];
            v = (v >= 0.f) ? v : 0.2f * v;    // leaky_relu 0.2
            z[s] = v; m = fmaxf(m, v);
        }
        float e[5]; float sum = 0.f;
        #pragma unroll
        for (int s = 0; s < 5; s++) { e[s] = __expf(z[s] - m); sum += e[s]; }
        float r = 1.f / sum;
        #pragma unroll
        for (int s = 0; s < 5; s++) al[tid][s] = e[s] * r;
    }
    __syncthreads();
    float a0 = al[wave][0], a1 = al[wave][1], a2 = al[wave][2], a3 = al[wave][3], a4 = al[wave][4];
    __hip_bfloat16* xo = xbar + ((size_t)wave * NSPOT + n) * 512;
    #pragma unroll
    for (int j = 0; j < 8; j++) {
        int i = lane + j * 64;
        float v = a0 * xl[i] + a1 * xl[512 + i] + a2 * xl[1024 + i] + a3 * xl[1536 + i] + a4 * xl[2048 + i];
        xo[i] = __float2bfloat16(v);
    }
}

// ---------------------------------------------------------------------------
// bf16 MFMA GEMM: C[M,N] = A[M,K] @ Bt[N,K]^T.  128x128 tile, 4 waves (64x64
// each as 4x4 of 16x16), K%32==0.  Optional fp32 C and/or bf16 Cb outputs.
// Batched over blockIdx.z via element strides.  (used for attention proj only)
#define KP 40   // padded halfword stride in LDS (80B: 2-way bank aliasing = free)
__global__ __launch_bounds__(256) void gemm_bf16(
    const __hip_bfloat16* __restrict__ A, int lda, long sA,
    const __hip_bfloat16* __restrict__ Bt, int ldb, long sB,
    float* __restrict__ C, int ldc,
    __hip_bfloat16* __restrict__ Cb, int ldcb, long sCb,
    int M, int N, int K) {
    __shared__ short As[128 * KP];
    __shared__ short Bs[128 * KP];
    int z = blockIdx.z;
    A += (size_t)z * sA;
    Bt += (size_t)z * sB;
    if (Cb) Cb += (size_t)z * sCb;
    int tid = threadIdx.x;
    int wave = tid >> 6, lane = tid & 63;
    int wr = wave & 1, wc = wave >> 1;
    int quad = lane >> 4, l16 = lane & 15;
    int rowbase = blockIdx.x * 128;
    int colbase = blockIdx.y * 128;
    int srow = tid >> 2;            // 0..63
    int skoff = (tid & 3) * 8;      // 0,8,16,24
    floatx4 acc[4][4];
    #pragma unroll
    for (int i = 0; i < 4; i++)
        #pragma unroll
        for (int j = 0; j < 4; j++)
            acc[i][j] = (floatx4){0.f, 0.f, 0.f, 0.f};

    for (int k0 = 0; k0 < K; k0 += 32) {
        #pragma unroll
        for (int i = 0; i < 2; i++) {
            int r = srow + i * 64;
            int gr = rowbase + r;
            int4 va = make_int4(0, 0, 0, 0);
            if (gr < M) va = *(const int4*)(A + (size_t)gr * lda + k0 + skoff);
            *(int4*)(As + r * KP + skoff) = va;
            int4 vb = *(const int4*)(Bt + (size_t)(colbase + r) * ldb + k0 + skoff);
            *(int4*)(Bs + r * KP + skoff) = vb;
        }
        __syncthreads();
        bhalf8 af[4], bfr[4];
        #pragma unroll
        for (int rt = 0; rt < 4; rt++)
            af[rt] = *(const bhalf8*)(As + (wr * 64 + rt * 16 + l16) * KP + quad * 8);
        #pragma unroll
        for (int ct = 0; ct < 4; ct++)
            bfr[ct] = *(const bhalf8*)(Bs + (wc * 64 + ct * 16 + l16) * KP + quad * 8);
        #pragma unroll
        for (int rt = 0; rt < 4; rt++)
            #pragma unroll
            for (int ct = 0; ct < 4; ct++)
                acc[rt][ct] = __builtin_amdgcn_mfma_f32_16x16x32_bf16(af[rt], bfr[ct], acc[rt][ct], 0, 0, 0);
        __syncthreads();
    }
    // epilogue: D row = quad*4 + reg, col = lane&15
    #pragma unroll
    for (int rt = 0; rt < 4; rt++) {
        #pragma unroll
        for (int r = 0; r < 4; r++) {
            int grow = rowbase + wr * 64 + rt * 16 + quad * 4 + r;
            if (grow < M) {
                #pragma unroll
                for (int ct = 0; ct < 4; ct++) {
                    int gcol = colbase + wc * 64 + ct * 16 + l16;
                    float v = acc[rt][ct][r];
                    if (C)  C[(size_t)grow * ldc + gcol] = v;
                    if (Cb) Cb[(size_t)grow * ldcb + gcol] = __float2bfloat16(v);
                }
            }
        }
    }
}

// ---------------------------------------------------------------------------
// Grouped GEMM: 8 independent C[M,256] = A[M,K] @ Bt[256,K]^T problems in one
// launch (blockIdx.z = group).  Same inner structure as gemm_bf16; tails of
// small groups overlap with large groups -> no per-launch drain.
struct GemmDesc {
    const __hip_bfloat16* A;
    const __hip_bfloat16* Bt;
    float* C;
    __hip_bfloat16* Cb;
    int lda, ldb, ldc, ldcb, M, K;
};
struct GemmDesc8 { GemmDesc d[8]; };

__global__ __launch_bounds__(256) void gemm_bf16_grouped(GemmDesc8 descs) {
    GemmDesc g = descs.d[blockIdx.z];
    int rowbase = blockIdx.x * 128;
    if (rowbase >= g.M) return;                 // uniform early-exit (before barriers)
    __shared__ short As[128 * KP];
    __shared__ short Bs[128 * KP];
    int tid = threadIdx.x;
    int wave = tid >> 6, lane = tid & 63;
    int wr = wave & 1, wc = wave >> 1;
    int quad = lane >> 4, l16 = lane & 15;
    int colbase = blockIdx.y * 128;             // N fixed = 256 -> y in {0,1}
    int srow = tid >> 2;
    int skoff = (tid & 3) * 8;
    floatx4 acc[4][4];
    #pragma unroll
    for (int i = 0; i < 4; i++)
        #pragma unroll
        for (int j = 0; j < 4; j++)
            acc[i][j] = (floatx4){0.f, 0.f, 0.f, 0.f};

    for (int k0 = 0; k0 < g.K; k0 += 32) {
        #pragma unroll
        for (int i = 0; i < 2; i++) {
            int r = srow + i * 64;
            int gr = rowbase + r;
            int4 va = make_int4(0, 0, 0, 0);
            if (gr < g.M) va = *(const int4*)(g.A + (size_t)gr * g.lda + k0 + skoff);
            *(int4*)(As + r * KP + skoff) = va;
            int4 vb = *(const int4*)(g.Bt + (size_t)(colbase + r) * g.ldb + k0 + skoff);
            *(int4*)(Bs + r * KP + skoff) = vb;
        }
        __syncthreads();
        bhalf8 af[4], bfr[4];
        #pragma unroll
        for (int rt = 0; rt < 4; rt++)
            af[rt] = *(const bhalf8*)(As + (wr * 64 + rt * 16 + l16) * KP + quad * 8);
        #pragma unroll
        for (int ct = 0; ct < 4; ct++)
            bfr[ct] = *(const bhalf8*)(Bs + (wc * 64 + ct * 16 + l16) * KP + quad * 8);
        #pragma unroll
        for (int rt = 0; rt < 4; rt++)
            #pragma unroll
            for (int ct = 0; ct < 4; ct++)
                acc[rt][ct] = __builtin_amdgcn_mfma_f32_16x16x32_bf16(af[rt], bfr[ct], acc[rt][ct], 0, 0, 0);
        __syncthreads();
    }
    #pragma unroll
    for (int rt = 0; rt < 4; rt++) {
        #pragma unroll
        for (int r = 0; r < 4; r++) {
            int grow = rowbase + wr * 64 + rt * 16 + quad * 4 + r;
            if (grow < g.M) {
                #pragma unroll
                for (int ct = 0; ct < 4; ct++) {
                    int gcol = colbase + wc * 64 + ct * 16 + l16;
                    float v = acc[rt][ct][r];
                    if (g.C)  g.C[(size_t)grow * g.ldc + gcol] = v;
                    if (g.Cb) g.Cb[(size_t)grow * g.ldcb + gcol] = __float2bfloat16(v);
                }
            }
        }
    }
}

// ---------------------------------------------------------------------------
// Batched transpose-cast: in fp32 [K][N] -> out bf16 [N][Kp], zero-pad K..Kp.
struct TDesc { const float* in; __hip_bfloat16* out; int K; int N; int Kp; };
struct TDesc8 { TDesc d[8]; };
__global__ void transpose_cast_kernel(TDesc8 descs) {
    TDesc dsc = descs.d[blockIdx.z];
    __shared__ float tile[32][33];
    int k0 = blockIdx.x * 32, n0 = blockIdx.y * 32;
    if (k0 >= dsc.Kp || n0 >= dsc.N) return;
    int tn = threadIdx.x & 31, t8 = threadIdx.x >> 5;
    #pragma unroll
    for (int i = 0; i < 4; i++) {
        int k = k0 + t8 * 4 + i;
        float v = 0.f;
        if (k < dsc.K && n0 + tn < dsc.N) v = dsc.in[(size_t)k * dsc.N + n0 + tn];
        tile[t8 * 4 + i][tn] = v;
    }
    __syncthreads();
    int kk = threadIdx.x & 31, n8 = threadIdx.x >> 5;
    #pragma unroll
    for (int i = 0; i < 4; i++) {
        int n = n0 + n8 * 4 + i;
        int k = k0 + kk;
        if (n < dsc.N && k < dsc.Kp)
            dsc.out[(size_t)n * dsc.Kp + k] = __float2bfloat16(tile[kk][n8 * 4 + i]);
    }
}

// cast fp32 -> bf16 (flat)
__global__ void cast_kernel(const float* __restrict__ in, __hip_bfloat16* __restrict__ out, int n) {
    int i = blockIdx.x * 256 + threadIdx.x;
    if (i < n) out[i] = __float2bfloat16(in[i]);
}

// cast fp32 [rows][K] -> bf16 [rows][Kp] zero-padded
__global__ void cast_pad_kernel(const float* __restrict__ in, __hip_bfloat16* __restrict__ out,
                                int rows, int K, int Kp) {
    int idx = blockIdx.x * 256 + threadIdx.x;
    if (idx >= rows * Kp) return;
    int r = idx / Kp, k = idx - r * Kp;
    out[idx] = (k < K) ? __float2bfloat16(in[(size_t)r * K + k]) : __float2bfloat16(0.f);
}

// ---------------------------------------------------------------------------
// Fused CSR build for all 4 edge types: histogram -> scan(+cursor) -> fill
struct EdgeDesc { const int* src; const int* tgt; int E; int n;
                  int* deg; int* rp; int* cur; int* cs; };
struct EdgeDesc4 { EdgeDesc d[4]; };

__global__ void hist4_kernel(EdgeDesc4 ds) {
    EdgeDesc d = ds.d[blockIdx.y];
    int e = blockIdx.x * 256 + threadIdx.x;
    if (e < d.E) atomicAdd(&d.deg[d.tgt[e]], 1);
}

__global__ void scan4_kernel(EdgeDesc4 ds) {
    EdgeDesc dd = ds.d[blockIdx.x];
    __shared__ int partx[257];
    __shared__ int part[256];
    int tid = threadIdx.x;
    int n = dd.n;
    int chunk = (n + 255) / 256;
    int lo = tid * chunk;
    int hi = lo + chunk; if (hi > n) hi = n;
    int s = 0;
    for (int i = lo; i < hi; i++) s += dd.deg[i];
    part[tid] = s;
    __syncthreads();
    if (tid == 0) {
        int acc = 0;
        for (int i = 0; i < 256; i++) { partx[i] = acc; acc += part[i]; }
        partx[256] = acc;
    }
    __syncthreads();
    int acc = partx[tid];
    for (int i = lo; i < hi; i++) { dd.rp[i] = acc; dd.cur[i] = acc; acc += dd.deg[i]; }
    if (tid == 0) dd.rp[n] = partx[256];
}

__global__ void fill4_kernel(EdgeDesc4 ds) {
    EdgeDesc d = ds.d[blockIdx.y];
    int e = blockIdx.x * 256 + threadIdx.x;
    if (e >= d.E) return;
    int t = d.tgt[e];
    int pos = atomicAdd(&d.cur[t], 1);
    d.cs[pos] = d.src[e];
}

// ---------------------------------------------------------------------------
// Fused segmented mean over bf16 messages (4 edge types in one launch):
// one block per target row, thread d = dim d.
struct AggDesc { const __hip_bfloat16* msg; const int* rp; const int* cs; float* outm; };
struct AggDesc4 { AggDesc d[4]; int start1, start2, start3; };

__global__ __launch_bounds__(256) void agg4_kernel(AggDesc4 ds) {
    int bid = blockIdx.x;
    int gi = (bid >= ds.start1) + (bid >= ds.start2) + (bid >= ds.start3);
    int base = (gi == 0) ? 0 : (gi == 1) ? ds.start1 : (gi == 2) ? ds.start2 : ds.start3;
    AggDesc g = ds.d[gi];
    int t = bid - base;
    int d = threadIdx.x;
    int lo = g.rp[t], hi = g.rp[t + 1];
    float acc = 0.f;
    int i = lo;
    for (; i + 4 <= hi; i += 4) {
        int s0 = g.cs[i], s1 = g.cs[i + 1], s2 = g.cs[i + 2], s3 = g.cs[i + 3];
        float m0 = __bfloat162float(g.msg[(size_t)s0 * HID + d]);
        float m1 = __bfloat162float(g.msg[(size_t)s1 * HID + d]);
        float m2 = __bfloat162float(g.msg[(size_t)s2 * HID + d]);
        float m3 = __bfloat162float(g.msg[(size_t)s3 * HID + d]);
        acc += m0 + m1 + m2 + m3;
    }
    for (; i < hi; i++) acc += __bfloat162float(g.msg[(size_t)g.cs[i] * HID + d]);
    g.outm[(size_t)t * HID + d] = acc / fmaxf((float)(hi - lo), 1.f);
}

// ---------------------------------------------------------------------------
// Fused combine for all three node types.  NOTE: no __restrict__ — in layer 2
// the outputs alias the mean inputs (same-index elementwise, in-place safe).
__global__ void combine_all(const float* Sa, const float* Sb, const float* mH, const float* mD,
                            float* so, __hip_bfloat16* sob,
                            const float* Sc, const float* mI, float* co, __hip_bfloat16* cob,
                            const float* Sw, const float* mR, float* wo, __hip_bfloat16* wob) {
    int bid = blockIdx.x;
    int tid = threadIdx.x;
    if (bid < NSPOT) {
        int idx = bid * 256 + tid;
        float v = fmaxf((Sa[idx] + Sb[idx] + mH[idx] + mD[idx]) * 0.5f, 0.f);
        so[idx] = v;
        if (sob) sob[idx] = __float2bfloat16(v);
    } else if (bid < NSPOT + NCITY) {
        int idx = (bid - NSPOT) * 256 + tid;
        float v = fmaxf(Sc[idx] + mI[idx], 0.f);
        co[idx] = v;
        if (cob) cob[idx] = __float2bfloat16(v);
    } else {
        int idx = (bid - NSPOT - NCITY) * 256 + tid;
        float v = fmaxf(Sw[idx] + mR[idx], 0.f);
        wo[idx] = v;
        if (wob) wob[idx] = __float2bfloat16(v);
    }
}

// ---------------------------------------------------------------------------
// Fused (a+b)/2 for the three node types (float4 granularity).
__global__ void mean3_kernel(const float* a0, const float* b0, float* o0, int n0,
                             const float* a1, const float* b1, float* o1, int n1,
                             const float* a2, const float* b2, float* o2, int n2) {
    int i = blockIdx.x * 256 + threadIdx.x;
    const float* a; const float* b; float* o;
    if (i < n0) { a = a0; b = b0; o = o0; }
    else if (i < n0 + n1) { a = a1; b = b1; o = o1; i -= n0; }
    else if (i < n0 + n1 + n2) { a = a2; b = b2; o = o2; i -= n0 + n1; }
    else return;
    float4 x = reinterpret_cast<const float4*>(a)[i];
    float4 y = reinterpret_cast<const float4*>(b)[i];
    reinterpret_cast<float4*>(o)[i] =
        make_float4((x.x + y.x) * 0.5f, (x.y + y.y) * 0.5f, (x.z + y.z) * 0.5f, (x.w + y.w) * 0.5f);
}

// Fused row-dot heads for the three node types.  4 rows per block (wave each).
__global__ void rowdot3_kernel(const float* X0, const float* w0, const float* b0, float* o0, int B0,
                               const float* X1, const float* w1, const float* b1, float* o1, int B1,
                               const float* X2, const float* w2, const float* b2, float* o2, int B2) {
    int bid = blockIdx.x;
    const float* X; const float* w; const float* b; float* o; int M;
    if (bid < B0) { X = X0; w = w0; b = b0; o = o0; M = B0 * 4; }
    else if (bid < B0 + B1) { X = X1; w = w1; b = b1; o = o1; M = B1 * 4; bid -= B0; }
    else { X = X2; w = w2; b = b2; o = o2; M = B2 * 4; bid -= B0 + B1; }
    int row = bid * 4 + (threadIdx.x >> 6);
    if (row >= M) return;
    int lane = threadIdx.x & 63;
    const float* x = X + (size_t)row * HID;
    float s = 0.f;
    #pragma unroll
    for (int j = 0; j < 4; j++) s += x[lane + j * 64] * w[lane + j * 64];
    #pragma unroll
    for (int off = 32; off > 0; off >>= 1) s += __shfl_down(s, off, 64);
    if (lane == 0) o[row] = s + b[0];
}

// ---------------------------------------------------------------------------
extern "C" void kernel_launch(void* const* d_in, const int* in_sizes, int n_in,
                              void* d_out, int out_size, void* d_ws, size_t ws_size,
                              hipStream_t stream) {
    const float* x_spot   = (const float*)d_in[0];
    const float* x_city   = (const float*)d_in[1];
    const float* x_word   = (const float*)d_in[2];
    const float* W_att    = (const float*)d_in[3];
    const float* q_att    = (const float*)d_in[4];
    const float* w1[8] = { (const float*)d_in[5], (const float*)d_in[6], (const float*)d_in[7],
                           (const float*)d_in[8], (const float*)d_in[9], (const float*)d_in[10],
                           (const float*)d_in[11], (const float*)d_in[12] };
    const float* w2[8] = { (const float*)d_in[13], (const float*)d_in[14], (const float*)d_in[15],
                           (const float*)d_in[16], (const float*)d_in[17], (const float*)d_in[18],
                           (const float*)d_in[19], (const float*)d_in[20] };
    const float* wl_spot = (const float*)d_in[21];
    const float* wl_city = (const float*)d_in[22];
    const float* wl_word = (const float*)d_in[23];
    const float* bl_spot = (const float*)d_in[24];
    const float* bl_city = (const float*)d_in[25];
    const float* bl_word = (const float*)d_in[26];
    const int* e_has_src   = (const int*)d_in[27];
    const int* e_has_tgt   = (const int*)d_in[28];
    const int* e_in_src    = (const int*)d_in[29];
    const int* e_in_tgt    = (const int*)d_in[30];
    const int* e_desc_src  = (const int*)d_in[31];
    const int* e_desc_tgt  = (const int*)d_in[32];
    const int* e_rdesc_src = (const int*)d_in[33];
    const int* e_rdesc_tgt = (const int*)d_in[34];
    const int E_has   = in_sizes[27];
    const int E_in    = in_sizes[29];
    const int E_desc  = in_sizes[31];
    const int E_rdesc = in_sizes[33];

    float* out = (float*)d_out;
    float* wsf = (float*)d_ws;
    typedef __hip_bfloat16 bf;

    // ---- workspace layout (units of float; bf16 arrays use half) ----
    size_t o = 0;
    auto alloc = [&](size_t nfloats) { float* p = wsf + o; o += (nfloats + 15) & ~(size_t)15; return p; };
    float* wqb       = alloc(2048);
    bf* xs_bf        = (bf*)alloc((size_t)NSPOT * 512 / 2);
    bf* x_city_bf    = (bf*)alloc((size_t)NCITY * 128 / 2);
    bf* x_word_bf    = (bf*)alloc((size_t)NWORD * 320 / 2);
    bf* Wt_att       = (bf*)alloc((size_t)4 * 128 * 512 / 2);
    // L1 transposed weights: [N=256][Kp]
    int K1[8]  = {128, 512, 512, 128, 300, 512, 512, 300};
    int Kp1[8] = {128, 512, 512, 128, 320, 512, 512, 320};
    bf* Wt1[8];
    for (int i = 0; i < 8; i++) Wt1[i] = (bf*)alloc((size_t)256 * Kp1[i] / 2);
    bf* Wt2[8];
    for (int i = 0; i < 8; i++) Wt2[i] = (bf*)alloc((size_t)256 * 256 / 2);
    float* Sa = alloc((size_t)NSPOT * HID);
    float* Sb = alloc((size_t)NSPOT * HID);
    float* Sc = alloc((size_t)NCITY * HID);
    float* Sw = alloc((size_t)NWORD * HID);
    float* m_has   = alloc((size_t)NSPOT * HID);   // layer-2: also s2 (element-wise in-place safe)
    float* m_desc  = alloc((size_t)NSPOT * HID);
    float* m_in    = alloc((size_t)NCITY * HID);   // also c2
    float* m_rdesc = alloc((size_t)NWORD * HID);   // also wd2
    float* s1  = alloc((size_t)NSPOT * HID);
    float* c1  = alloc((size_t)NCITY * HID);
    float* wd1 = alloc((size_t)NWORD * HID);
    // region X: xbar (attention, dead after projection GEMMs) hosts P_* and s1b trio
    size_t regX = o;
    bf* xbar_bf = (bf*)(wsf + regX);                         // 4*NSPOT*512 bf16 = 20.48M floats
    size_t ox = regX;
    auto allocX = [&](size_t nfloats) { float* p = wsf + ox; ox += (nfloats + 15) & ~(size_t)15; return p; };
    bf* P_has_bf   = (bf*)allocX((size_t)NCITY * HID / 2);
    bf* P_in_bf    = (bf*)allocX((size_t)NSPOT * HID / 2);
    bf* P_desc_bf  = (bf*)allocX((size_t)NWORD * HID / 2);
    bf* P_rdesc_bf = (bf*)allocX((size_t)NSPOT * HID / 2);
    bf* s1b = (bf*)allocX((size_t)NSPOT * HID / 2);
    bf* c1b = (bf*)allocX((size_t)NCITY * HID / 2);
    bf* wd1b = (bf*)allocX((size_t)NWORD * HID / 2);
    o = regX + (size_t)4 * NSPOT * 512 / 2;                  // past xbar end (covers allocX region)
    float* s2  = m_has;
    float* c2  = m_in;
    float* wd2 = m_rdesc;
    // CSR ints
    int* wsi = (int*)(wsf + o);
    size_t io = 0;
    int* deg_has    = wsi + io; io += NSPOT;
    int* deg_desc   = wsi + io; io += NSPOT;
    int* deg_in     = wsi + io; io += NCITY;
    int* deg_rdesc  = wsi + io; io += NWORD;
    size_t deg_bytes = io * sizeof(int);
    int* rp_has     = wsi + io; io += NSPOT + 1;
    int* rp_desc    = wsi + io; io += NSPOT + 1;
    int* rp_in      = wsi + io; io += NCITY + 1;
    int* rp_rdesc   = wsi + io; io += NWORD + 1;
    int* cur_has    = wsi + io; io += NSPOT + 1;
    int* cur_desc   = wsi + io; io += NSPOT + 1;
    int* cur_in     = wsi + io; io += NCITY + 1;
    int* cur_rdesc  = wsi + io; io += NWORD + 1;
    int* cs_has     = wsi + io; io += E_has;
    int* cs_desc    = wsi + io; io += E_desc;
    int* cs_in      = wsi + io; io += E_in;
    int* cs_rdesc   = wsi + io; io += E_rdesc;
    (void)ws_size; (void)n_in; (void)out_size;

    // ---- weight transpose-casts + input casts ----
    {
        TDesc8 t{};
        for (int i = 0; i < 4; i++)
            t.d[i] = TDesc{ W_att + (size_t)i * 512 * 128, Wt_att + (size_t)i * 128 * 512, 512, 128, 512 };
        hipLaunchKernelGGL(transpose_cast_kernel, dim3(16, 4, 4), dim3(256), 0, stream, t);
    }
    {
        TDesc8 t{};
        for (int i = 0; i < 8; i++) t.d[i] = TDesc{ w1[i], Wt1[i], K1[i], 256, Kp1[i] };
        hipLaunchKernelGGL(transpose_cast_kernel, dim3(16, 8, 8), dim3(256), 0, stream, t);
    }
    {
        TDesc8 t{};
        for (int i = 0; i < 8; i++) t.d[i] = TDesc{ w2[i], Wt2[i], 256, 256, 256 };
        hipLaunchKernelGGL(transpose_cast_kernel, dim3(8, 8, 8), dim3(256), 0, stream, t);
    }
    hipLaunchKernelGGL(cast_kernel, dim3((NCITY * 128 + 255) / 256), dim3(256), 0, stream,
                       x_city, x_city_bf, NCITY * 128);
    hipLaunchKernelGGL(cast_pad_kernel, dim3((NWORD * 320 + 255) / 256), dim3(256), 0, stream,
                       x_word, x_word_bf, NWORD, 300, 320);

    // ---- fused CSR build (reused by both layers) ----
    EdgeDesc4 ed;
    ed.d[0] = EdgeDesc{ e_has_src,   e_has_tgt,   E_has,   NSPOT, deg_has,   rp_has,   cur_has,   cs_has };
    ed.d[1] = EdgeDesc{ e_desc_src,  e_desc_tgt,  E_desc,  NSPOT, deg_desc,  rp_desc,  cur_desc,  cs_desc };
    ed.d[2] = EdgeDesc{ e_in_src,    e_in_tgt,    E_in,    NCITY, deg_in,    rp_in,    cur_in,    cs_in };
    ed.d[3] = EdgeDesc{ e_rdesc_src, e_rdesc_tgt, E_rdesc, NWORD, deg_rdesc, rp_rdesc, cur_rdesc, cs_rdesc };
    int Emax = E_has;
    if (E_desc > Emax) Emax = E_desc;
    if (E_in > Emax) Emax = E_in;
    if (E_rdesc > Emax) Emax = E_rdesc;
    hipMemsetAsync((void*)deg_has, 0, deg_bytes, stream);
    hipLaunchKernelGGL(hist4_kernel, dim3((Emax + 255) / 256, 4), dim3(256), 0, stream, ed);
    hipLaunchKernelGGL(scan4_kernel, dim3(4), dim3(256), 0, stream, ed);
    hipLaunchKernelGGL(fill4_kernel, dim3((Emax + 255) / 256, 4), dim3(256), 0, stream, ed);

    // ---- attention ----
    hipLaunchKernelGGL(wq_kernel, dim3(8), dim3(256), 0, stream, W_att, q_att, wqb);
    hipLaunchKernelGGL(attn_kernel, dim3(NSPOT), dim3(256), 0, stream, x_spot, wqb, xbar_bf);
    // projection: 4 heads batched; xs[n][h*128..] = xbar[h] @ W_att[h]
    {
        dim3 g((NSPOT + 127) / 128, 1, 4);
        hipLaunchKernelGGL(gemm_bf16, g, dim3(256), 0, stream,
                           xbar_bf, 512, (long)NSPOT * 512, Wt_att, 512, (long)128 * 512,
                           nullptr, 0, xs_bf, 512, 128, NSPOT, 128, 512);
    }

    int gx = (NSPOT + 127) / 128;   // 157 row-blocks covers the largest group

    // ---- layer 1 GEMMs (one grouped launch) ----
    {
        GemmDesc8 gd;
        gd.d[0] = GemmDesc{ x_city_bf, Wt1[0], nullptr, P_has_bf,   128, 128, 0, HID, NCITY, 128 };
        gd.d[1] = GemmDesc{ xs_bf,     Wt1[1], Sa,      nullptr,    512, 512, HID, 0, NSPOT, 512 };
        gd.d[2] = GemmDesc{ xs_bf,     Wt1[2], nullptr, P_in_bf,    512, 512, 0, HID, NSPOT, 512 };
        gd.d[3] = GemmDesc{ x_city_bf, Wt1[3], Sc,      nullptr,    128, 128, HID, 0, NCITY, 128 };
        gd.d[4] = GemmDesc{ x_word_bf, Wt1[4], nullptr, P_desc_bf,  320, 320, 0, HID, NWORD, 320 };
        gd.d[5] = GemmDesc{ xs_bf,     Wt1[5], Sb,      nullptr,    512, 512, HID, 0, NSPOT, 512 };
        gd.d[6] = GemmDesc{ xs_bf,     Wt1[6], nullptr, P_rdesc_bf, 512, 512, 0, HID, NSPOT, 512 };
        gd.d[7] = GemmDesc{ x_word_bf, Wt1[7], Sw,      nullptr,    320, 320, HID, 0, NWORD, 320 };
        hipLaunchKernelGGL(gemm_bf16_grouped, dim3(gx, 2, 8), dim3(256), 0, stream, gd);
    }

    // ---- layer 1 aggregation + combine ----
    AggDesc4 ag;
    ag.start1 = NSPOT; ag.start2 = 2 * NSPOT; ag.start3 = 2 * NSPOT + NCITY;
    int agg_blocks = 2 * NSPOT + NCITY + NWORD;
    ag.d[0] = AggDesc{ P_has_bf,   rp_has,   cs_has,   m_has };
    ag.d[1] = AggDesc{ P_desc_bf,  rp_desc,  cs_desc,  m_desc };
    ag.d[2] = AggDesc{ P_in_bf,    rp_in,    cs_in,    m_in };
    ag.d[3] = AggDesc{ P_rdesc_bf, rp_rdesc, cs_rdesc, m_rdesc };
    hipLaunchKernelGGL(agg4_kernel, dim3(agg_blocks), dim3(256), 0, stream, ag);
    hipLaunchKernelGGL(combine_all, dim3(NSPOT + NCITY + NWORD), dim3(256), 0, stream,
                       Sa, Sb, m_has, m_desc, s1, s1b,
                       Sc, m_in, c1, c1b,
                       Sw, m_rdesc, wd1, wd1b);

    // ---- layer 2 GEMMs (one grouped launch) ----
    {
        GemmDesc8 gd;
        gd.d[0] = GemmDesc{ c1b,  Wt2[0], nullptr, P_has_bf,   HID, HID, 0, HID, NCITY, HID };
        gd.d[1] = GemmDesc{ s1b,  Wt2[1], Sa,      nullptr,    HID, HID, HID, 0, NSPOT, HID };
        gd.d[2] = GemmDesc{ s1b,  Wt2[2], nullptr, P_in_bf,    HID, HID, 0, HID, NSPOT, HID };
        gd.d[3] = GemmDesc{ c1b,  Wt2[3], Sc,      nullptr,    HID, HID, HID, 0, NCITY, HID };
        gd.d[4] = GemmDesc{ wd1b, Wt2[4], nullptr, P_desc_bf,  HID, HID, 0, HID, NWORD, HID };
        gd.d[5] = GemmDesc{ s1b,  Wt2[5], Sb,      nullptr,    HID, HID, HID, 0, NSPOT, HID };
        gd.d[6] = GemmDesc{ s1b,  Wt2[6], nullptr, P_rdesc_bf, HID, HID, 0, HID, NSPOT, HID };
        gd.d[7] = GemmDesc{ wd1b, Wt2[7], Sw,      nullptr,    HID, HID, HID, 0, NWORD, HID };
        hipLaunchKernelGGL(gemm_bf16_grouped, dim3(gx, 2, 8), dim3(256), 0, stream, gd);
    }

    // ---- layer 2 aggregation + combine (s2/c2/wd2 alias m_has/m_in/m_rdesc) ----
    hipLaunchKernelGGL(agg4_kernel, dim3(agg_blocks), dim3(256), 0, stream, ag);
    hipLaunchKernelGGL(combine_all, dim3(NSPOT + NCITY + NWORD), dim3(256), 0, stream,
                       Sa, Sb, m_has, m_desc, s2, (bf*)nullptr,
                       Sc, m_in, c2, (bf*)nullptr,
                       Sw, m_rdesc, wd2, (bf*)nullptr);

    // ---- outputs ----
    float* out0 = out;
    float* out1 = out + (size_t)NSPOT * HID;
    float* out2 = out1 + (size_t)NCITY * HID;
    float* out3 = out2 + (size_t)NWORD * HID;
    float* out4 = out3 + NSPOT;
    float* out5 = out4 + NCITY;
    int n4s = NSPOT * HID / 4, n4c = NCITY * HID / 4, n4w = NWORD * HID / 4;
    int n4tot = n4s + n4c + n4w;
    hipLaunchKernelGGL(mean3_kernel, dim3((n4tot + 255) / 256), dim3(256), 0, stream,
                       s1, s2, out0, n4s, c1, c2, out1, n4c, wd1, wd2, out2, n4w);
    hipLaunchKernelGGL(rowdot3_kernel, dim3(NSPOT / 4 + NCITY / 4 + NWORD / 4), dim3(256), 0, stream,
                       s2, wl_spot, bl_spot, out3, NSPOT / 4,
                       c2, wl_city, bl_city, out4, NCITY / 4,
                       wd2, wl_word, bl_word, out5, NWORD / 4);
}

// Round 2
// 960.769 us; speedup vs baseline: 1.3242x; 1.0544x over previous
//
#include <hip/hip_runtime.h>
#include <hip/hip_bf16.h>

#define HID 256
#define NSPOT 20000
#define NCITY 2000
#define NWORD 20000

typedef __attribute__((ext_vector_type(8))) short bhalf8;
typedef __attribute__((ext_vector_type(4))) float floatx4;

__device__ inline float bf2f(unsigned short u) {
    union { unsigned int i; float f; } v; v.i = (unsigned int)u << 16; return v.f;
}
__device__ inline unsigned short f2bf(float f) {
    __hip_bfloat16 b = __float2bfloat16(f);
    return *reinterpret_cast<unsigned short*>(&b);
}
__device__ inline float4 ld4(const float* p, size_t off) {
    return *reinterpret_cast<const float4*>(p + off);
}

// ---------------------------------------------------------------------------
// wq[h][i] = sum_o W_att[h][i][o] * q_att[h][o]
__global__ void wq_kernel(const float* __restrict__ W, const float* __restrict__ q,
                          float* __restrict__ wq) {
    int idx = blockIdx.x * 256 + threadIdx.x;   // 4*512 = 2048
    if (idx >= 2048) return;
    int h = idx >> 9, i = idx & 511;
    const float* Wr = W + ((size_t)h * 512 + i) * 128;
    const float* qr = q + h * 128;
    float s = 0.f;
    #pragma unroll 4
    for (int o = 0; o < 128; o++) s += Wr[o] * qr[o];
    wq[idx] = s;
}

// ---------------------------------------------------------------------------
// Per-node attention: scores via wave-reduction (conflict-free LDS), softmax,
// blend -> xbar bf16 [h][n][512].
__global__ __launch_bounds__(256) void attn_kernel(const float* __restrict__ x,
                                                   const float* __restrict__ wq,
                                                   __hip_bfloat16* __restrict__ xbar) {
    __shared__ float xl[2560];
    __shared__ float al[4][8];
    int n = blockIdx.x;
    int tid = threadIdx.x;
    int wave = tid >> 6, lane = tid & 63;
    const float4* xr4 = (const float4*)(x + (size_t)n * 2560);
    for (int i = tid; i < 640; i += 256) ((float4*)xl)[i] = xr4[i];
    __syncthreads();
    // wave w = head w; 5 dot-products of length 512 over 64 lanes
    const float* wqh = wq + wave * 512;
    for (int s = 0; s < 5; s++) {
        float a = 0.f;
        #pragma unroll
        for (int j = 0; j < 8; j++)
            a += xl[s * 512 + lane + j * 64] * wqh[lane + j * 64];
        #pragma unroll
        for (int off = 32; off > 0; off >>= 1) a += __shfl_down(a, off, 64);
        if (lane == 0) al[wave][s] = a;
    }
    __syncthreads();
    if (tid < 4) {
        float z[5]; float m = -1e30f;
        #pragma unroll
        for (int s = 0; s < 5; s++) {
            float v = al[tid][s];
            v = (v >= 0.f) ? v : 0.2f * v;    // leaky_relu 0.2
            z[s] = v; m = fmaxf(m, v);
        }
        float e[5]; float sum = 0.f;
        #pragma unroll
        for (int s = 0; s < 5; s++) { e[s] = __expf(z[s] - m); sum += e[s]; }
        float r = 1.f / sum;
        #pragma unroll
        for (int s = 0; s < 5; s++) al[tid][s] = e[s] * r;
    }
    __syncthreads();
    float a0 = al[wave][0], a1 = al[wave][1], a2 = al[wave][2], a3 = al[wave][3], a4 = al[wave][4];
    __hip_bfloat16* xo = xbar + ((size_t)wave * NSPOT + n) * 512;
    #pragma unroll
    for (int j = 0; j < 8; j++) {
        int i = lane + j * 64;
        float v = a0 * xl[i] + a1 * xl[512 + i] + a2 * xl[1024 + i] + a3 * xl[1536 + i] + a4 * xl[2048 + i];
        xo[i] = __float2bfloat16(v);
    }
}

// ---------------------------------------------------------------------------
// bf16 MFMA GEMM: C[M,N] = A[M,K] @ Bt[N,K]^T.  128x128 tile, 4 waves (64x64
// each as 4x4 of 16x16), K%32==0.  Batched over blockIdx.z via element strides.
// (used for attention projection only)
#define KP 40   // padded halfword stride in LDS (80B: 2-way bank aliasing = free)
__global__ __launch_bounds__(256) void gemm_bf16(
    const __hip_bfloat16* __restrict__ A, int lda, long sA,
    const __hip_bfloat16* __restrict__ Bt, int ldb, long sB,
    float* __restrict__ C, int ldc,
    __hip_bfloat16* __restrict__ Cb, int ldcb, long sCb,
    int M, int N, int K) {
    __shared__ short As[128 * KP];
    __shared__ short Bs[128 * KP];
    int z = blockIdx.z;
    A += (size_t)z * sA;
    Bt += (size_t)z * sB;
    if (Cb) Cb += (size_t)z * sCb;
    int tid = threadIdx.x;
    int wave = tid >> 6, lane = tid & 63;
    int wr = wave & 1, wc = wave >> 1;
    int quad = lane >> 4, l16 = lane & 15;
    int rowbase = blockIdx.x * 128;
    int colbase = blockIdx.y * 128;
    int srow = tid >> 2;            // 0..63
    int skoff = (tid & 3) * 8;      // 0,8,16,24
    floatx4 acc[4][4];
    #pragma unroll
    for (int i = 0; i < 4; i++)
        #pragma unroll
        for (int j = 0; j < 4; j++)
            acc[i][j] = (floatx4){0.f, 0.f, 0.f, 0.f};

    for (int k0 = 0; k0 < K; k0 += 32) {
        #pragma unroll
        for (int i = 0; i < 2; i++) {
            int r = srow + i * 64;
            int gr = rowbase + r;
            int4 va = make_int4(0, 0, 0, 0);
            if (gr < M) va = *(const int4*)(A + (size_t)gr * lda + k0 + skoff);
            *(int4*)(As + r * KP + skoff) = va;
            int4 vb = *(const int4*)(Bt + (size_t)(colbase + r) * ldb + k0 + skoff);
            *(int4*)(Bs + r * KP + skoff) = vb;
        }
        __syncthreads();
        bhalf8 af[4], bfr[4];
        #pragma unroll
        for (int rt = 0; rt < 4; rt++)
            af[rt] = *(const bhalf8*)(As + (wr * 64 + rt * 16 + l16) * KP + quad * 8);
        #pragma unroll
        for (int ct = 0; ct < 4; ct++)
            bfr[ct] = *(const bhalf8*)(Bs + (wc * 64 + ct * 16 + l16) * KP + quad * 8);
        #pragma unroll
        for (int rt = 0; rt < 4; rt++)
            #pragma unroll
            for (int ct = 0; ct < 4; ct++)
                acc[rt][ct] = __builtin_amdgcn_mfma_f32_16x16x32_bf16(af[rt], bfr[ct], acc[rt][ct], 0, 0, 0);
        __syncthreads();
    }
    #pragma unroll
    for (int rt = 0; rt < 4; rt++) {
        #pragma unroll
        for (int r = 0; r < 4; r++) {
            int grow = rowbase + wr * 64 + rt * 16 + quad * 4 + r;
            if (grow < M) {
                #pragma unroll
                for (int ct = 0; ct < 4; ct++) {
                    int gcol = colbase + wc * 64 + ct * 16 + l16;
                    float v = acc[rt][ct][r];
                    if (C)  C[(size_t)grow * ldc + gcol] = v;
                    if (Cb) Cb[(size_t)grow * ldcb + gcol] = __float2bfloat16(v);
                }
            }
        }
    }
}

// ---------------------------------------------------------------------------
// Grouped GEMM: 8 independent C[M,256] = A[M,K] @ Bt[256,K]^T problems in one
// launch (blockIdx.z = group).  Tails of small groups overlap with large ones.
struct GemmDesc {
    const __hip_bfloat16* A;
    const __hip_bfloat16* Bt;
    float* C;
    __hip_bfloat16* Cb;
    int lda, ldb, ldc, ldcb, M, K;
};
struct GemmDesc8 { GemmDesc d[8]; };

__global__ __launch_bounds__(256) void gemm_bf16_grouped(GemmDesc8 descs) {
    GemmDesc g = descs.d[blockIdx.z];
    int rowbase = blockIdx.x * 128;
    if (rowbase >= g.M) return;                 // uniform early-exit (before barriers)
    __shared__ short As[128 * KP];
    __shared__ short Bs[128 * KP];
    int tid = threadIdx.x;
    int wave = tid >> 6, lane = tid & 63;
    int wr = wave & 1, wc = wave >> 1;
    int quad = lane >> 4, l16 = lane & 15;
    int colbase = blockIdx.y * 128;             // N fixed = 256 -> y in {0,1}
    int srow = tid >> 2;
    int skoff = (tid & 3) * 8;
    floatx4 acc[4][4];
    #pragma unroll
    for (int i = 0; i < 4; i++)
        #pragma unroll
        for (int j = 0; j < 4; j++)
            acc[i][j] = (floatx4){0.f, 0.f, 0.f, 0.f};

    for (int k0 = 0; k0 < g.K; k0 += 32) {
        #pragma unroll
        for (int i = 0; i < 2; i++) {
            int r = srow + i * 64;
            int gr = rowbase + r;
            int4 va = make_int4(0, 0, 0, 0);
            if (gr < g.M) va = *(const int4*)(g.A + (size_t)gr * g.lda + k0 + skoff);
            *(int4*)(As + r * KP + skoff) = va;
            int4 vb = *(const int4*)(g.Bt + (size_t)(colbase + r) * g.ldb + k0 + skoff);
            *(int4*)(Bs + r * KP + skoff) = vb;
        }
        __syncthreads();
        bhalf8 af[4], bfr[4];
        #pragma unroll
        for (int rt = 0; rt < 4; rt++)
            af[rt] = *(const bhalf8*)(As + (wr * 64 + rt * 16 + l16) * KP + quad * 8);
        #pragma unroll
        for (int ct = 0; ct < 4; ct++)
            bfr[ct] = *(const bhalf8*)(Bs + (wc * 64 + ct * 16 + l16) * KP + quad * 8);
        #pragma unroll
        for (int rt = 0; rt < 4; rt++)
            #pragma unroll
            for (int ct = 0; ct < 4; ct++)
                acc[rt][ct] = __builtin_amdgcn_mfma_f32_16x16x32_bf16(af[rt], bfr[ct], acc[rt][ct], 0, 0, 0);
        __syncthreads();
    }
    #pragma unroll
    for (int rt = 0; rt < 4; rt++) {
        #pragma unroll
        for (int r = 0; r < 4; r++) {
            int grow = rowbase + wr * 64 + rt * 16 + quad * 4 + r;
            if (grow < g.M) {
                #pragma unroll
                for (int ct = 0; ct < 4; ct++) {
                    int gcol = colbase + wc * 64 + ct * 16 + l16;
                    float v = acc[rt][ct][r];
                    if (g.C)  g.C[(size_t)grow * g.ldc + gcol] = v;
                    if (g.Cb) g.Cb[(size_t)grow * g.ldcb + gcol] = __float2bfloat16(v);
                }
            }
        }
    }
}

// ---------------------------------------------------------------------------
// Batched transpose-cast: in fp32 [K][N] -> out bf16 [N][Kp], zero-pad K..Kp.
struct TDesc { const float* in; __hip_bfloat16* out; int K; int N; int Kp; };
struct TDesc8 { TDesc d[8]; };
__global__ void transpose_cast_kernel(TDesc8 descs) {
    TDesc dsc = descs.d[blockIdx.z];
    __shared__ float tile[32][33];
    int k0 = blockIdx.x * 32, n0 = blockIdx.y * 32;
    if (k0 >= dsc.Kp || n0 >= dsc.N) return;
    int tn = threadIdx.x & 31, t8 = threadIdx.x >> 5;
    #pragma unroll
    for (int i = 0; i < 4; i++) {
        int k = k0 + t8 * 4 + i;
        float v = 0.f;
        if (k < dsc.K && n0 + tn < dsc.N) v = dsc.in[(size_t)k * dsc.N + n0 + tn];
        tile[t8 * 4 + i][tn] = v;
    }
    __syncthreads();
    int kk = threadIdx.x & 31, n8 = threadIdx.x >> 5;
    #pragma unroll
    for (int i = 0; i < 4; i++) {
        int n = n0 + n8 * 4 + i;
        int k = k0 + kk;
        if (n < dsc.N && k < dsc.Kp)
            dsc.out[(size_t)n * dsc.Kp + k] = __float2bfloat16(tile[kk][n8 * 4 + i]);
    }
}

// cast fp32 -> bf16 (flat)
__global__ void cast_kernel(const float* __restrict__ in, __hip_bfloat16* __restrict__ out, int n) {
    int i = blockIdx.x * 256 + threadIdx.x;
    if (i < n) out[i] = __float2bfloat16(in[i]);
}

// cast fp32 [rows][K] -> bf16 [rows][Kp] zero-padded
__global__ void cast_pad_kernel(const float* __restrict__ in, __hip_bfloat16* __restrict__ out,
                                int rows, int K, int Kp) {
    int idx = blockIdx.x * 256 + threadIdx.x;
    if (idx >= rows * Kp) return;
    int r = idx / Kp, k = idx - r * Kp;
    out[idx] = (k < K) ? __float2bfloat16(in[(size_t)r * K + k]) : __float2bfloat16(0.f);
}

// ---------------------------------------------------------------------------
// Fused CSR build for all 4 edge types: histogram -> scan(+cursor) -> fill
struct EdgeDesc { const int* src; const int* tgt; int E; int n;
                  int* deg; int* rp; int* cur; int* cs; };
struct EdgeDesc4 { EdgeDesc d[4]; };

__global__ void hist4_kernel(EdgeDesc4 ds) {
    EdgeDesc d = ds.d[blockIdx.y];
    int e = blockIdx.x * 256 + threadIdx.x;
    if (e < d.E) atomicAdd(&d.deg[d.tgt[e]], 1);
}

__global__ void scan4_kernel(EdgeDesc4 ds) {
    EdgeDesc dd = ds.d[blockIdx.x];
    __shared__ int partx[257];
    __shared__ int part[256];
    int tid = threadIdx.x;
    int n = dd.n;
    int chunk = (n + 255) / 256;
    int lo = tid * chunk;
    int hi = lo + chunk; if (hi > n) hi = n;
    int s = 0;
    for (int i = lo; i < hi; i++) s += dd.deg[i];
    part[tid] = s;
    __syncthreads();
    if (tid == 0) {
        int acc = 0;
        for (int i = 0; i < 256; i++) { partx[i] = acc; acc += part[i]; }
        partx[256] = acc;
    }
    __syncthreads();
    int acc = partx[tid];
    for (int i = lo; i < hi; i++) { dd.rp[i] = acc; dd.cur[i] = acc; acc += dd.deg[i]; }
    if (tid == 0) dd.rp[n] = partx[256];
}

__global__ void fill4_kernel(EdgeDesc4 ds) {
    EdgeDesc d = ds.d[blockIdx.y];
    int e = blockIdx.x * 256 + threadIdx.x;
    if (e >= d.E) return;
    int t = d.tgt[e];
    int pos = atomicAdd(&d.cur[t], 1);
    d.cs[pos] = d.src[e];
}

// ---------------------------------------------------------------------------
// Fused segmented mean over bf16 messages (4 edge types in one launch).
// Wave-per-row: 64 lanes x ushort4 = one 512B coalesced load per edge.
// 4 rows per block, 4-edge unroll for memory-level parallelism.
struct AggDesc { const __hip_bfloat16* msg; const int* rp; const int* cs; float* outm; };
struct AggDesc4 { AggDesc d[4]; int start1, start2, start3; };

__global__ __launch_bounds__(256) void agg4_kernel(AggDesc4 ds, int nrows) {
    int row = blockIdx.x * 4 + (threadIdx.x >> 6);
    if (row >= nrows) return;
    int lane = threadIdx.x & 63;
    int gi = (row >= ds.start1) + (row >= ds.start2) + (row >= ds.start3);
    int base = (gi == 0) ? 0 : (gi == 1) ? ds.start1 : (gi == 2) ? ds.start2 : ds.start3;
    AggDesc g = ds.d[gi];
    int t = row - base;
    int lo = g.rp[t], hi = g.rp[t + 1];
    float a0 = 0.f, a1 = 0.f, a2 = 0.f, a3 = 0.f;
    int doff = lane * 4;
    int i = lo;
    for (; i + 4 <= hi; i += 4) {
        int s0 = g.cs[i], s1 = g.cs[i + 1], s2 = g.cs[i + 2], s3 = g.cs[i + 3];
        ushort4 u0 = *(const ushort4*)(g.msg + (size_t)s0 * HID + doff);
        ushort4 u1 = *(const ushort4*)(g.msg + (size_t)s1 * HID + doff);
        ushort4 u2 = *(const ushort4*)(g.msg + (size_t)s2 * HID + doff);
        ushort4 u3 = *(const ushort4*)(g.msg + (size_t)s3 * HID + doff);
        a0 += (bf2f(u0.x) + bf2f(u1.x)) + (bf2f(u2.x) + bf2f(u3.x));
        a1 += (bf2f(u0.y) + bf2f(u1.y)) + (bf2f(u2.y) + bf2f(u3.y));
        a2 += (bf2f(u0.z) + bf2f(u1.z)) + (bf2f(u2.z) + bf2f(u3.z));
        a3 += (bf2f(u0.w) + bf2f(u1.w)) + (bf2f(u2.w) + bf2f(u3.w));
    }
    for (; i < hi; i++) {
        ushort4 u = *(const ushort4*)(g.msg + (size_t)g.cs[i] * HID + doff);
        a0 += bf2f(u.x); a1 += bf2f(u.y); a2 += bf2f(u.z); a3 += bf2f(u.w);
    }
    float inv = 1.f / fmaxf((float)(hi - lo), 1.f);
    float4 o = make_float4(a0 * inv, a1 * inv, a2 * inv, a3 * inv);
    *reinterpret_cast<float4*>(g.outm + (size_t)t * HID + doff) = o;
}

// ---------------------------------------------------------------------------
// Layer-1 combine (vectorized): wave-per-row, float4/lane.  Writes fp32 + bf16.
// NOTE: no __restrict__ — element-wise same-index, aliasing-safe by design.
__global__ __launch_bounds__(256) void combine1v_kernel(
    const float* Sa, const float* Sb, const float* mH, const float* mD,
    float* s1, __hip_bfloat16* s1b,
    const float* Sc, const float* mI, float* c1, __hip_bfloat16* c1b,
    const float* Sw, const float* mR, float* wd1, __hip_bfloat16* wd1b) {
    int row = blockIdx.x * 4 + (threadIdx.x >> 6);
    if (row >= NSPOT + NCITY + NWORD) return;
    int lane = threadIdx.x & 63;
    float4 v; float* of; __hip_bfloat16* ob; size_t off;
    if (row < NSPOT) {
        off = (size_t)row * HID + lane * 4;
        float4 a = ld4(Sa, off), b = ld4(Sb, off), h = ld4(mH, off), d = ld4(mD, off);
        v = make_float4(fmaxf((a.x + b.x + h.x + d.x) * 0.5f, 0.f),
                        fmaxf((a.y + b.y + h.y + d.y) * 0.5f, 0.f),
                        fmaxf((a.z + b.z + h.z + d.z) * 0.5f, 0.f),
                        fmaxf((a.w + b.w + h.w + d.w) * 0.5f, 0.f));
        of = s1; ob = s1b;
    } else if (row < NSPOT + NCITY) {
        off = (size_t)(row - NSPOT) * HID + lane * 4;
        float4 a = ld4(Sc, off), m = ld4(mI, off);
        v = make_float4(fmaxf(a.x + m.x, 0.f), fmaxf(a.y + m.y, 0.f),
                        fmaxf(a.z + m.z, 0.f), fmaxf(a.w + m.w, 0.f));
        of = c1; ob = c1b;
    } else {
        off = (size_t)(row - NSPOT - NCITY) * HID + lane * 4;
        float4 a = ld4(Sw, off), m = ld4(mR, off);
        v = make_float4(fmaxf(a.x + m.x, 0.f), fmaxf(a.y + m.y, 0.f),
                        fmaxf(a.z + m.z, 0.f), fmaxf(a.w + m.w, 0.f));
        of = wd1; ob = wd1b;
    }
    *reinterpret_cast<float4*>(of + off) = v;
    ushort4 ub = make_ushort4(f2bf(v.x), f2bf(v.y), f2bf(v.z), f2bf(v.w));
    *reinterpret_cast<ushort4*>((unsigned short*)ob + off) = ub;
}

// ---------------------------------------------------------------------------
// Finale: L2 combine + (l1+l2)/2 mean + rowdot head, fused.  s2/c2/wd2 never
// materialized.  Wave-per-row, float4/lane, wave shuffle-reduce for the dot.
__global__ __launch_bounds__(256) void finale_kernel(
    const float* Sa, const float* Sb, const float* mH, const float* mD,
    const float* s1, float* out0, const float* wls, const float* bls, float* out3,
    const float* Sc, const float* mI, const float* c1, float* out1,
    const float* wlc, const float* blc, float* out4,
    const float* Sw, const float* mR, const float* wd1, float* out2,
    const float* wlw, const float* blw, float* out5) {
    int row = blockIdx.x * 4 + (threadIdx.x >> 6);
    if (row >= NSPOT + NCITY + NWORD) return;
    int lane = threadIdx.x & 63;
    float4 v, p; const float* wl; const float* bl; float* om; float* od;
    int r; size_t off;
    if (row < NSPOT) {
        r = row; off = (size_t)r * HID + lane * 4;
        float4 a = ld4(Sa, off), b = ld4(Sb, off), h = ld4(mH, off), d = ld4(mD, off);
        v = make_float4(fmaxf((a.x + b.x + h.x + d.x) * 0.5f, 0.f),
                        fmaxf((a.y + b.y + h.y + d.y) * 0.5f, 0.f),
                        fmaxf((a.z + b.z + h.z + d.z) * 0.5f, 0.f),
                        fmaxf((a.w + b.w + h.w + d.w) * 0.5f, 0.f));
        p = ld4(s1, off); wl = wls; bl = bls; om = out0; od = out3;
    } else if (row < NSPOT + NCITY) {
        r = row - NSPOT; off = (size_t)r * HID + lane * 4;
        float4 a = ld4(Sc, off), m = ld4(mI, off);
        v = make_float4(fmaxf(a.x + m.x, 0.f), fmaxf(a.y + m.y, 0.f),
                        fmaxf(a.z + m.z, 0.f), fmaxf(a.w + m.w, 0.f));
        p = ld4(c1, off); wl = wlc; bl = blc; om = out1; od = out4;
    } else {
        r = row - NSPOT - NCITY; off = (size_t)r * HID + lane * 4;
        float4 a = ld4(Sw, off), m = ld4(mR, off);
        v = make_float4(fmaxf(a.x + m.x, 0.f), fmaxf(a.y + m.y, 0.f),
                        fmaxf(a.z + m.z, 0.f), fmaxf(a.w + m.w, 0.f));
        p = ld4(wd1, off); wl = wlw; bl = blw; om = out2; od = out5;
    }
    float4 m4 = make_float4((p.x + v.x) * 0.5f, (p.y + v.y) * 0.5f,
                            (p.z + v.z) * 0.5f, (p.w + v.w) * 0.5f);
    *reinterpret_cast<float4*>(om + off) = m4;
    float4 w = *reinterpret_cast<const float4*>(wl + lane * 4);
    float s = v.x * w.x + v.y * w.y + v.z * w.z + v.w * w.w;
    #pragma unroll
    for (int o2 = 32; o2 > 0; o2 >>= 1) s += __shfl_down(s, o2, 64);
    if (lane == 0) od[r] = s + bl[0];
}

// ---------------------------------------------------------------------------
extern "C" void kernel_launch(void* const* d_in, const int* in_sizes, int n_in,
                              void* d_out, int out_size, void* d_ws, size_t ws_size,
                              hipStream_t stream) {
    const float* x_spot   = (const float*)d_in[0];
    const float* x_city   = (const float*)d_in[1];
    const float* x_word   = (const float*)d_in[2];
    const float* W_att    = (const float*)d_in[3];
    const float* q_att    = (const float*)d_in[4];
    const float* w1[8] = { (const float*)d_in[5], (const float*)d_in[6], (const float*)d_in[7],
                           (const float*)d_in[8], (const float*)d_in[9], (const float*)d_in[10],
                           (const float*)d_in[11], (const float*)d_in[12] };
    const float* w2[8] = { (const float*)d_in[13], (const float*)d_in[14], (const float*)d_in[15],
                           (const float*)d_in[16], (const float*)d_in[17], (const float*)d_in[18],
                           (const float*)d_in[19], (const float*)d_in[20] };
    const float* wl_spot = (const float*)d_in[21];
    const float* wl_city = (const float*)d_in[22];
    const float* wl_word = (const float*)d_in[23];
    const float* bl_spot = (const float*)d_in[24];
    const float* bl_city = (const float*)d_in[25];
    const float* bl_word = (const float*)d_in[26];
    const int* e_has_src   = (const int*)d_in[27];
    const int* e_has_tgt   = (const int*)d_in[28];
    const int* e_in_src    = (const int*)d_in[29];
    const int* e_in_tgt    = (const int*)d_in[30];
    const int* e_desc_src  = (const int*)d_in[31];
    const int* e_desc_tgt  = (const int*)d_in[32];
    const int* e_rdesc_src = (const int*)d_in[33];
    const int* e_rdesc_tgt = (const int*)d_in[34];
    const int E_has   = in_sizes[27];
    const int E_in    = in_sizes[29];
    const int E_desc  = in_sizes[31];
    const int E_rdesc = in_sizes[33];

    float* out = (float*)d_out;
    float* wsf = (float*)d_ws;
    typedef __hip_bfloat16 bf;

    // ---- workspace layout (units of float; bf16 arrays use half) ----
    size_t o = 0;
    auto alloc = [&](size_t nfloats) { float* p = wsf + o; o += (nfloats + 15) & ~(size_t)15; return p; };
    float* wqb       = alloc(2048);
    bf* xs_bf        = (bf*)alloc((size_t)NSPOT * 512 / 2);
    bf* x_city_bf    = (bf*)alloc((size_t)NCITY * 128 / 2);
    bf* x_word_bf    = (bf*)alloc((size_t)NWORD * 320 / 2);
    bf* Wt_att       = (bf*)alloc((size_t)4 * 128 * 512 / 2);
    // L1 transposed weights: [N=256][Kp]
    int K1[8]  = {128, 512, 512, 128, 300, 512, 512, 300};
    int Kp1[8] = {128, 512, 512, 128, 320, 512, 512, 320};
    bf* Wt1[8];
    for (int i = 0; i < 8; i++) Wt1[i] = (bf*)alloc((size_t)256 * Kp1[i] / 2);
    bf* Wt2[8];
    for (int i = 0; i < 8; i++) Wt2[i] = (bf*)alloc((size_t)256 * 256 / 2);
    float* Sa = alloc((size_t)NSPOT * HID);
    float* Sb = alloc((size_t)NSPOT * HID);
    float* Sc = alloc((size_t)NCITY * HID);
    float* Sw = alloc((size_t)NWORD * HID);
    float* m_has   = alloc((size_t)NSPOT * HID);
    float* m_desc  = alloc((size_t)NSPOT * HID);
    float* m_in    = alloc((size_t)NCITY * HID);
    float* m_rdesc = alloc((size_t)NWORD * HID);
    float* s1  = alloc((size_t)NSPOT * HID);
    float* c1  = alloc((size_t)NCITY * HID);
    float* wd1 = alloc((size_t)NWORD * HID);
    // region X: xbar (attention, dead after projection GEMMs) hosts P_* and s1b trio
    size_t regX = o;
    bf* xbar_bf = (bf*)(wsf + regX);                         // 4*NSPOT*512 bf16 = 20.48M floats
    size_t ox = regX;
    auto allocX = [&](size_t nfloats) { float* p = wsf + ox; ox += (nfloats + 15) & ~(size_t)15; return p; };
    bf* P_has_bf   = (bf*)allocX((size_t)NCITY * HID / 2);
    bf* P_in_bf    = (bf*)allocX((size_t)NSPOT * HID / 2);
    bf* P_desc_bf  = (bf*)allocX((size_t)NWORD * HID / 2);
    bf* P_rdesc_bf = (bf*)allocX((size_t)NSPOT * HID / 2);
    bf* s1b = (bf*)allocX((size_t)NSPOT * HID / 2);
    bf* c1b = (bf*)allocX((size_t)NCITY * HID / 2);
    bf* wd1b = (bf*)allocX((size_t)NWORD * HID / 2);
    o = regX + (size_t)4 * NSPOT * 512 / 2;                  // past xbar end (covers allocX region)
    // CSR ints
    int* wsi = (int*)(wsf + o);
    size_t io = 0;
    int* deg_has    = wsi + io; io += NSPOT;
    int* deg_desc   = wsi + io; io += NSPOT;
    int* deg_in     = wsi + io; io += NCITY;
    int* deg_rdesc  = wsi + io; io += NWORD;
    size_t deg_bytes = io * sizeof(int);
    int* rp_has     = wsi + io; io += NSPOT + 1;
    int* rp_desc    = wsi + io; io += NSPOT + 1;
    int* rp_in      = wsi + io; io += NCITY + 1;
    int* rp_rdesc   = wsi + io; io += NWORD + 1;
    int* cur_has    = wsi + io; io += NSPOT + 1;
    int* cur_desc   = wsi + io; io += NSPOT + 1;
    int* cur_in     = wsi + io; io += NCITY + 1;
    int* cur_rdesc  = wsi + io; io += NWORD + 1;
    int* cs_has     = wsi + io; io += E_has;
    int* cs_desc    = wsi + io; io += E_desc;
    int* cs_in      = wsi + io; io += E_in;
    int* cs_rdesc   = wsi + io; io += E_rdesc;
    (void)ws_size; (void)n_in; (void)out_size;

    // ---- weight transpose-casts + input casts ----
    {
        TDesc8 t{};
        for (int i = 0; i < 4; i++)
            t.d[i] = TDesc{ W_att + (size_t)i * 512 * 128, Wt_att + (size_t)i * 128 * 512, 512, 128, 512 };
        hipLaunchKernelGGL(transpose_cast_kernel, dim3(16, 4, 4), dim3(256), 0, stream, t);
    }
    {
        TDesc8 t{};
        for (int i = 0; i < 8; i++) t.d[i] = TDesc{ w1[i], Wt1[i], K1[i], 256, Kp1[i] };
        hipLaunchKernelGGL(transpose_cast_kernel, dim3(16, 8, 8), dim3(256), 0, stream, t);
    }
    {
        TDesc8 t{};
        for (int i = 0; i < 8; i++) t.d[i] = TDesc{ w2[i], Wt2[i], 256, 256, 256 };
        hipLaunchKernelGGL(transpose_cast_kernel, dim3(8, 8, 8), dim3(256), 0, stream, t);
    }
    hipLaunchKernelGGL(cast_kernel, dim3((NCITY * 128 + 255) / 256), dim3(256), 0, stream,
                       x_city, x_city_bf, NCITY * 128);
    hipLaunchKernelGGL(cast_pad_kernel, dim3((NWORD * 320 + 255) / 256), dim3(256), 0, stream,
                       x_word, x_word_bf, NWORD, 300, 320);

    // ---- fused CSR build (reused by both layers) ----
    EdgeDesc4 ed;
    ed.d[0] = EdgeDesc{ e_has_src,   e_has_tgt,   E_has,   NSPOT, deg_has,   rp_has,   cur_has,   cs_has };
    ed.d[1] = EdgeDesc{ e_desc_src,  e_desc_tgt,  E_desc,  NSPOT, deg_desc,  rp_desc,  cur_desc,  cs_desc };
    ed.d[2] = EdgeDesc{ e_in_src,    e_in_tgt,    E_in,    NCITY, deg_in,    rp_in,    cur_in,    cs_in };
    ed.d[3] = EdgeDesc{ e_rdesc_src, e_rdesc_tgt, E_rdesc, NWORD, deg_rdesc, rp_rdesc, cur_rdesc, cs_rdesc };
    int Emax = E_has;
    if (E_desc > Emax) Emax = E_desc;
    if (E_in > Emax) Emax = E_in;
    if (E_rdesc > Emax) Emax = E_rdesc;
    hipMemsetAsync((void*)deg_has, 0, deg_bytes, stream);
    hipLaunchKernelGGL(hist4_kernel, dim3((Emax + 255) / 256, 4), dim3(256), 0, stream, ed);
    hipLaunchKernelGGL(scan4_kernel, dim3(4), dim3(256), 0, stream, ed);
    hipLaunchKernelGGL(fill4_kernel, dim3((Emax + 255) / 256, 4), dim3(256), 0, stream, ed);

    // ---- attention ----
    hipLaunchKernelGGL(wq_kernel, dim3(8), dim3(256), 0, stream, W_att, q_att, wqb);
    hipLaunchKernelGGL(attn_kernel, dim3(NSPOT), dim3(256), 0, stream, x_spot, wqb, xbar_bf);
    {
        dim3 g((NSPOT + 127) / 128, 1, 4);
        hipLaunchKernelGGL(gemm_bf16, g, dim3(256), 0, stream,
                           xbar_bf, 512, (long)NSPOT * 512, Wt_att, 512, (long)128 * 512,
                           nullptr, 0, xs_bf, 512, 128, NSPOT, 128, 512);
    }

    int gx = (NSPOT + 127) / 128;   // 157 row-blocks covers the largest group

    // ---- layer 1 GEMMs (one grouped launch) ----
    {
        GemmDesc8 gd;
        gd.d[0] = GemmDesc{ x_city_bf, Wt1[0], nullptr, P_has_bf,   128, 128, 0, HID, NCITY, 128 };
        gd.d[1] = GemmDesc{ xs_bf,     Wt1[1], Sa,      nullptr,    512, 512, HID, 0, NSPOT, 512 };
        gd.d[2] = GemmDesc{ xs_bf,     Wt1[2], nullptr, P_in_bf,    512, 512, 0, HID, NSPOT, 512 };
        gd.d[3] = GemmDesc{ x_city_bf, Wt1[3], Sc,      nullptr,    128, 128, HID, 0, NCITY, 128 };
        gd.d[4] = GemmDesc{ x_word_bf, Wt1[4], nullptr, P_desc_bf,  320, 320, 0, HID, NWORD, 320 };
        gd.d[5] = GemmDesc{ xs_bf,     Wt1[5], Sb,      nullptr,    512, 512, HID, 0, NSPOT, 512 };
        gd.d[6] = GemmDesc{ xs_bf,     Wt1[6], nullptr, P_rdesc_bf, 512, 512, 0, HID, NSPOT, 512 };
        gd.d[7] = GemmDesc{ x_word_bf, Wt1[7], Sw,      nullptr,    320, 320, HID, 0, NWORD, 320 };
        hipLaunchKernelGGL(gemm_bf16_grouped, dim3(gx, 2, 8), dim3(256), 0, stream, gd);
    }

    // ---- layer 1 aggregation + combine ----
    AggDesc4 ag;
    ag.start1 = NSPOT; ag.start2 = 2 * NSPOT; ag.start3 = 2 * NSPOT + NCITY;
    int agg_rows = 2 * NSPOT + NCITY + NWORD;
    ag.d[0] = AggDesc{ P_has_bf,   rp_has,   cs_has,   m_has };
    ag.d[1] = AggDesc{ P_desc_bf,  rp_desc,  cs_desc,  m_desc };
    ag.d[2] = AggDesc{ P_in_bf,    rp_in,    cs_in,    m_in };
    ag.d[3] = AggDesc{ P_rdesc_bf, rp_rdesc, cs_rdesc, m_rdesc };
    hipLaunchKernelGGL(agg4_kernel, dim3((agg_rows + 3) / 4), dim3(256), 0, stream, ag, agg_rows);
    hipLaunchKernelGGL(combine1v_kernel, dim3((NSPOT + NCITY + NWORD) / 4), dim3(256), 0, stream,
                       Sa, Sb, m_has, m_desc, s1, s1b,
                       Sc, m_in, c1, c1b,
                       Sw, m_rdesc, wd1, wd1b);

    // ---- layer 2 GEMMs (one grouped launch) ----
    {
        GemmDesc8 gd;
        gd.d[0] = GemmDesc{ c1b,  Wt2[0], nullptr, P_has_bf,   HID, HID, 0, HID, NCITY, HID };
        gd.d[1] = GemmDesc{ s1b,  Wt2[1], Sa,      nullptr,    HID, HID, HID, 0, NSPOT, HID };
        gd.d[2] = GemmDesc{ s1b,  Wt2[2], nullptr, P_in_bf,    HID, HID, 0, HID, NSPOT, HID };
        gd.d[3] = GemmDesc{ c1b,  Wt2[3], Sc,      nullptr,    HID, HID, HID, 0, NCITY, HID };
        gd.d[4] = GemmDesc{ wd1b, Wt2[4], nullptr, P_desc_bf,  HID, HID, 0, HID, NWORD, HID };
        gd.d[5] = GemmDesc{ s1b,  Wt2[5], Sb,      nullptr,    HID, HID, HID, 0, NSPOT, HID };
        gd.d[6] = GemmDesc{ s1b,  Wt2[6], nullptr, P_rdesc_bf, HID, HID, 0, HID, NSPOT, HID };
        gd.d[7] = GemmDesc{ wd1b, Wt2[7], Sw,      nullptr,    HID, HID, HID, 0, NWORD, HID };
        hipLaunchKernelGGL(gemm_bf16_grouped, dim3(gx, 2, 8), dim3(256), 0, stream, gd);
    }

    // ---- layer 2 aggregation ----
    hipLaunchKernelGGL(agg4_kernel, dim3((agg_rows + 3) / 4), dim3(256), 0, stream, ag, agg_rows);

    // ---- fused L2 combine + mean + rowdot ----
    float* out0 = out;
    float* out1 = out + (size_t)NSPOT * HID;
    float* out2 = out1 + (size_t)NCITY * HID;
    float* out3 = out2 + (size_t)NWORD * HID;
    float* out4 = out3 + NSPOT;
    float* out5 = out4 + NCITY;
    hipLaunchKernelGGL(finale_kernel, dim3((NSPOT + NCITY + NWORD) / 4), dim3(256), 0, stream,
                       Sa, Sb, m_has, m_desc, s1, out0, wl_spot, bl_spot, out3,
                       Sc, m_in, c1, out1, wl_city, bl_city, out4,
                       Sw, m_rdesc, wd1, out2, wl_word, bl_word, out5);
}

// Round 4
// 842.695 us; speedup vs baseline: 1.5098x; 1.1401x over previous
//
#include <hip/hip_runtime.h>
#include <hip/hip_bf16.h>

#define HID 256
#define NSPOT 20000
#define NCITY 2000
#define NWORD 20000

typedef __attribute__((ext_vector_type(8))) short bhalf8;
typedef __attribute__((ext_vector_type(4))) float floatx4;

__device__ inline float bf2f(unsigned short u) {
    union { unsigned int i; float f; } v; v.i = (unsigned int)u << 16; return v.f;
}
__device__ inline unsigned short f2bf(float f) {
    __hip_bfloat16 b = __float2bfloat16(f);
    return *reinterpret_cast<unsigned short*>(&b);
}
__device__ inline float4 ld4(const float* p, size_t off) {
    return *reinterpret_cast<const float4*>(p + off);
}

// ---------------------------------------------------------------------------
// wq[h][i] = sum_o W_att[h][i][o] * q_att[h][o]
__global__ void wq_kernel(const float* __restrict__ W, const float* __restrict__ q,
                          float* __restrict__ wq) {
    int idx = blockIdx.x * 256 + threadIdx.x;   // 4*512 = 2048
    if (idx >= 2048) return;
    int h = idx >> 9, i = idx & 511;
    const float* Wr = W + ((size_t)h * 512 + i) * 128;
    const float* qr = q + h * 128;
    float s = 0.f;
    #pragma unroll 4
    for (int o = 0; o < 128; o++) s += Wr[o] * qr[o];
    wq[idx] = s;
}

// ---------------------------------------------------------------------------
// Per-node attention: scores via wave-reduction, softmax, blend -> xbar bf16.
__global__ __launch_bounds__(256) void attn_kernel(const float* __restrict__ x,
                                                   const float* __restrict__ wq,
                                                   __hip_bfloat16* __restrict__ xbar) {
    __shared__ float xl[2560];
    __shared__ float al[4][8];
    int n = blockIdx.x;
    int tid = threadIdx.x;
    int wave = tid >> 6, lane = tid & 63;
    const float4* xr4 = (const float4*)(x + (size_t)n * 2560);
    for (int i = tid; i < 640; i += 256) ((float4*)xl)[i] = xr4[i];
    __syncthreads();
    const float* wqh = wq + wave * 512;
    for (int s = 0; s < 5; s++) {
        float a = 0.f;
        #pragma unroll
        for (int j = 0; j < 8; j++)
            a += xl[s * 512 + lane + j * 64] * wqh[lane + j * 64];
        #pragma unroll
        for (int off = 32; off > 0; off >>= 1) a += __shfl_down(a, off, 64);
        if (lane == 0) al[wave][s] = a;
    }
    __syncthreads();
    if (tid < 4) {
        float z[5]; float m = -1e30f;
        #pragma unroll
        for (int s = 0; s < 5; s++) {
            float v = al[tid][s];
            v = (v >= 0.f) ? v : 0.2f * v;    // leaky_relu 0.2
            z[s] = v; m = fmaxf(m, v);
        }
        float e[5]; float sum = 0.f;
        #pragma unroll
        for (int s = 0; s < 5; s++) { e[s] = __expf(z[s] - m); sum += e[s]; }
        float r = 1.f / sum;
        #pragma unroll
        for (int s = 0; s < 5; s++) al[tid][s] = e[s] * r;
    }
    __syncthreads();
    float a0 = al[wave][0], a1 = al[wave][1], a2 = al[wave][2], a3 = al[wave][3], a4 = al[wave][4];
    __hip_bfloat16* xo = xbar + ((size_t)wave * NSPOT + n) * 512;
    #pragma unroll
    for (int j = 0; j < 8; j++) {
        int i = lane + j * 64;
        float v = a0 * xl[i] + a1 * xl[512 + i] + a2 * xl[1024 + i] + a3 * xl[1536 + i] + a4 * xl[2048 + i];
        xo[i] = __float2bfloat16(v);
    }
}

// ---------------------------------------------------------------------------
// Grouped bf16 MFMA GEMM: per-group C[M,N] = A[M,K] @ Bt[N,K]^T, N in {128,256}.
// 128x128 tile, 4 waves (64x64 each as 4x4 of 16x16), K%32==0.  Reg-staged
// LDS KP=40 (80B stride: 2-way bank aliasing = free).  Proven structure.
#define KP 40
struct GemmDesc {
    const __hip_bfloat16* A;
    const __hip_bfloat16* Bt;
    float* C;
    __hip_bfloat16* Cb;
    int lda, ldb, ldc, ldcb, M, K, N;
};
struct GemmDesc8 { GemmDesc d[8]; };

__global__ __launch_bounds__(256) void gemm_grouped(GemmDesc8 descs) {
    GemmDesc g = descs.d[blockIdx.z];
    int rowbase = blockIdx.x * 128;
    int colbase = blockIdx.y * 128;
    if (rowbase >= g.M || colbase >= g.N) return;   // block-uniform early-exit
    __shared__ short As[128 * KP];
    __shared__ short Bs[128 * KP];
    int tid = threadIdx.x;
    int wave = tid >> 6, lane = tid & 63;
    int wr = wave & 1, wc = wave >> 1;
    int quad = lane >> 4, l16 = lane & 15;
    int srow = tid >> 2;            // 0..63
    int skoff = (tid & 3) * 8;      // 0,8,16,24
    const __hip_bfloat16* A = g.A;
    const __hip_bfloat16* Bt = g.Bt;
    int lda = g.lda, ldb = g.ldb, M = g.M, K = g.K;
    floatx4 acc[4][4];
    #pragma unroll
    for (int i = 0; i < 4; i++)
        #pragma unroll
        for (int j = 0; j < 4; j++)
            acc[i][j] = (floatx4){0.f, 0.f, 0.f, 0.f};

    for (int k0 = 0; k0 < K; k0 += 32) {
        #pragma unroll
        for (int i = 0; i < 2; i++) {
            int r = srow + i * 64;
            int gr = rowbase + r;
            int4 va = make_int4(0, 0, 0, 0);
            if (gr < M) va = *(const int4*)(A + (size_t)gr * lda + k0 + skoff);
            *(int4*)(As + r * KP + skoff) = va;
            int4 vb = *(const int4*)(Bt + (size_t)(colbase + r) * ldb + k0 + skoff);
            *(int4*)(Bs + r * KP + skoff) = vb;
        }
        __syncthreads();
        bhalf8 af[4], bfr[4];
        #pragma unroll
        for (int rt = 0; rt < 4; rt++)
            af[rt] = *(const bhalf8*)(As + (wr * 64 + rt * 16 + l16) * KP + quad * 8);
        #pragma unroll
        for (int ct = 0; ct < 4; ct++)
            bfr[ct] = *(const bhalf8*)(Bs + (wc * 64 + ct * 16 + l16) * KP + quad * 8);
        #pragma unroll
        for (int rt = 0; rt < 4; rt++)
            #pragma unroll
            for (int ct = 0; ct < 4; ct++)
                acc[rt][ct] = __builtin_amdgcn_mfma_f32_16x16x32_bf16(af[rt], bfr[ct], acc[rt][ct], 0, 0, 0);
        __syncthreads();
    }
    #pragma unroll
    for (int rt = 0; rt < 4; rt++) {
        #pragma unroll
        for (int r = 0; r < 4; r++) {
            int grow = rowbase + wr * 64 + rt * 16 + quad * 4 + r;
            if (grow < M) {
                #pragma unroll
                for (int ct = 0; ct < 4; ct++) {
                    int gcol = colbase + wc * 64 + ct * 16 + l16;
                    float v = acc[rt][ct][r];
                    if (g.C)  g.C[(size_t)grow * g.ldc + gcol] = v;
                    if (g.Cb) g.Cb[(size_t)grow * g.ldcb + gcol] = __float2bfloat16(v);
                }
            }
        }
    }
}

// ---------------------------------------------------------------------------
// Batched transpose-cast: in fp32 [K][N] (+optional in2, summed) -> bf16
// [N][Kp], zero-pad K..Kp.
struct TDesc { const float* in; const float* in2; __hip_bfloat16* out; int K; int N; int Kp; };
struct TDesc8 { TDesc d[8]; };
__global__ void transpose_cast_kernel(TDesc8 descs) {
    TDesc dsc = descs.d[blockIdx.z];
    __shared__ float tile[32][33];
    int k0 = blockIdx.x * 32, n0 = blockIdx.y * 32;
    if (k0 >= dsc.Kp || n0 >= dsc.N) return;
    int tn = threadIdx.x & 31, t8 = threadIdx.x >> 5;
    #pragma unroll
    for (int i = 0; i < 4; i++) {
        int k = k0 + t8 * 4 + i;
        float v = 0.f;
        if (k < dsc.K && n0 + tn < dsc.N) {
            v = dsc.in[(size_t)k * dsc.N + n0 + tn];
            if (dsc.in2) v += dsc.in2[(size_t)k * dsc.N + n0 + tn];
        }
        tile[t8 * 4 + i][tn] = v;
    }
    __syncthreads();
    int kk = threadIdx.x & 31, n8 = threadIdx.x >> 5;
    #pragma unroll
    for (int i = 0; i < 4; i++) {
        int n = n0 + n8 * 4 + i;
        int k = k0 + kk;
        if (n < dsc.N && k < dsc.Kp)
            dsc.out[(size_t)n * dsc.Kp + k] = __float2bfloat16(tile[kk][n8 * 4 + i]);
    }
}

// cast fp32 -> bf16 (flat)
__global__ void cast_kernel(const float* __restrict__ in, __hip_bfloat16* __restrict__ out, int n) {
    int i = blockIdx.x * 256 + threadIdx.x;
    if (i < n) out[i] = __float2bfloat16(in[i]);
}

// cast fp32 [rows][K] -> bf16 [rows][Kp] zero-padded
__global__ void cast_pad_kernel(const float* __restrict__ in, __hip_bfloat16* __restrict__ out,
                                int rows, int K, int Kp) {
    int idx = blockIdx.x * 256 + threadIdx.x;
    if (idx >= rows * Kp) return;
    int r = idx / Kp, k = idx - r * Kp;
    out[idx] = (k < K) ? __float2bfloat16(in[(size_t)r * K + k]) : __float2bfloat16(0.f);
}

// ---------------------------------------------------------------------------
// Fused CSR build for all 4 edge types: histogram -> scan(+cursor) -> fill
struct EdgeDesc { const int* src; const int* tgt; int E; int n;
                  int* deg; int* rp; int* cur; int* cs; };
struct EdgeDesc4 { EdgeDesc d[4]; };

__global__ void hist4_kernel(EdgeDesc4 ds) {
    EdgeDesc d = ds.d[blockIdx.y];
    int e = blockIdx.x * 256 + threadIdx.x;
    if (e < d.E) atomicAdd(&d.deg[d.tgt[e]], 1);
}

__global__ void scan4_kernel(EdgeDesc4 ds) {
    EdgeDesc dd = ds.d[blockIdx.x];
    __shared__ int partx[257];
    __shared__ int part[256];
    int tid = threadIdx.x;
    int n = dd.n;
    int chunk = (n + 255) / 256;
    int lo = tid * chunk;
    int hi = lo + chunk; if (hi > n) hi = n;
    int s = 0;
    for (int i = lo; i < hi; i++) s += dd.deg[i];
    part[tid] = s;
    __syncthreads();
    if (tid == 0) {
        int acc = 0;
        for (int i = 0; i < 256; i++) { partx[i] = acc; acc += part[i]; }
        partx[256] = acc;
    }
    __syncthreads();
    int acc = partx[tid];
    for (int i = lo; i < hi; i++) { dd.rp[i] = acc; dd.cur[i] = acc; acc += dd.deg[i]; }
    if (tid == 0) dd.rp[n] = partx[256];
}

__global__ void fill4_kernel(EdgeDesc4 ds) {
    EdgeDesc d = ds.d[blockIdx.y];
    int e = blockIdx.x * 256 + threadIdx.x;
    if (e >= d.E) return;
    int t = d.tgt[e];
    int pos = atomicAdd(&d.cur[t], 1);
    d.cs[pos] = d.src[e];
}

// ---------------------------------------------------------------------------
// Segment mean helper: wave-per-row, 64 lanes x ushort4 = one 512B coalesced
// load per edge, 4-edge unroll for MLP.
__device__ inline float4 seg_mean(const __hip_bfloat16* __restrict__ msg,
                                  const int* __restrict__ rp, const int* __restrict__ cs,
                                  int t, int doff) {
    int lo = rp[t], hi = rp[t + 1];
    float a0 = 0.f, a1 = 0.f, a2 = 0.f, a3 = 0.f;
    int i = lo;
    for (; i + 4 <= hi; i += 4) {
        int s0 = cs[i], s1 = cs[i + 1], s2 = cs[i + 2], s3 = cs[i + 3];
        ushort4 u0 = *(const ushort4*)(msg + (size_t)s0 * HID + doff);
        ushort4 u1 = *(const ushort4*)(msg + (size_t)s1 * HID + doff);
        ushort4 u2 = *(const ushort4*)(msg + (size_t)s2 * HID + doff);
        ushort4 u3 = *(const ushort4*)(msg + (size_t)s3 * HID + doff);
        a0 += (bf2f(u0.x) + bf2f(u1.x)) + (bf2f(u2.x) + bf2f(u3.x));
        a1 += (bf2f(u0.y) + bf2f(u1.y)) + (bf2f(u2.y) + bf2f(u3.y));
        a2 += (bf2f(u0.z) + bf2f(u1.z)) + (bf2f(u2.z) + bf2f(u3.z));
        a3 += (bf2f(u0.w) + bf2f(u1.w)) + (bf2f(u2.w) + bf2f(u3.w));
    }
    for (; i < hi; i++) {
        ushort4 u = *(const ushort4*)(msg + (size_t)cs[i] * HID + doff);
        a0 += bf2f(u.x); a1 += bf2f(u.y); a2 += bf2f(u.z); a3 += bf2f(u.w);
    }
    float inv = 1.f / fmaxf((float)(hi - lo), 1.f);
    return make_float4(a0 * inv, a1 * inv, a2 * inv, a3 * inv);
}

// ---------------------------------------------------------------------------
// Layer-1 fused: segment-mean gathers + combine + ReLU + fp32/bf16 store.
// Wave-per-row over all 42000 output rows (spot rows gather has+desc).
__global__ __launch_bounds__(256) void fused_ac1_kernel(
    const __hip_bfloat16* __restrict__ Phas,   const int* __restrict__ rp_has,   const int* __restrict__ cs_has,
    const __hip_bfloat16* __restrict__ Pdesc,  const int* __restrict__ rp_desc,  const int* __restrict__ cs_desc,
    const __hip_bfloat16* __restrict__ Pin,    const int* __restrict__ rp_in,    const int* __restrict__ cs_in,
    const __hip_bfloat16* __restrict__ Prdesc, const int* __restrict__ rp_rdesc, const int* __restrict__ cs_rdesc,
    const float* __restrict__ Ss, const float* __restrict__ Sc, const float* __restrict__ Sw,
    float* __restrict__ s1, __hip_bfloat16* __restrict__ s1b,
    float* __restrict__ c1, __hip_bfloat16* __restrict__ c1b,
    float* __restrict__ wd1, __hip_bfloat16* __restrict__ wd1b) {
    int row = blockIdx.x * 4 + (threadIdx.x >> 6);
    if (row >= NSPOT + NCITY + NWORD) return;
    int lane = threadIdx.x & 63;
    int doff = lane * 4;
    float4 v; float* of; __hip_bfloat16* ob; size_t off;
    if (row < NSPOT) {
        float4 mh = seg_mean(Phas, rp_has, cs_has, row, doff);
        float4 md = seg_mean(Pdesc, rp_desc, cs_desc, row, doff);
        off = (size_t)row * HID + doff;
        float4 s = ld4(Ss, off);
        v = make_float4(fmaxf((s.x + mh.x + md.x) * 0.5f, 0.f),
                        fmaxf((s.y + mh.y + md.y) * 0.5f, 0.f),
                        fmaxf((s.z + mh.z + md.z) * 0.5f, 0.f),
                        fmaxf((s.w + mh.w + md.w) * 0.5f, 0.f));
        of = s1; ob = s1b;
    } else if (row < NSPOT + NCITY) {
        int r = row - NSPOT;
        float4 mi = seg_mean(Pin, rp_in, cs_in, r, doff);
        off = (size_t)r * HID + doff;
        float4 s = ld4(Sc, off);
        v = make_float4(fmaxf(s.x + mi.x, 0.f), fmaxf(s.y + mi.y, 0.f),
                        fmaxf(s.z + mi.z, 0.f), fmaxf(s.w + mi.w, 0.f));
        of = c1; ob = c1b;
    } else {
        int r = row - NSPOT - NCITY;
        float4 mr = seg_mean(Prdesc, rp_rdesc, cs_rdesc, r, doff);
        off = (size_t)r * HID + doff;
        float4 s = ld4(Sw, off);
        v = make_float4(fmaxf(s.x + mr.x, 0.f), fmaxf(s.y + mr.y, 0.f),
                        fmaxf(s.z + mr.z, 0.f), fmaxf(s.w + mr.w, 0.f));
        of = wd1; ob = wd1b;
    }
    *reinterpret_cast<float4*>(of + off) = v;
    ushort4 ub = make_ushort4(f2bf(v.x), f2bf(v.y), f2bf(v.z), f2bf(v.w));
    *reinterpret_cast<ushort4*>((unsigned short*)ob + off) = ub;
}

// ---------------------------------------------------------------------------
// Layer-2 fused finale: gathers + combine + (l1+l2)/2 mean + rowdot head.
__global__ __launch_bounds__(256) void fused_finale_kernel(
    const __hip_bfloat16* __restrict__ Phas,   const int* __restrict__ rp_has,   const int* __restrict__ cs_has,
    const __hip_bfloat16* __restrict__ Pdesc,  const int* __restrict__ rp_desc,  const int* __restrict__ cs_desc,
    const __hip_bfloat16* __restrict__ Pin,    const int* __restrict__ rp_in,    const int* __restrict__ cs_in,
    const __hip_bfloat16* __restrict__ Prdesc, const int* __restrict__ rp_rdesc, const int* __restrict__ cs_rdesc,
    const float* __restrict__ Ss, const float* __restrict__ Sc, const float* __restrict__ Sw,
    const float* __restrict__ s1, const float* __restrict__ c1, const float* __restrict__ wd1,
    float* __restrict__ out0, const float* __restrict__ wls, const float* __restrict__ bls, float* __restrict__ out3,
    float* __restrict__ out1, const float* __restrict__ wlc, const float* __restrict__ blc, float* __restrict__ out4,
    float* __restrict__ out2, const float* __restrict__ wlw, const float* __restrict__ blw, float* __restrict__ out5) {
    int row = blockIdx.x * 4 + (threadIdx.x >> 6);
    if (row >= NSPOT + NCITY + NWORD) return;
    int lane = threadIdx.x & 63;
    int doff = lane * 4;
    float4 v, p; const float* wl; const float* bl; float* om; float* od;
    int r; size_t off;
    if (row < NSPOT) {
        r = row;
        float4 mh = seg_mean(Phas, rp_has, cs_has, r, doff);
        float4 md = seg_mean(Pdesc, rp_desc, cs_desc, r, doff);
        off = (size_t)r * HID + doff;
        float4 s = ld4(Ss, off);
        v = make_float4(fmaxf((s.x + mh.x + md.x) * 0.5f, 0.f),
                        fmaxf((s.y + mh.y + md.y) * 0.5f, 0.f),
                        fmaxf((s.z + mh.z + md.z) * 0.5f, 0.f),
                        fmaxf((s.w + mh.w + md.w) * 0.5f, 0.f));
        p = ld4(s1, off); wl = wls; bl = bls; om = out0; od = out3;
    } else if (row < NSPOT + NCITY) {
        r = row - NSPOT;
        float4 mi = seg_mean(Pin, rp_in, cs_in, r, doff);
        off = (size_t)r * HID + doff;
        float4 s = ld4(Sc, off);
        v = make_float4(fmaxf(s.x + mi.x, 0.f), fmaxf(s.y + mi.y, 0.f),
                        fmaxf(s.z + mi.z, 0.f), fmaxf(s.w + mi.w, 0.f));
        p = ld4(c1, off); wl = wlc; bl = blc; om = out1; od = out4;
    } else {
        r = row - NSPOT - NCITY;
        float4 mr = seg_mean(Prdesc, rp_rdesc, cs_rdesc, r, doff);
        off = (size_t)r * HID + doff;
        float4 s = ld4(Sw, off);
        v = make_float4(fmaxf(s.x + mr.x, 0.f), fmaxf(s.y + mr.y, 0.f),
                        fmaxf(s.z + mr.z, 0.f), fmaxf(s.w + mr.w, 0.f));
        p = ld4(wd1, off); wl = wlw; bl = blw; om = out2; od = out5;
    }
    float4 m4 = make_float4((p.x + v.x) * 0.5f, (p.y + v.y) * 0.5f,
                            (p.z + v.z) * 0.5f, (p.w + v.w) * 0.5f);
    *reinterpret_cast<float4*>(om + off) = m4;
    float4 w = *reinterpret_cast<const float4*>(wl + doff);
    float s = v.x * w.x + v.y * w.y + v.z * w.z + v.w * w.w;
    #pragma unroll
    for (int o2 = 32; o2 > 0; o2 >>= 1) s += __shfl_down(s, o2, 64);
    if (lane == 0) od[r] = s + bl[0];
}

// ---------------------------------------------------------------------------
extern "C" void kernel_launch(void* const* d_in, const int* in_sizes, int n_in,
                              void* d_out, int out_size, void* d_ws, size_t ws_size,
                              hipStream_t stream) {
    const float* x_spot   = (const float*)d_in[0];
    const float* x_city   = (const float*)d_in[1];
    const float* x_word   = (const float*)d_in[2];
    const float* W_att    = (const float*)d_in[3];
    const float* q_att    = (const float*)d_in[4];
    const float* w1[8] = { (const float*)d_in[5], (const float*)d_in[6], (const float*)d_in[7],
                           (const float*)d_in[8], (const float*)d_in[9], (const float*)d_in[10],
                           (const float*)d_in[11], (const float*)d_in[12] };
    const float* w2[8] = { (const float*)d_in[13], (const float*)d_in[14], (const float*)d_in[15],
                           (const float*)d_in[16], (const float*)d_in[17], (const float*)d_in[18],
                           (const float*)d_in[19], (const float*)d_in[20] };
    const float* wl_spot = (const float*)d_in[21];
    const float* wl_city = (const float*)d_in[22];
    const float* wl_word = (const float*)d_in[23];
    const float* bl_spot = (const float*)d_in[24];
    const float* bl_city = (const float*)d_in[25];
    const float* bl_word = (const float*)d_in[26];
    const int* e_has_src   = (const int*)d_in[27];
    const int* e_has_tgt   = (const int*)d_in[28];
    const int* e_in_src    = (const int*)d_in[29];
    const int* e_in_tgt    = (const int*)d_in[30];
    const int* e_desc_src  = (const int*)d_in[31];
    const int* e_desc_tgt  = (const int*)d_in[32];
    const int* e_rdesc_src = (const int*)d_in[33];
    const int* e_rdesc_tgt = (const int*)d_in[34];
    const int E_has   = in_sizes[27];
    const int E_in    = in_sizes[29];
    const int E_desc  = in_sizes[31];
    const int E_rdesc = in_sizes[33];

    float* out = (float*)d_out;
    float* wsf = (float*)d_ws;
    typedef __hip_bfloat16 bf;

    // ---- workspace layout (units of float; bf16 arrays use half) ----
    size_t o = 0;
    auto alloc = [&](size_t nfloats) { float* p = wsf + o; o += (nfloats + 15) & ~(size_t)15; return p; };
    float* wqb       = alloc(2048);
    bf* xs_bf        = (bf*)alloc((size_t)NSPOT * 512 / 2);
    bf* x_city_bf    = (bf*)alloc((size_t)NCITY * 128 / 2);
    bf* x_word_bf    = (bf*)alloc((size_t)NWORD * 320 / 2);
    bf* Wt_att       = (bf*)alloc((size_t)4 * 128 * 512 / 2);
    // L1 transposed weights [N=256][Kp]: 0:has_s 1:SUM(has_t+desc_t) 2:in_s
    // 3:in_t 4:desc_s 5:rdesc_s 6:rdesc_t
    int Kp1[7] = {128, 512, 512, 128, 320, 512, 320};
    bf* Wt1[7];
    for (int i = 0; i < 7; i++) Wt1[i] = (bf*)alloc((size_t)256 * Kp1[i] / 2);
    bf* Wt2[7];
    for (int i = 0; i < 7; i++) Wt2[i] = (bf*)alloc((size_t)256 * 256 / 2);
    float* Ss = alloc((size_t)NSPOT * HID);        // merged has_t+desc_t self term
    float* Sc = alloc((size_t)NCITY * HID);
    float* Sw = alloc((size_t)NWORD * HID);
    float* s1  = alloc((size_t)NSPOT * HID);
    float* c1  = alloc((size_t)NCITY * HID);
    float* wd1 = alloc((size_t)NWORD * HID);
    // region X: xbar (dead after projection GEMM) hosts P_* and the bf16 trio
    size_t regX = o;
    bf* xbar_bf = (bf*)(wsf + regX);                         // 4*NSPOT*512 bf16
    size_t ox = regX;
    auto allocX = [&](size_t nfloats) { float* p = wsf + ox; ox += (nfloats + 15) & ~(size_t)15; return p; };
    bf* P_has_bf   = (bf*)allocX((size_t)NCITY * HID / 2);
    bf* P_in_bf    = (bf*)allocX((size_t)NSPOT * HID / 2);
    bf* P_desc_bf  = (bf*)allocX((size_t)NWORD * HID / 2);
    bf* P_rdesc_bf = (bf*)allocX((size_t)NSPOT * HID / 2);
    bf* s1b = (bf*)allocX((size_t)NSPOT * HID / 2);
    bf* c1b = (bf*)allocX((size_t)NCITY * HID / 2);
    bf* wd1b = (bf*)allocX((size_t)NWORD * HID / 2);
    o = regX + (size_t)4 * NSPOT * 512 / 2;                  // past xbar end
    // CSR ints
    int* wsi = (int*)(wsf + o);
    size_t io = 0;
    int* deg_has    = wsi + io; io += NSPOT;
    int* deg_desc   = wsi + io; io += NSPOT;
    int* deg_in     = wsi + io; io += NCITY;
    int* deg_rdesc  = wsi + io; io += NWORD;
    size_t deg_bytes = io * sizeof(int);
    int* rp_has     = wsi + io; io += NSPOT + 1;
    int* rp_desc    = wsi + io; io += NSPOT + 1;
    int* rp_in      = wsi + io; io += NCITY + 1;
    int* rp_rdesc   = wsi + io; io += NWORD + 1;
    int* cur_has    = wsi + io; io += NSPOT + 1;
    int* cur_desc   = wsi + io; io += NSPOT + 1;
    int* cur_in     = wsi + io; io += NCITY + 1;
    int* cur_rdesc  = wsi + io; io += NWORD + 1;
    int* cs_has     = wsi + io; io += E_has;
    int* cs_desc    = wsi + io; io += E_desc;
    int* cs_in      = wsi + io; io += E_in;
    int* cs_rdesc   = wsi + io; io += E_rdesc;
    (void)ws_size; (void)n_in; (void)out_size;

    // ---- weight transpose-casts + input casts ----
    {
        TDesc8 t{};
        for (int i = 0; i < 4; i++)
            t.d[i] = TDesc{ W_att + (size_t)i * 512 * 128, nullptr,
                            Wt_att + (size_t)i * 128 * 512, 512, 128, 512 };
        hipLaunchKernelGGL(transpose_cast_kernel, dim3(16, 4, 4), dim3(256), 0, stream, t);
    }
    {
        TDesc8 t{};
        t.d[0] = TDesc{ w1[0], nullptr, Wt1[0], 128, 256, 128 };
        t.d[1] = TDesc{ w1[1], w1[5],   Wt1[1], 512, 256, 512 };   // has_t + desc_t
        t.d[2] = TDesc{ w1[2], nullptr, Wt1[2], 512, 256, 512 };
        t.d[3] = TDesc{ w1[3], nullptr, Wt1[3], 128, 256, 128 };
        t.d[4] = TDesc{ w1[4], nullptr, Wt1[4], 300, 256, 320 };
        t.d[5] = TDesc{ w1[6], nullptr, Wt1[5], 512, 256, 512 };
        t.d[6] = TDesc{ w1[7], nullptr, Wt1[6], 300, 256, 320 };
        hipLaunchKernelGGL(transpose_cast_kernel, dim3(16, 8, 8), dim3(256), 0, stream, t);
    }
    {
        TDesc8 t{};
        t.d[0] = TDesc{ w2[0], nullptr, Wt2[0], 256, 256, 256 };
        t.d[1] = TDesc{ w2[1], w2[5],   Wt2[1], 256, 256, 256 };   // has_t + desc_t
        t.d[2] = TDesc{ w2[2], nullptr, Wt2[2], 256, 256, 256 };
        t.d[3] = TDesc{ w2[3], nullptr, Wt2[3], 256, 256, 256 };
        t.d[4] = TDesc{ w2[4], nullptr, Wt2[4], 256, 256, 256 };
        t.d[5] = TDesc{ w2[6], nullptr, Wt2[5], 256, 256, 256 };
        t.d[6] = TDesc{ w2[7], nullptr, Wt2[6], 256, 256, 256 };
        hipLaunchKernelGGL(transpose_cast_kernel, dim3(8, 8, 8), dim3(256), 0, stream, t);
    }
    hipLaunchKernelGGL(cast_kernel, dim3((NCITY * 128 + 255) / 256), dim3(256), 0, stream,
                       x_city, x_city_bf, NCITY * 128);
    hipLaunchKernelGGL(cast_pad_kernel, dim3((NWORD * 320 + 255) / 256), dim3(256), 0, stream,
                       x_word, x_word_bf, NWORD, 300, 320);

    // ---- fused CSR build (reused by both layers) ----
    EdgeDesc4 ed;
    ed.d[0] = EdgeDesc{ e_has_src,   e_has_tgt,   E_has,   NSPOT, deg_has,   rp_has,   cur_has,   cs_has };
    ed.d[1] = EdgeDesc{ e_desc_src,  e_desc_tgt,  E_desc,  NSPOT, deg_desc,  rp_desc,  cur_desc,  cs_desc };
    ed.d[2] = EdgeDesc{ e_in_src,    e_in_tgt,    E_in,    NCITY, deg_in,    rp_in,    cur_in,    cs_in };
    ed.d[3] = EdgeDesc{ e_rdesc_src, e_rdesc_tgt, E_rdesc, NWORD, deg_rdesc, rp_rdesc, cur_rdesc, cs_rdesc };
    int Emax = E_has;
    if (E_desc > Emax) Emax = E_desc;
    if (E_in > Emax) Emax = E_in;
    if (E_rdesc > Emax) Emax = E_rdesc;
    hipMemsetAsync((void*)deg_has, 0, deg_bytes, stream);
    hipLaunchKernelGGL(hist4_kernel, dim3((Emax + 255) / 256, 4), dim3(256), 0, stream, ed);
    hipLaunchKernelGGL(scan4_kernel, dim3(4), dim3(256), 0, stream, ed);
    hipLaunchKernelGGL(fill4_kernel, dim3((Emax + 255) / 256, 4), dim3(256), 0, stream, ed);

    // ---- attention ----
    hipLaunchKernelGGL(wq_kernel, dim3(8), dim3(256), 0, stream, W_att, q_att, wqb);
    hipLaunchKernelGGL(attn_kernel, dim3(NSPOT), dim3(256), 0, stream, x_spot, wqb, xbar_bf);

    int gx = (NSPOT + 127) / 128;   // 157

    // projection: 4 heads as a grouped GEMM (N=128)
    {
        GemmDesc8 gd{};
        for (int h = 0; h < 4; h++)
            gd.d[h] = GemmDesc{ xbar_bf + (size_t)h * NSPOT * 512, Wt_att + (size_t)h * 128 * 512,
                                nullptr, xs_bf + h * 128, 512, 512, 0, 512, NSPOT, 512, 128 };
        hipLaunchKernelGGL(gemm_grouped, dim3(gx, 1, 4), dim3(256), 0, stream, gd);
    }

    // ---- layer 1 GEMMs (one grouped launch, 7 groups) ----
    {
        GemmDesc8 gd{};
        gd.d[0] = GemmDesc{ x_city_bf, Wt1[0], nullptr, P_has_bf,   128, 128, 0, HID, NCITY, 128, HID };
        gd.d[1] = GemmDesc{ xs_bf,     Wt1[1], Ss,      nullptr,    512, 512, HID, 0, NSPOT, 512, HID };
        gd.d[2] = GemmDesc{ xs_bf,     Wt1[2], nullptr, P_in_bf,    512, 512, 0, HID, NSPOT, 512, HID };
        gd.d[3] = GemmDesc{ x_city_bf, Wt1[3], Sc,      nullptr,    128, 128, HID, 0, NCITY, 128, HID };
        gd.d[4] = GemmDesc{ x_word_bf, Wt1[4], nullptr, P_desc_bf,  320, 320, 0, HID, NWORD, 320, HID };
        gd.d[5] = GemmDesc{ xs_bf,     Wt1[5], nullptr, P_rdesc_bf, 512, 512, 0, HID, NSPOT, 512, HID };
        gd.d[6] = GemmDesc{ x_word_bf, Wt1[6], Sw,      nullptr,    320, 320, HID, 0, NWORD, 320, HID };
        gd.d[7].M = 0; gd.d[7].N = 0;
        hipLaunchKernelGGL(gemm_grouped, dim3(gx, 2, 8), dim3(256), 0, stream, gd);
    }

    // ---- layer 1 fused aggregation + combine ----
    int rows3 = NSPOT + NCITY + NWORD;
    hipLaunchKernelGGL(fused_ac1_kernel, dim3((rows3 + 3) / 4), dim3(256), 0, stream,
                       P_has_bf, rp_has, cs_has, P_desc_bf, rp_desc, cs_desc,
                       P_in_bf, rp_in, cs_in, P_rdesc_bf, rp_rdesc, cs_rdesc,
                       Ss, Sc, Sw, s1, s1b, c1, c1b, wd1, wd1b);

    // ---- layer 2 GEMMs (one grouped launch, 7 groups) ----
    {
        GemmDesc8 gd{};
        gd.d[0] = GemmDesc{ c1b,  Wt2[0], nullptr, P_has_bf,   HID, HID, 0, HID, NCITY, HID, HID };
        gd.d[1] = GemmDesc{ s1b,  Wt2[1], Ss,      nullptr,    HID, HID, HID, 0, NSPOT, HID, HID };
        gd.d[2] = GemmDesc{ s1b,  Wt2[2], nullptr, P_in_bf,    HID, HID, 0, HID, NSPOT, HID, HID };
        gd.d[3] = GemmDesc{ c1b,  Wt2[3], Sc,      nullptr,    HID, HID, HID, 0, NCITY, HID, HID };
        gd.d[4] = GemmDesc{ wd1b, Wt2[4], nullptr, P_desc_bf,  HID, HID, 0, HID, NWORD, HID, HID };
        gd.d[5] = GemmDesc{ s1b,  Wt2[5], nullptr, P_rdesc_bf, HID, HID, 0, HID, NSPOT, HID, HID };
        gd.d[6] = GemmDesc{ wd1b, Wt2[6], Sw,      nullptr,    HID, HID, HID, 0, NWORD, HID, HID };
        gd.d[7].M = 0; gd.d[7].N = 0;
        hipLaunchKernelGGL(gemm_grouped, dim3(gx, 2, 8), dim3(256), 0, stream, gd);
    }

    // ---- layer 2 fused aggregation + combine + mean + rowdot ----
    float* out0 = out;
    float* out1 = out + (size_t)NSPOT * HID;
    float* out2 = out1 + (size_t)NCITY * HID;
    float* out3 = out2 + (size_t)NWORD * HID;
    float* out4 = out3 + NSPOT;
    float* out5 = out4 + NCITY;
    hipLaunchKernelGGL(fused_finale_kernel, dim3((rows3 + 3) / 4), dim3(256), 0, stream,
                       P_has_bf, rp_has, cs_has, P_desc_bf, rp_desc, cs_desc,
                       P_in_bf, rp_in, cs_in, P_rdesc_bf, rp_rdesc, cs_rdesc,
                       Ss, Sc, Sw, s1, c1, wd1,
                       out0, wl_spot, bl_spot, out3,
                       out1, wl_city, bl_city, out4,
                       out2, wl_word, bl_word, out5);
}

// Round 6
// 838.763 us; speedup vs baseline: 1.5168x; 1.0047x over previous
//
#include <hip/hip_runtime.h>
#include <hip/hip_bf16.h>

#define HID 256
#define NSPOT 20000
#define NCITY 2000
#define NWORD 20000

typedef __attribute__((ext_vector_type(8))) short bhalf8;
typedef __attribute__((ext_vector_type(4))) float floatx4;
typedef __attribute__((ext_vector_type(8))) unsigned short ushortx8;

__device__ inline float bf2f(unsigned short u) {
    union { unsigned int i; float f; } v; v.i = (unsigned int)u << 16; return v.f;
}
__device__ inline unsigned short f2bf(float f) {
    __hip_bfloat16 b = __float2bfloat16(f);
    return *reinterpret_cast<unsigned short*>(&b);
}
__device__ inline float4 ld4(const float* p, size_t off) {
    return *reinterpret_cast<const float4*>(p + off);
}

// ---------------------------------------------------------------------------
// wq[h][i] = sum_o W_att[h][i][o] * q_att[h][o]
__global__ void wq_kernel(const float* __restrict__ W, const float* __restrict__ q,
                          float* __restrict__ wq) {
    int idx = blockIdx.x * 256 + threadIdx.x;   // 4*512 = 2048
    if (idx >= 2048) return;
    int h = idx >> 9, i = idx & 511;
    const float* Wr = W + ((size_t)h * 512 + i) * 128;
    const float* qr = q + h * 128;
    float s = 0.f;
    #pragma unroll 4
    for (int o = 0; o < 128; o++) s += Wr[o] * qr[o];
    wq[idx] = s;
}

// ---------------------------------------------------------------------------
// Per-node attention: scores via wave-reduction, softmax, blend -> xbar bf16.
__global__ __launch_bounds__(256) void attn_kernel(const float* __restrict__ x,
                                                   const float* __restrict__ wq,
                                                   __hip_bfloat16* __restrict__ xbar) {
    __shared__ float xl[2560];
    __shared__ float al[4][8];
    int n = blockIdx.x;
    int tid = threadIdx.x;
    int wave = tid >> 6, lane = tid & 63;
    const float4* xr4 = (const float4*)(x + (size_t)n * 2560);
    for (int i = tid; i < 640; i += 256) ((float4*)xl)[i] = xr4[i];
    __syncthreads();
    const float* wqh = wq + wave * 512;
    for (int s = 0; s < 5; s++) {
        float a = 0.f;
        #pragma unroll
        for (int j = 0; j < 8; j++)
            a += xl[s * 512 + lane + j * 64] * wqh[lane + j * 64];
        #pragma unroll
        for (int off = 32; off > 0; off >>= 1) a += __shfl_down(a, off, 64);
        if (lane == 0) al[wave][s] = a;
    }
    __syncthreads();
    if (tid < 4) {
        float z[5]; float m = -1e30f;
        #pragma unroll
        for (int s = 0; s < 5; s++) {
            float v = al[tid][s];
            v = (v >= 0.f) ? v : 0.2f * v;    // leaky_relu 0.2
            z[s] = v; m = fmaxf(m, v);
        }
        float e[5]; float sum = 0.f;
        #pragma unroll
        for (int s = 0; s < 5; s++) { e[s] = __expf(z[s] - m); sum += e[s]; }
        float r = 1.f / sum;
        #pragma unroll
        for (int s = 0; s < 5; s++) al[tid][s] = e[s] * r;
    }
    __syncthreads();
    float a0 = al[wave][0], a1 = al[wave][1], a2 = al[wave][2], a3 = al[wave][3], a4 = al[wave][4];
    __hip_bfloat16* xo = xbar + ((size_t)wave * NSPOT + n) * 512;
    #pragma unroll
    for (int j = 0; j < 8; j++) {
        int i = lane + j * 64;
        float v = a0 * xl[i] + a1 * xl[512 + i] + a2 * xl[1024 + i] + a3 * xl[1536 + i] + a4 * xl[2048 + i];
        xo[i] = __float2bfloat16(v);
    }
}

// ---------------------------------------------------------------------------
// Grouped bf16 MFMA GEMM: per-group C[M,N] = A[M,K] @ Bt[N,K]^T, N in {128,256}.
// 128x128 tile, 4 waves (64x64 each as 4x4 of 16x16), K%32==0.  Reg-staged
// LDS KP=40 (80B stride: 2-way bank aliasing = free).  Harness-proven.
#define KP 40
struct GemmDesc {
    const __hip_bfloat16* A;
    const __hip_bfloat16* Bt;
    float* C;
    __hip_bfloat16* Cb;
    int lda, ldb, ldc, ldcb, M, K, N;
};
struct GemmDesc8 { GemmDesc d[8]; };

__global__ __launch_bounds__(256) void gemm_grouped(GemmDesc8 descs) {
    GemmDesc g = descs.d[blockIdx.z];
    int rowbase = blockIdx.x * 128;
    int colbase = blockIdx.y * 128;
    if (rowbase >= g.M || colbase >= g.N) return;   // block-uniform early-exit
    __shared__ short As[128 * KP];
    __shared__ short Bs[128 * KP];
    int tid = threadIdx.x;
    int wave = tid >> 6, lane = tid & 63;
    int wr = wave & 1, wc = wave >> 1;
    int quad = lane >> 4, l16 = lane & 15;
    int srow = tid >> 2;            // 0..63
    int skoff = (tid & 3) * 8;      // 0,8,16,24
    const __hip_bfloat16* A = g.A;
    const __hip_bfloat16* Bt = g.Bt;
    int lda = g.lda, ldb = g.ldb, M = g.M, K = g.K;
    floatx4 acc[4][4];
    #pragma unroll
    for (int i = 0; i < 4; i++)
        #pragma unroll
        for (int j = 0; j < 4; j++)
            acc[i][j] = (floatx4){0.f, 0.f, 0.f, 0.f};

    for (int k0 = 0; k0 < K; k0 += 32) {
        #pragma unroll
        for (int i = 0; i < 2; i++) {
            int r = srow + i * 64;
            int gr = rowbase + r;
            int4 va = make_int4(0, 0, 0, 0);
            if (gr < M) va = *(const int4*)(A + (size_t)gr * lda + k0 + skoff);
            *(int4*)(As + r * KP + skoff) = va;
            int4 vb = *(const int4*)(Bt + (size_t)(colbase + r) * ldb + k0 + skoff);
            *(int4*)(Bs + r * KP + skoff) = vb;
        }
        __syncthreads();
        bhalf8 af[4], bfr[4];
        #pragma unroll
        for (int rt = 0; rt < 4; rt++)
            af[rt] = *(const bhalf8*)(As + (wr * 64 + rt * 16 + l16) * KP + quad * 8);
        #pragma unroll
        for (int ct = 0; ct < 4; ct++)
            bfr[ct] = *(const bhalf8*)(Bs + (wc * 64 + ct * 16 + l16) * KP + quad * 8);
        #pragma unroll
        for (int rt = 0; rt < 4; rt++)
            #pragma unroll
            for (int ct = 0; ct < 4; ct++)
                acc[rt][ct] = __builtin_amdgcn_mfma_f32_16x16x32_bf16(af[rt], bfr[ct], acc[rt][ct], 0, 0, 0);
        __syncthreads();
    }
    #pragma unroll
    for (int rt = 0; rt < 4; rt++) {
        #pragma unroll
        for (int r = 0; r < 4; r++) {
            int grow = rowbase + wr * 64 + rt * 16 + quad * 4 + r;
            if (grow < M) {
                #pragma unroll
                for (int ct = 0; ct < 4; ct++) {
                    int gcol = colbase + wc * 64 + ct * 16 + l16;
                    float v = acc[rt][ct][r];
                    if (g.C)  g.C[(size_t)grow * g.ldc + gcol] = v;
                    if (g.Cb) g.Cb[(size_t)grow * g.ldcb + gcol] = __float2bfloat16(v);
                }
            }
        }
    }
}

// ---------------------------------------------------------------------------
// Batched transpose-cast: in fp32 [K][N] (+optional in2, summed) -> bf16
// [N][Kp], zero-pad K..Kp.
struct TDesc { const float* in; const float* in2; __hip_bfloat16* out; int K; int N; int Kp; };
struct TDesc8 { TDesc d[8]; };
__global__ void transpose_cast_kernel(TDesc8 descs) {
    TDesc dsc = descs.d[blockIdx.z];
    __shared__ float tile[32][33];
    int k0 = blockIdx.x * 32, n0 = blockIdx.y * 32;
    if (k0 >= dsc.Kp || n0 >= dsc.N) return;
    int tn = threadIdx.x & 31, t8 = threadIdx.x >> 5;
    #pragma unroll
    for (int i = 0; i < 4; i++) {
        int k = k0 + t8 * 4 + i;
        float v = 0.f;
        if (k < dsc.K && n0 + tn < dsc.N) {
            v = dsc.in[(size_t)k * dsc.N + n0 + tn];
            if (dsc.in2) v += dsc.in2[(size_t)k * dsc.N + n0 + tn];
        }
        tile[t8 * 4 + i][tn] = v;
    }
    __syncthreads();
    int kk = threadIdx.x & 31, n8 = threadIdx.x >> 5;
    #pragma unroll
    for (int i = 0; i < 4; i++) {
        int n = n0 + n8 * 4 + i;
        int k = k0 + kk;
        if (n < dsc.N && k < dsc.Kp)
            dsc.out[(size_t)n * dsc.Kp + k] = __float2bfloat16(tile[kk][n8 * 4 + i]);
    }
}

// cast fp32 -> bf16 (flat)
__global__ void cast_kernel(const float* __restrict__ in, __hip_bfloat16* __restrict__ out, int n) {
    int i = blockIdx.x * 256 + threadIdx.x;
    if (i < n) out[i] = __float2bfloat16(in[i]);
}

// cast fp32 [rows][K] -> bf16 [rows][Kp] zero-padded
__global__ void cast_pad_kernel(const float* __restrict__ in, __hip_bfloat16* __restrict__ out,
                                int rows, int K, int Kp) {
    int idx = blockIdx.x * 256 + threadIdx.x;
    if (idx >= rows * Kp) return;
    int r = idx / Kp, k = idx - r * Kp;
    out[idx] = (k < K) ? __float2bfloat16(in[(size_t)r * K + k]) : __float2bfloat16(0.f);
}

// ---------------------------------------------------------------------------
// Fused CSR build for all 4 edge types: histogram -> scan(+cursor) -> fill
struct EdgeDesc { const int* src; const int* tgt; int E; int n;
                  int* deg; int* rp; int* cur; int* cs; };
struct EdgeDesc4 { EdgeDesc d[4]; };

__global__ void hist4_kernel(EdgeDesc4 ds) {
    EdgeDesc d = ds.d[blockIdx.y];
    int e = blockIdx.x * 256 + threadIdx.x;
    if (e < d.E) atomicAdd(&d.deg[d.tgt[e]], 1);
}

__global__ void scan4_kernel(EdgeDesc4 ds) {
    EdgeDesc dd = ds.d[blockIdx.x];
    __shared__ int partx[257];
    __shared__ int part[256];
    int tid = threadIdx.x;
    int n = dd.n;
    int chunk = (n + 255) / 256;
    int lo = tid * chunk;
    int hi = lo + chunk; if (hi > n) hi = n;
    int s = 0;
    for (int i = lo; i < hi; i++) s += dd.deg[i];
    part[tid] = s;
    __syncthreads();
    if (tid == 0) {
        int acc = 0;
        for (int i = 0; i < 256; i++) { partx[i] = acc; acc += part[i]; }
        partx[256] = acc;
    }
    __syncthreads();
    int acc = partx[tid];
    for (int i = lo; i < hi; i++) { dd.rp[i] = acc; dd.cur[i] = acc; acc += dd.deg[i]; }
    if (tid == 0) dd.rp[n] = partx[256];
}

__global__ void fill4_kernel(EdgeDesc4 ds) {
    EdgeDesc d = ds.d[blockIdx.y];
    int e = blockIdx.x * 256 + threadIdx.x;
    if (e >= d.E) return;
    int t = d.tgt[e];
    int pos = atomicAdd(&d.cur[t], 1);
    d.cs[pos] = d.src[e];
}

// ---------------------------------------------------------------------------
// Segment mean, half-wave-per-edge: 32 lanes x ushort8 (16B) cover one 512B
// message row, so each wave VMEM instruction fetches TWO edges (half=0 takes
// even CSR slots, half=1 odd).  After the loop a shfl_down(32) merges the
// halves; lanes 0..31 hold the 8-dims/lane result (lanes 32..63 garbage).
__device__ inline void seg_mean8(const __hip_bfloat16* __restrict__ msg,
                                 const int* __restrict__ rp, const int* __restrict__ cs,
                                 int t, int half, int li, float a[8]) {
    int lo = rp[t], hi = rp[t + 1];
    #pragma unroll
    for (int j = 0; j < 8; j++) a[j] = 0.f;
    int col = li * 8;
    int i = lo + half;
    for (; i + 2 < hi; i += 4) {
        ushortx8 u0 = *(const ushortx8*)(msg + (size_t)cs[i] * HID + col);
        ushortx8 u1 = *(const ushortx8*)(msg + (size_t)cs[i + 2] * HID + col);
        #pragma unroll
        for (int j = 0; j < 8; j++) a[j] += bf2f(u0[j]) + bf2f(u1[j]);
    }
    if (i < hi) {
        ushortx8 u = *(const ushortx8*)(msg + (size_t)cs[i] * HID + col);
        #pragma unroll
        for (int j = 0; j < 8; j++) a[j] += bf2f(u[j]);
    }
    #pragma unroll
    for (int j = 0; j < 8; j++) a[j] += __shfl_down(a[j], 32, 64);
    float inv = 1.f / fmaxf((float)(hi - lo), 1.f);
    #pragma unroll
    for (int j = 0; j < 8; j++) a[j] *= inv;
}

// ---------------------------------------------------------------------------
// Layer-1 fused: segment-mean gathers + combine + ReLU + fp32/bf16 store.
// Wave-per-row over all 42000 output rows (spot rows gather has+desc).
__global__ __launch_bounds__(256) void fused_ac1_kernel(
    const __hip_bfloat16* __restrict__ Phas,   const int* __restrict__ rp_has,   const int* __restrict__ cs_has,
    const __hip_bfloat16* __restrict__ Pdesc,  const int* __restrict__ rp_desc,  const int* __restrict__ cs_desc,
    const __hip_bfloat16* __restrict__ Pin,    const int* __restrict__ rp_in,    const int* __restrict__ cs_in,
    const __hip_bfloat16* __restrict__ Prdesc, const int* __restrict__ rp_rdesc, const int* __restrict__ cs_rdesc,
    const float* __restrict__ Ss, const float* __restrict__ Sc, const float* __restrict__ Sw,
    float* __restrict__ s1, __hip_bfloat16* __restrict__ s1b,
    float* __restrict__ c1, __hip_bfloat16* __restrict__ c1b,
    float* __restrict__ wd1, __hip_bfloat16* __restrict__ wd1b) {
    int row = blockIdx.x * 4 + (threadIdx.x >> 6);
    if (row >= NSPOT + NCITY + NWORD) return;
    int lane = threadIdx.x & 63;
    int half = lane >> 5, li = lane & 31;
    float v[8]; float* of; __hip_bfloat16* ob; size_t off;
    if (row < NSPOT) {
        float mh[8], md[8];
        seg_mean8(Phas, rp_has, cs_has, row, half, li, mh);
        seg_mean8(Pdesc, rp_desc, cs_desc, row, half, li, md);
        off = (size_t)row * HID + li * 8;
        float4 sa = ld4(Ss, off), sb = ld4(Ss, off + 4);
        v[0] = fmaxf((sa.x + mh[0] + md[0]) * 0.5f, 0.f);
        v[1] = fmaxf((sa.y + mh[1] + md[1]) * 0.5f, 0.f);
        v[2] = fmaxf((sa.z + mh[2] + md[2]) * 0.5f, 0.f);
        v[3] = fmaxf((sa.w + mh[3] + md[3]) * 0.5f, 0.f);
        v[4] = fmaxf((sb.x + mh[4] + md[4]) * 0.5f, 0.f);
        v[5] = fmaxf((sb.y + mh[5] + md[5]) * 0.5f, 0.f);
        v[6] = fmaxf((sb.z + mh[6] + md[6]) * 0.5f, 0.f);
        v[7] = fmaxf((sb.w + mh[7] + md[7]) * 0.5f, 0.f);
        of = s1; ob = s1b;
    } else if (row < NSPOT + NCITY) {
        int r = row - NSPOT;
        float mi[8];
        seg_mean8(Pin, rp_in, cs_in, r, half, li, mi);
        off = (size_t)r * HID + li * 8;
        float4 sa = ld4(Sc, off), sb = ld4(Sc, off + 4);
        v[0] = fmaxf(sa.x + mi[0], 0.f); v[1] = fmaxf(sa.y + mi[1], 0.f);
        v[2] = fmaxf(sa.z + mi[2], 0.f); v[3] = fmaxf(sa.w + mi[3], 0.f);
        v[4] = fmaxf(sb.x + mi[4], 0.f); v[5] = fmaxf(sb.y + mi[5], 0.f);
        v[6] = fmaxf(sb.z + mi[6], 0.f); v[7] = fmaxf(sb.w + mi[7], 0.f);
        of = c1; ob = c1b;
    } else {
        int r = row - NSPOT - NCITY;
        float mr[8];
        seg_mean8(Prdesc, rp_rdesc, cs_rdesc, r, half, li, mr);
        off = (size_t)r * HID + li * 8;
        float4 sa = ld4(Sw, off), sb = ld4(Sw, off + 4);
        v[0] = fmaxf(sa.x + mr[0], 0.f); v[1] = fmaxf(sa.y + mr[1], 0.f);
        v[2] = fmaxf(sa.z + mr[2], 0.f); v[3] = fmaxf(sa.w + mr[3], 0.f);
        v[4] = fmaxf(sb.x + mr[4], 0.f); v[5] = fmaxf(sb.y + mr[5], 0.f);
        v[6] = fmaxf(sb.z + mr[6], 0.f); v[7] = fmaxf(sb.w + mr[7], 0.f);
        of = wd1; ob = wd1b;
    }
    if (half == 0) {
        *reinterpret_cast<float4*>(of + off)     = make_float4(v[0], v[1], v[2], v[3]);
        *reinterpret_cast<float4*>(of + off + 4) = make_float4(v[4], v[5], v[6], v[7]);
        ushortx8 ub;
        #pragma unroll
        for (int j = 0; j < 8; j++) ub[j] = f2bf(v[j]);
        *reinterpret_cast<ushortx8*>((unsigned short*)ob + off) = ub;
    }
}

// ---------------------------------------------------------------------------
// Layer-2 fused finale: gathers + combine + (l1+l2)/2 mean + rowdot head.
__global__ __launch_bounds__(256) void fused_finale_kernel(
    const __hip_bfloat16* __restrict__ Phas,   const int* __restrict__ rp_has,   const int* __restrict__ cs_has,
    const __hip_bfloat16* __restrict__ Pdesc,  const int* __restrict__ rp_desc,  const int* __restrict__ cs_desc,
    const __hip_bfloat16* __restrict__ Pin,    const int* __restrict__ rp_in,    const int* __restrict__ cs_in,
    const __hip_bfloat16* __restrict__ Prdesc, const int* __restrict__ rp_rdesc, const int* __restrict__ cs_rdesc,
    const float* __restrict__ Ss, const float* __restrict__ Sc, const float* __restrict__ Sw,
    const float* __restrict__ s1, const float* __restrict__ c1, const float* __restrict__ wd1,
    float* __restrict__ out0, const float* __restrict__ wls, const float* __restrict__ bls, float* __restrict__ out3,
    float* __restrict__ out1, const float* __restrict__ wlc, const float* __restrict__ blc, float* __restrict__ out4,
    float* __restrict__ out2, const float* __restrict__ wlw, const float* __restrict__ blw, float* __restrict__ out5) {
    int row = blockIdx.x * 4 + (threadIdx.x >> 6);
    if (row >= NSPOT + NCITY + NWORD) return;
    int lane = threadIdx.x & 63;
    int half = lane >> 5, li = lane & 31;
    float v[8]; const float* pl; const float* wl; const float* bl; float* om; float* od;
    int r; size_t off;
    if (row < NSPOT) {
        r = row;
        float mh[8], md[8];
        seg_mean8(Phas, rp_has, cs_has, r, half, li, mh);
        seg_mean8(Pdesc, rp_desc, cs_desc, r, half, li, md);
        off = (size_t)r * HID + li * 8;
        float4 sa = ld4(Ss, off), sb = ld4(Ss, off + 4);
        v[0] = fmaxf((sa.x + mh[0] + md[0]) * 0.5f, 0.f);
        v[1] = fmaxf((sa.y + mh[1] + md[1]) * 0.5f, 0.f);
        v[2] = fmaxf((sa.z + mh[2] + md[2]) * 0.5f, 0.f);
        v[3] = fmaxf((sa.w + mh[3] + md[3]) * 0.5f, 0.f);
        v[4] = fmaxf((sb.x + mh[4] + md[4]) * 0.5f, 0.f);
        v[5] = fmaxf((sb.y + mh[5] + md[5]) * 0.5f, 0.f);
        v[6] = fmaxf((sb.z + mh[6] + md[6]) * 0.5f, 0.f);
        v[7] = fmaxf((sb.w + mh[7] + md[7]) * 0.5f, 0.f);
        pl = s1; wl = wls; bl = bls; om = out0; od = out3;
    } else if (row < NSPOT + NCITY) {
        r = row - NSPOT;
        float mi[8];
        seg_mean8(Pin, rp_in, cs_in, r, half, li, mi);
        off = (size_t)r * HID + li * 8;
        float4 sa = ld4(Sc, off), sb = ld4(Sc, off + 4);
        v[0] = fmaxf(sa.x + mi[0], 0.f); v[1] = fmaxf(sa.y + mi[1], 0.f);
        v[2] = fmaxf(sa.z + mi[2], 0.f); v[3] = fmaxf(sa.w + mi[3], 0.f);
        v[4] = fmaxf(sb.x + mi[4], 0.f); v[5] = fmaxf(sb.y + mi[5], 0.f);
        v[6] = fmaxf(sb.z + mi[6], 0.f); v[7] = fmaxf(sb.w + mi[7], 0.f);
        pl = c1; wl = wlc; bl = blc; om = out1; od = out4;
    } else {
        r = row - NSPOT - NCITY;
        float mr[8];
        seg_mean8(Prdesc, rp_rdesc, cs_rdesc, r, half, li, mr);
        off = (size_t)r * HID + li * 8;
        float4 sa = ld4(Sw, off), sb = ld4(Sw, off + 4);
        v[0] = fmaxf(sa.x + mr[0], 0.f); v[1] = fmaxf(sa.y + mr[1], 0.f);
        v[2] = fmaxf(sa.z + mr[2], 0.f); v[3] = fmaxf(sa.w + mr[3], 0.f);
        v[4] = fmaxf(sb.x + mr[4], 0.f); v[5] = fmaxf(sb.y + mr[5], 0.f);
        v[6] = fmaxf(sb.z + mr[6], 0.f); v[7] = fmaxf(sb.w + mr[7], 0.f);
        pl = wd1; wl = wlw; bl = blw; om = out2; od = out5;
    }
    // mean with layer-1 output (valid on lanes 0..31 only; stores guarded)
    float4 pa = ld4(pl, off), pb = ld4(pl, off + 4);
    if (half == 0) {
        *reinterpret_cast<float4*>(om + off) =
            make_float4((pa.x + v[0]) * 0.5f, (pa.y + v[1]) * 0.5f,
                        (pa.z + v[2]) * 0.5f, (pa.w + v[3]) * 0.5f);
        *reinterpret_cast<float4*>(om + off + 4) =
            make_float4((pb.x + v[4]) * 0.5f, (pb.y + v[5]) * 0.5f,
                        (pb.z + v[6]) * 0.5f, (pb.w + v[7]) * 0.5f);
    }
    // rowdot over 256 dims held 8-per-lane on lanes 0..31
    float4 wa = *reinterpret_cast<const float4*>(wl + li * 8);
    float4 wb = *reinterpret_cast<const float4*>(wl + li * 8 + 4);
    float s = v[0] * wa.x + v[1] * wa.y + v[2] * wa.z + v[3] * wa.w
            + v[4] * wb.x + v[5] * wb.y + v[6] * wb.z + v[7] * wb.w;
    s += __shfl_down(s, 16, 64);
    s += __shfl_down(s, 8, 64);
    s += __shfl_down(s, 4, 64);
    s += __shfl_down(s, 2, 64);
    s += __shfl_down(s, 1, 64);
    if (lane == 0) od[r] = s + bl[0];
}

// ---------------------------------------------------------------------------
extern "C" void kernel_launch(void* const* d_in, const int* in_sizes, int n_in,
                              void* d_out, int out_size, void* d_ws, size_t ws_size,
                              hipStream_t stream) {
    const float* x_spot   = (const float*)d_in[0];
    const float* x_city   = (const float*)d_in[1];
    const float* x_word   = (const float*)d_in[2];
    const float* W_att    = (const float*)d_in[3];
    const float* q_att    = (const float*)d_in[4];
    const float* w1[8] = { (const float*)d_in[5], (const float*)d_in[6], (const float*)d_in[7],
                           (const float*)d_in[8], (const float*)d_in[9], (const float*)d_in[10],
                           (const float*)d_in[11], (const float*)d_in[12] };
    const float* w2[8] = { (const float*)d_in[13], (const float*)d_in[14], (const float*)d_in[15],
                           (const float*)d_in[16], (const float*)d_in[17], (const float*)d_in[18],
                           (const float*)d_in[19], (const float*)d_in[20] };
    const float* wl_spot = (const float*)d_in[21];
    const float* wl_city = (const float*)d_in[22];
    const float* wl_word = (const float*)d_in[23];
    const float* bl_spot = (const float*)d_in[24];
    const float* bl_city = (const float*)d_in[25];
    const float* bl_word = (const float*)d_in[26];
    const int* e_has_src   = (const int*)d_in[27];
    const int* e_has_tgt   = (const int*)d_in[28];
    const int* e_in_src    = (const int*)d_in[29];
    const int* e_in_tgt    = (const int*)d_in[30];
    const int* e_desc_src  = (const int*)d_in[31];
    const int* e_desc_tgt  = (const int*)d_in[32];
    const int* e_rdesc_src = (const int*)d_in[33];
    const int* e_rdesc_tgt = (const int*)d_in[34];
    const int E_has   = in_sizes[27];
    const int E_in    = in_sizes[29];
    const int E_desc  = in_sizes[31];
    const int E_rdesc = in_sizes[33];

    float* out = (float*)d_out;
    float* wsf = (float*)d_ws;
    typedef __hip_bfloat16 bf;

    // ---- workspace layout (units of float; bf16 arrays use half) ----
    size_t o = 0;
    auto alloc = [&](size_t nfloats) { float* p = wsf + o; o += (nfloats + 15) & ~(size_t)15; return p; };
    float* wqb       = alloc(2048);
    bf* xs_bf        = (bf*)alloc((size_t)NSPOT * 512 / 2);
    bf* x_city_bf    = (bf*)alloc((size_t)NCITY * 128 / 2);
    bf* x_word_bf    = (bf*)alloc((size_t)NWORD * 320 / 2);
    bf* Wt_att       = (bf*)alloc((size_t)4 * 128 * 512 / 2);
    // L1 transposed weights [N=256][Kp]: 0:has_s 1:SUM(has_t+desc_t) 2:in_s
    // 3:in_t 4:desc_s 5:rdesc_s 6:rdesc_t
    int Kp1[7] = {128, 512, 512, 128, 320, 512, 320};
    bf* Wt1[7];
    for (int i = 0; i < 7; i++) Wt1[i] = (bf*)alloc((size_t)256 * Kp1[i] / 2);
    bf* Wt2[7];
    for (int i = 0; i < 7; i++) Wt2[i] = (bf*)alloc((size_t)256 * 256 / 2);
    float* Ss = alloc((size_t)NSPOT * HID);        // merged has_t+desc_t self term
    float* Sc = alloc((size_t)NCITY * HID);
    float* Sw = alloc((size_t)NWORD * HID);
    float* s1  = alloc((size_t)NSPOT * HID);
    float* c1  = alloc((size_t)NCITY * HID);
    float* wd1 = alloc((size_t)NWORD * HID);
    // region X: xbar (dead after projection GEMM) hosts P_* and the bf16 trio
    size_t regX = o;
    bf* xbar_bf = (bf*)(wsf + regX);                         // 4*NSPOT*512 bf16
    size_t ox = regX;
    auto allocX = [&](size_t nfloats) { float* p = wsf + ox; ox += (nfloats + 15) & ~(size_t)15; return p; };
    bf* P_has_bf   = (bf*)allocX((size_t)NCITY * HID / 2);
    bf* P_in_bf    = (bf*)allocX((size_t)NSPOT * HID / 2);
    bf* P_desc_bf  = (bf*)allocX((size_t)NWORD * HID / 2);
    bf* P_rdesc_bf = (bf*)allocX((size_t)NSPOT * HID / 2);
    bf* s1b = (bf*)allocX((size_t)NSPOT * HID / 2);
    bf* c1b = (bf*)allocX((size_t)NCITY * HID / 2);
    bf* wd1b = (bf*)allocX((size_t)NWORD * HID / 2);
    o = regX + (size_t)4 * NSPOT * 512 / 2;                  // past xbar end
    // CSR ints
    int* wsi = (int*)(wsf + o);
    size_t io = 0;
    int* deg_has    = wsi + io; io += NSPOT;
    int* deg_desc   = wsi + io; io += NSPOT;
    int* deg_in     = wsi + io; io += NCITY;
    int* deg_rdesc  = wsi + io; io += NWORD;
    size_t deg_bytes = io * sizeof(int);
    int* rp_has     = wsi + io; io += NSPOT + 1;
    int* rp_desc    = wsi + io; io += NSPOT + 1;
    int* rp_in      = wsi + io; io += NCITY + 1;
    int* rp_rdesc   = wsi + io; io += NWORD + 1;
    int* cur_has    = wsi + io; io += NSPOT + 1;
    int* cur_desc   = wsi + io; io += NSPOT + 1;
    int* cur_in     = wsi + io; io += NCITY + 1;
    int* cur_rdesc  = wsi + io; io += NWORD + 1;
    int* cs_has     = wsi + io; io += E_has;
    int* cs_desc    = wsi + io; io += E_desc;
    int* cs_in      = wsi + io; io += E_in;
    int* cs_rdesc   = wsi + io; io += E_rdesc;
    (void)ws_size; (void)n_in; (void)out_size;

    // ---- weight transpose-casts + input casts ----
    {
        TDesc8 t{};
        for (int i = 0; i < 4; i++)
            t.d[i] = TDesc{ W_att + (size_t)i * 512 * 128, nullptr,
                            Wt_att + (size_t)i * 128 * 512, 512, 128, 512 };
        hipLaunchKernelGGL(transpose_cast_kernel, dim3(16, 4, 4), dim3(256), 0, stream, t);
    }
    {
        TDesc8 t{};
        t.d[0] = TDesc{ w1[0], nullptr, Wt1[0], 128, 256, 128 };
        t.d[1] = TDesc{ w1[1], w1[5],   Wt1[1], 512, 256, 512 };   // has_t + desc_t
        t.d[2] = TDesc{ w1[2], nullptr, Wt1[2], 512, 256, 512 };
        t.d[3] = TDesc{ w1[3], nullptr, Wt1[3], 128, 256, 128 };
        t.d[4] = TDesc{ w1[4], nullptr, Wt1[4], 300, 256, 320 };
        t.d[5] = TDesc{ w1[6], nullptr, Wt1[5], 512, 256, 512 };
        t.d[6] = TDesc{ w1[7], nullptr, Wt1[6], 300, 256, 320 };
        hipLaunchKernelGGL(transpose_cast_kernel, dim3(16, 8, 8), dim3(256), 0, stream, t);
    }
    {
        TDesc8 t{};
        t.d[0] = TDesc{ w2[0], nullptr, Wt2[0], 256, 256, 256 };
        t.d[1] = TDesc{ w2[1], w2[5],   Wt2[1], 256, 256, 256 };   // has_t + desc_t
        t.d[2] = TDesc{ w2[2], nullptr, Wt2[2], 256, 256, 256 };
        t.d[3] = TDesc{ w2[3], nullptr, Wt2[3], 256, 256, 256 };
        t.d[4] = TDesc{ w2[4], nullptr, Wt2[4], 256, 256, 256 };
        t.d[5] = TDesc{ w2[6], nullptr, Wt2[5], 256, 256, 256 };
        t.d[6] = TDesc{ w2[7], nullptr, Wt2[6], 256, 256, 256 };
        hipLaunchKernelGGL(transpose_cast_kernel, dim3(8, 8, 8), dim3(256), 0, stream, t);
    }
    hipLaunchKernelGGL(cast_kernel, dim3((NCITY * 128 + 255) / 256), dim3(256), 0, stream,
                       x_city, x_city_bf, NCITY * 128);
    hipLaunchKernelGGL(cast_pad_kernel, dim3((NWORD * 320 + 255) / 256), dim3(256), 0, stream,
                       x_word, x_word_bf, NWORD, 300, 320);

    // ---- fused CSR build (reused by both layers) ----
    EdgeDesc4 ed;
    ed.d[0] = EdgeDesc{ e_has_src,   e_has_tgt,   E_has,   NSPOT, deg_has,   rp_has,   cur_has,   cs_has };
    ed.d[1] = EdgeDesc{ e_desc_src,  e_desc_tgt,  E_desc,  NSPOT, deg_desc,  rp_desc,  cur_desc,  cs_desc };
    ed.d[2] = EdgeDesc{ e_in_src,    e_in_tgt,    E_in,    NCITY, deg_in,    rp_in,    cur_in,    cs_in };
    ed.d[3] = EdgeDesc{ e_rdesc_src, e_rdesc_tgt, E_rdesc, NWORD, deg_rdesc, rp_rdesc, cur_rdesc, cs_rdesc };
    int Emax = E_has;
    if (E_desc > Emax) Emax = E_desc;
    if (E_in > Emax) Emax = E_in;
    if (E_rdesc > Emax) Emax = E_rdesc;
    hipMemsetAsync((void*)deg_has, 0, deg_bytes, stream);
    hipLaunchKernelGGL(hist4_kernel, dim3((Emax + 255) / 256, 4), dim3(256), 0, stream, ed);
    hipLaunchKernelGGL(scan4_kernel, dim3(4), dim3(256), 0, stream, ed);
    hipLaunchKernelGGL(fill4_kernel, dim3((Emax + 255) / 256, 4), dim3(256), 0, stream, ed);

    // ---- attention ----
    hipLaunchKernelGGL(wq_kernel, dim3(8), dim3(256), 0, stream, W_att, q_att, wqb);
    hipLaunchKernelGGL(attn_kernel, dim3(NSPOT), dim3(256), 0, stream, x_spot, wqb, xbar_bf);

    int gx = (NSPOT + 127) / 128;   // 157

    // projection: 4 heads as a grouped GEMM (N=128)
    {
        GemmDesc8 gd{};
        for (int h = 0; h < 4; h++)
            gd.d[h] = GemmDesc{ xbar_bf + (size_t)h * NSPOT * 512, Wt_att + (size_t)h * 128 * 512,
                                nullptr, xs_bf + h * 128, 512, 512, 0, 512, NSPOT, 512, 128 };
        hipLaunchKernelGGL(gemm_grouped, dim3(gx, 1, 4), dim3(256), 0, stream, gd);
    }

    // ---- layer 1 GEMMs (one grouped launch, 7 groups) ----
    {
        GemmDesc8 gd{};
        gd.d[0] = GemmDesc{ x_city_bf, Wt1[0], nullptr, P_has_bf,   128, 128, 0, HID, NCITY, 128, HID };
        gd.d[1] = GemmDesc{ xs_bf,     Wt1[1], Ss,      nullptr,    512, 512, HID, 0, NSPOT, 512, HID };
        gd.d[2] = GemmDesc{ xs_bf,     Wt1[2], nullptr, P_in_bf,    512, 512, 0, HID, NSPOT, 512, HID };
        gd.d[3] = GemmDesc{ x_city_bf, Wt1[3], Sc,      nullptr,    128, 128, HID, 0, NCITY, 128, HID };
        gd.d[4] = GemmDesc{ x_word_bf, Wt1[4], nullptr, P_desc_bf,  320, 320, 0, HID, NWORD, 320, HID };
        gd.d[5] = GemmDesc{ xs_bf,     Wt1[5], nullptr, P_rdesc_bf, 512, 512, 0, HID, NSPOT, 512, HID };
        gd.d[6] = GemmDesc{ x_word_bf, Wt1[6], Sw,      nullptr,    320, 320, HID, 0, NWORD, 320, HID };
        gd.d[7].M = 0; gd.d[7].N = 0;
        hipLaunchKernelGGL(gemm_grouped, dim3(gx, 2, 8), dim3(256), 0, stream, gd);
    }

    // ---- layer 1 fused aggregation + combine ----
    int rows3 = NSPOT + NCITY + NWORD;
    hipLaunchKernelGGL(fused_ac1_kernel, dim3((rows3 + 3) / 4), dim3(256), 0, stream,
                       P_has_bf, rp_has, cs_has, P_desc_bf, rp_desc, cs_desc,
                       P_in_bf, rp_in, cs_in, P_rdesc_bf, rp_rdesc, cs_rdesc,
                       Ss, Sc, Sw, s1, s1b, c1, c1b, wd1, wd1b);

    // ---- layer 2 GEMMs (one grouped launch, 7 groups) ----
    {
        GemmDesc8 gd{};
        gd.d[0] = GemmDesc{ c1b,  Wt2[0], nullptr, P_has_bf,   HID, HID, 0, HID, NCITY, HID, HID };
        gd.d[1] = GemmDesc{ s1b,  Wt2[1], Ss,      nullptr,    HID, HID, HID, 0, NSPOT, HID, HID };
        gd.d[2] = GemmDesc{ s1b,  Wt2[2], nullptr, P_in_bf,    HID, HID, 0, HID, NSPOT, HID, HID };
        gd.d[3] = GemmDesc{ c1b,  Wt2[3], Sc,      nullptr,    HID, HID, HID, 0, NCITY, HID, HID };
        gd.d[4] = GemmDesc{ wd1b, Wt2[4], nullptr, P_desc_bf,  HID, HID, 0, HID, NWORD, HID, HID };
        gd.d[5] = GemmDesc{ s1b,  Wt2[5], nullptr, P_rdesc_bf, HID, HID, 0, HID, NSPOT, HID, HID };
        gd.d[6] = GemmDesc{ wd1b, Wt2[6], Sw,      nullptr,    HID, HID, HID, 0, NWORD, HID, HID };
        gd.d[7].M = 0; gd.d[7].N = 0;
        hipLaunchKernelGGL(gemm_grouped, dim3(gx, 2, 8), dim3(256), 0, stream, gd);
    }

    // ---- layer 2 fused aggregation + combine + mean + rowdot ----
    float* out0 = out;
    float* out1 = out + (size_t)NSPOT * HID;
    float* out2 = out1 + (size_t)NCITY * HID;
    float* out3 = out2 + (size_t)NWORD * HID;
    float* out4 = out3 + NSPOT;
    float* out5 = out4 + NCITY;
    hipLaunchKernelGGL(fused_finale_kernel, dim3((rows3 + 3) / 4), dim3(256), 0, stream,
                       P_has_bf, rp_has, cs_has, P_desc_bf, rp_desc, cs_desc,
                       P_in_bf, rp_in, cs_in, P_rdesc_bf, rp_rdesc, cs_rdesc,
                       Ss, Sc, Sw, s1, c1, wd1,
                       out0, wl_spot, bl_spot, out3,
                       out1, wl_city, bl_city, out4,
                       out2, wl_word, bl_word, out5);
}

// Round 8
// 835.092 us; speedup vs baseline: 1.5235x; 1.0044x over previous
//
#include <hip/hip_runtime.h>
#include <hip/hip_bf16.h>

#define HID 256
#define NSPOT 20000
#define NCITY 2000
#define NWORD 20000

typedef __attribute__((ext_vector_type(8))) short bhalf8;
typedef __attribute__((ext_vector_type(4))) float floatx4;
typedef __attribute__((ext_vector_type(8))) unsigned short ushortx8;

__device__ inline float bf2f(unsigned short u) {
    union { unsigned int i; float f; } v; v.i = (unsigned int)u << 16; return v.f;
}
__device__ inline unsigned short f2bf(float f) {
    __hip_bfloat16 b = __float2bfloat16(f);
    return *reinterpret_cast<unsigned short*>(&b);
}
__device__ inline float4 ld4(const float* p, size_t off) {
    return *reinterpret_cast<const float4*>(p + off);
}

// ---------------------------------------------------------------------------
// wq[h][i] = sum_o W_att[h][i][o] * q_att[h][o]
__global__ void wq_kernel(const float* __restrict__ W, const float* __restrict__ q,
                          float* __restrict__ wq) {
    int idx = blockIdx.x * 256 + threadIdx.x;   // 4*512 = 2048
    if (idx >= 2048) return;
    int h = idx >> 9, i = idx & 511;
    const float* Wr = W + ((size_t)h * 512 + i) * 128;
    const float* qr = q + h * 128;
    float s = 0.f;
    #pragma unroll 4
    for (int o = 0; o < 128; o++) s += Wr[o] * qr[o];
    wq[idx] = s;
}

// ---------------------------------------------------------------------------
// Per-node attention: scores via wave-reduction, softmax, blend -> xbar bf16.
__global__ __launch_bounds__(256) void attn_kernel(const float* __restrict__ x,
                                                   const float* __restrict__ wq,
                                                   __hip_bfloat16* __restrict__ xbar) {
    __shared__ float xl[2560];
    __shared__ float al[4][8];
    int n = blockIdx.x;
    int tid = threadIdx.x;
    int wave = tid >> 6, lane = tid & 63;
    const float4* xr4 = (const float4*)(x + (size_t)n * 2560);
    for (int i = tid; i < 640; i += 256) ((float4*)xl)[i] = xr4[i];
    __syncthreads();
    const float* wqh = wq + wave * 512;
    for (int s = 0; s < 5; s++) {
        float a = 0.f;
        #pragma unroll
        for (int j = 0; j < 8; j++)
            a += xl[s * 512 + lane + j * 64] * wqh[lane + j * 64];
        #pragma unroll
        for (int off = 32; off > 0; off >>= 1) a += __shfl_down(a, off, 64);
        if (lane == 0) al[wave][s] = a;
    }
    __syncthreads();
    if (tid < 4) {
        float z[5]; float m = -1e30f;
        #pragma unroll
        for (int s = 0; s < 5; s++) {
            float v = al[tid][s];
            v = (v >= 0.f) ? v : 0.2f * v;    // leaky_relu 0.2
            z[s] = v; m = fmaxf(m, v);
        }
        float e[5]; float sum = 0.f;
        #pragma unroll
        for (int s = 0; s < 5; s++) { e[s] = __expf(z[s] - m); sum += e[s]; }
        float r = 1.f / sum;
        #pragma unroll
        for (int s = 0; s < 5; s++) al[tid][s] = e[s] * r;
    }
    __syncthreads();
    float a0 = al[wave][0], a1 = al[wave][1], a2 = al[wave][2], a3 = al[wave][3], a4 = al[wave][4];
    __hip_bfloat16* xo = xbar + ((size_t)wave * NSPOT + n) * 512;
    #pragma unroll
    for (int j = 0; j < 8; j++) {
        int i = lane + j * 64;
        float v = a0 * xl[i] + a1 * xl[512 + i] + a2 * xl[1024 + i] + a3 * xl[1536 + i] + a4 * xl[2048 + i];
        xo[i] = __float2bfloat16(v);
    }
}

// ---------------------------------------------------------------------------
// Grouped bf16 MFMA GEMM: per-group C[M,N] = A[M,K] @ Bt[N,K]^T, N in {128,256}.
// 128x128 tile, 4 waves (64x64 each as 4x4 of 16x16), K%32==0.  Reg-staged
// LDS KP=40 (80B stride: 2-way bank aliasing = free).  Harness-proven.
#define KP 40
struct GemmDesc {
    const __hip_bfloat16* A;
    const __hip_bfloat16* Bt;
    float* C;
    __hip_bfloat16* Cb;
    int lda, ldb, ldc, ldcb, M, K, N;
};
struct GemmDesc8 { GemmDesc d[8]; };

__global__ __launch_bounds__(256) void gemm_grouped(GemmDesc8 descs) {
    GemmDesc g = descs.d[blockIdx.z];
    int rowbase = blockIdx.x * 128;
    int colbase = blockIdx.y * 128;
    if (rowbase >= g.M || colbase >= g.N) return;   // block-uniform early-exit
    __shared__ short As[128 * KP];
    __shared__ short Bs[128 * KP];
    int tid = threadIdx.x;
    int wave = tid >> 6, lane = tid & 63;
    int wr = wave & 1, wc = wave >> 1;
    int quad = lane >> 4, l16 = lane & 15;
    int srow = tid >> 2;            // 0..63
    int skoff = (tid & 3) * 8;      // 0,8,16,24
    const __hip_bfloat16* A = g.A;
    const __hip_bfloat16* Bt = g.Bt;
    int lda = g.lda, ldb = g.ldb, M = g.M, K = g.K;
    floatx4 acc[4][4];
    #pragma unroll
    for (int i = 0; i < 4; i++)
        #pragma unroll
        for (int j = 0; j < 4; j++)
            acc[i][j] = (floatx4){0.f, 0.f, 0.f, 0.f};

    for (int k0 = 0; k0 < K; k0 += 32) {
        #pragma unroll
        for (int i = 0; i < 2; i++) {
            int r = srow + i * 64;
            int gr = rowbase + r;
            int4 va = make_int4(0, 0, 0, 0);
            if (gr < M) va = *(const int4*)(A + (size_t)gr * lda + k0 + skoff);
            *(int4*)(As + r * KP + skoff) = va;
            int4 vb = *(const int4*)(Bt + (size_t)(colbase + r) * ldb + k0 + skoff);
            *(int4*)(Bs + r * KP + skoff) = vb;
        }
        __syncthreads();
        bhalf8 af[4], bfr[4];
        #pragma unroll
        for (int rt = 0; rt < 4; rt++)
            af[rt] = *(const bhalf8*)(As + (wr * 64 + rt * 16 + l16) * KP + quad * 8);
        #pragma unroll
        for (int ct = 0; ct < 4; ct++)
            bfr[ct] = *(const bhalf8*)(Bs + (wc * 64 + ct * 16 + l16) * KP + quad * 8);
        #pragma unroll
        for (int rt = 0; rt < 4; rt++)
            #pragma unroll
            for (int ct = 0; ct < 4; ct++)
                acc[rt][ct] = __builtin_amdgcn_mfma_f32_16x16x32_bf16(af[rt], bfr[ct], acc[rt][ct], 0, 0, 0);
        __syncthreads();
    }
    #pragma unroll
    for (int rt = 0; rt < 4; rt++) {
        #pragma unroll
        for (int r = 0; r < 4; r++) {
            int grow = rowbase + wr * 64 + rt * 16 + quad * 4 + r;
            if (grow < M) {
                #pragma unroll
                for (int ct = 0; ct < 4; ct++) {
                    int gcol = colbase + wc * 64 + ct * 16 + l16;
                    float v = acc[rt][ct][r];
                    if (g.C)  g.C[(size_t)grow * g.ldc + gcol] = v;
                    if (g.Cb) g.Cb[(size_t)grow * g.ldcb + gcol] = __float2bfloat16(v);
                }
            }
        }
    }
}

// ---------------------------------------------------------------------------
// Batched transpose-cast: in fp32 [K][N] (+optional in2, summed) -> bf16
// [N][Kp], zero-pad K..Kp.
struct TDesc { const float* in; const float* in2; __hip_bfloat16* out; int K; int N; int Kp; };
struct TDesc8 { TDesc d[8]; };
__global__ void transpose_cast_kernel(TDesc8 descs) {
    TDesc dsc = descs.d[blockIdx.z];
    __shared__ float tile[32][33];
    int k0 = blockIdx.x * 32, n0 = blockIdx.y * 32;
    if (k0 >= dsc.Kp || n0 >= dsc.N) return;
    int tn = threadIdx.x & 31, t8 = threadIdx.x >> 5;
    #pragma unroll
    for (int i = 0; i < 4; i++) {
        int k = k0 + t8 * 4 + i;
        float v = 0.f;
        if (k < dsc.K && n0 + tn < dsc.N) {
            v = dsc.in[(size_t)k * dsc.N + n0 + tn];
            if (dsc.in2) v += dsc.in2[(size_t)k * dsc.N + n0 + tn];
        }
        tile[t8 * 4 + i][tn] = v;
    }
    __syncthreads();
    int kk = threadIdx.x & 31, n8 = threadIdx.x >> 5;
    #pragma unroll
    for (int i = 0; i < 4; i++) {
        int n = n0 + n8 * 4 + i;
        int k = k0 + kk;
        if (n < dsc.N && k < dsc.Kp)
            dsc.out[(size_t)n * dsc.Kp + k] = __float2bfloat16(tile[kk][n8 * 4 + i]);
    }
}

// cast fp32 -> bf16 (flat)
__global__ void cast_kernel(const float* __restrict__ in, __hip_bfloat16* __restrict__ out, int n) {
    int i = blockIdx.x * 256 + threadIdx.x;
    if (i < n) out[i] = __float2bfloat16(in[i]);
}

// cast fp32 [rows][K] -> bf16 [rows][Kp] zero-padded
__global__ void cast_pad_kernel(const float* __restrict__ in, __hip_bfloat16* __restrict__ out,
                                int rows, int K, int Kp) {
    int idx = blockIdx.x * 256 + threadIdx.x;
    if (idx >= rows * Kp) return;
    int r = idx / Kp, k = idx - r * Kp;
    out[idx] = (k < K) ? __float2bfloat16(in[(size_t)r * K + k]) : __float2bfloat16(0.f);
}

// ---------------------------------------------------------------------------
// Fused CSR build for all 4 edge types: histogram -> scan(+cursor) -> fill
struct EdgeDesc { const int* src; const int* tgt; int E; int n;
                  int* deg; int* rp; int* cur; int* cs; };
struct EdgeDesc4 { EdgeDesc d[4]; };

__global__ void hist4_kernel(EdgeDesc4 ds) {
    EdgeDesc d = ds.d[blockIdx.y];
    int e = blockIdx.x * 256 + threadIdx.x;
    if (e < d.E) atomicAdd(&d.deg[d.tgt[e]], 1);
}

__global__ void scan4_kernel(EdgeDesc4 ds) {
    EdgeDesc dd = ds.d[blockIdx.x];
    __shared__ int partx[257];
    __shared__ int part[256];
    int tid = threadIdx.x;
    int n = dd.n;
    int chunk = (n + 255) / 256;
    int lo = tid * chunk;
    int hi = lo + chunk; if (hi > n) hi = n;
    int s = 0;
    for (int i = lo; i < hi; i++) s += dd.deg[i];
    part[tid] = s;
    __syncthreads();
    if (tid == 0) {
        int acc = 0;
        for (int i = 0; i < 256; i++) { partx[i] = acc; acc += part[i]; }
        partx[256] = acc;
    }
    __syncthreads();
    int acc = partx[tid];
    for (int i = lo; i < hi; i++) { dd.rp[i] = acc; dd.cur[i] = acc; acc += dd.deg[i]; }
    if (tid == 0) dd.rp[n] = partx[256];
}

__global__ void fill4_kernel(EdgeDesc4 ds) {
    EdgeDesc d = ds.d[blockIdx.y];
    int e = blockIdx.x * 256 + threadIdx.x;
    if (e >= d.E) return;
    int t = d.tgt[e];
    int pos = atomicAdd(&d.cur[t], 1);
    d.cs[pos] = d.src[e];
}

// ---------------------------------------------------------------------------
// Segment mean, half-wave-per-edge (round-6 proven structure, 4-deep unroll):
// 32 lanes x ushort8 (16B) cover one 512B message row; half=0 takes even CSR
// slots, half=1 odd.  4 independent row loads in flight per half (8/wave).
// shfl_down(32) merges halves; lanes 0..31 hold the 8-dims/lane result.
__device__ inline void seg_mean8(const __hip_bfloat16* __restrict__ msg,
                                 const int* __restrict__ rp, const int* __restrict__ cs,
                                 int t, int half, int li, float a[8]) {
    int lo = rp[t], hi = rp[t + 1];
    #pragma unroll
    for (int j = 0; j < 8; j++) a[j] = 0.f;
    int col = li * 8;
    int i = lo + half;
    for (; i + 6 < hi; i += 8) {
        int s0 = cs[i], s1 = cs[i + 2], s2 = cs[i + 4], s3 = cs[i + 6];
        ushortx8 u0 = *(const ushortx8*)(msg + (size_t)s0 * HID + col);
        ushortx8 u1 = *(const ushortx8*)(msg + (size_t)s1 * HID + col);
        ushortx8 u2 = *(const ushortx8*)(msg + (size_t)s2 * HID + col);
        ushortx8 u3 = *(const ushortx8*)(msg + (size_t)s3 * HID + col);
        #pragma unroll
        for (int k = 0; k < 8; k++)
            a[k] += (bf2f(u0[k]) + bf2f(u1[k])) + (bf2f(u2[k]) + bf2f(u3[k]));
    }
    for (; i < hi; i += 2) {
        int s0 = cs[i];
        ushortx8 u = *(const ushortx8*)(msg + (size_t)s0 * HID + col);
        #pragma unroll
        for (int k = 0; k < 8; k++) a[k] += bf2f(u[k]);
    }
    #pragma unroll
    for (int j = 0; j < 8; j++) a[j] += __shfl_down(a[j], 32, 64);
    float inv = 1.f / fmaxf((float)(hi - lo), 1.f);
    #pragma unroll
    for (int j = 0; j < 8; j++) a[j] *= inv;
}

// ---------------------------------------------------------------------------
// Layer-1 fused: segment-mean gathers + combine + ReLU + bf16 store only
// (the fp32 copy is never needed: finale re-reads the bf16 version).
__global__ __launch_bounds__(256) void fused_ac1_kernel(
    const __hip_bfloat16* __restrict__ Phas,   const int* __restrict__ rp_has,   const int* __restrict__ cs_has,
    const __hip_bfloat16* __restrict__ Pdesc,  const int* __restrict__ rp_desc,  const int* __restrict__ cs_desc,
    const __hip_bfloat16* __restrict__ Pin,    const int* __restrict__ rp_in,    const int* __restrict__ cs_in,
    const __hip_bfloat16* __restrict__ Prdesc, const int* __restrict__ rp_rdesc, const int* __restrict__ cs_rdesc,
    const float* __restrict__ Ss, const float* __restrict__ Sc, const float* __restrict__ Sw,
    __hip_bfloat16* __restrict__ s1b, __hip_bfloat16* __restrict__ c1b,
    __hip_bfloat16* __restrict__ wd1b) {
    int row = blockIdx.x * 4 + (threadIdx.x >> 6);
    if (row >= NSPOT + NCITY + NWORD) return;
    int lane = threadIdx.x & 63;
    int half = lane >> 5, li = lane & 31;
    float v[8]; __hip_bfloat16* ob; size_t off;
    if (row < NSPOT) {
        float mh[8], md[8];
        seg_mean8(Phas, rp_has, cs_has, row, half, li, mh);
        seg_mean8(Pdesc, rp_desc, cs_desc, row, half, li, md);
        off = (size_t)row * HID + li * 8;
        float4 sa = ld4(Ss, off), sb = ld4(Ss, off + 4);
        v[0] = fmaxf((sa.x + mh[0] + md[0]) * 0.5f, 0.f);
        v[1] = fmaxf((sa.y + mh[1] + md[1]) * 0.5f, 0.f);
        v[2] = fmaxf((sa.z + mh[2] + md[2]) * 0.5f, 0.f);
        v[3] = fmaxf((sa.w + mh[3] + md[3]) * 0.5f, 0.f);
        v[4] = fmaxf((sb.x + mh[4] + md[4]) * 0.5f, 0.f);
        v[5] = fmaxf((sb.y + mh[5] + md[5]) * 0.5f, 0.f);
        v[6] = fmaxf((sb.z + mh[6] + md[6]) * 0.5f, 0.f);
        v[7] = fmaxf((sb.w + mh[7] + md[7]) * 0.5f, 0.f);
        ob = s1b;
    } else if (row < NSPOT + NCITY) {
        int r = row - NSPOT;
        float mi[8];
        seg_mean8(Pin, rp_in, cs_in, r, half, li, mi);
        off = (size_t)r * HID + li * 8;
        float4 sa = ld4(Sc, off), sb = ld4(Sc, off + 4);
        v[0] = fmaxf(sa.x + mi[0], 0.f); v[1] = fmaxf(sa.y + mi[1], 0.f);
        v[2] = fmaxf(sa.z + mi[2], 0.f); v[3] = fmaxf(sa.w + mi[3], 0.f);
        v[4] = fmaxf(sb.x + mi[4], 0.f); v[5] = fmaxf(sb.y + mi[5], 0.f);
        v[6] = fmaxf(sb.z + mi[6], 0.f); v[7] = fmaxf(sb.w + mi[7], 0.f);
        ob = c1b;
    } else {
        int r = row - NSPOT - NCITY;
        float mr[8];
        seg_mean8(Prdesc, rp_rdesc, cs_rdesc, r, half, li, mr);
        off = (size_t)r * HID + li * 8;
        float4 sa = ld4(Sw, off), sb = ld4(Sw, off + 4);
        v[0] = fmaxf(sa.x + mr[0], 0.f); v[1] = fmaxf(sa.y + mr[1], 0.f);
        v[2] = fmaxf(sa.z + mr[2], 0.f); v[3] = fmaxf(sa.w + mr[3], 0.f);
        v[4] = fmaxf(sb.x + mr[4], 0.f); v[5] = fmaxf(sb.y + mr[5], 0.f);
        v[6] = fmaxf(sb.z + mr[6], 0.f); v[7] = fmaxf(sb.w + mr[7], 0.f);
        ob = wd1b;
    }
    if (half == 0) {
        ushortx8 ub;
        #pragma unroll
        for (int j = 0; j < 8; j++) ub[j] = f2bf(v[j]);
        *reinterpret_cast<ushortx8*>((unsigned short*)ob + off) = ub;
    }
}

// ---------------------------------------------------------------------------
// Layer-2 fused finale: gathers + combine + (l1+l2)/2 mean + rowdot head.
// Layer-1 values come from the bf16 arrays (s1b/c1b/wd1b).
__global__ __launch_bounds__(256) void fused_finale_kernel(
    const __hip_bfloat16* __restrict__ Phas,   const int* __restrict__ rp_has,   const int* __restrict__ cs_has,
    const __hip_bfloat16* __restrict__ Pdesc,  const int* __restrict__ rp_desc,  const int* __restrict__ cs_desc,
    const __hip_bfloat16* __restrict__ Pin,    const int* __restrict__ rp_in,    const int* __restrict__ cs_in,
    const __hip_bfloat16* __restrict__ Prdesc, const int* __restrict__ rp_rdesc, const int* __restrict__ cs_rdesc,
    const float* __restrict__ Ss, const float* __restrict__ Sc, const float* __restrict__ Sw,
    const __hip_bfloat16* __restrict__ s1b, const __hip_bfloat16* __restrict__ c1b,
    const __hip_bfloat16* __restrict__ wd1b,
    float* __restrict__ out0, const float* __restrict__ wls, const float* __restrict__ bls, float* __restrict__ out3,
    float* __restrict__ out1, const float* __restrict__ wlc, const float* __restrict__ blc, float* __restrict__ out4,
    float* __restrict__ out2, const float* __restrict__ wlw, const float* __restrict__ blw, float* __restrict__ out5) {
    int row = blockIdx.x * 4 + (threadIdx.x >> 6);
    if (row >= NSPOT + NCITY + NWORD) return;
    int lane = threadIdx.x & 63;
    int half = lane >> 5, li = lane & 31;
    float v[8]; const __hip_bfloat16* pl; const float* wl; const float* bl;
    float* om; float* od;
    int r; size_t off;
    if (row < NSPOT) {
        r = row;
        float mh[8], md[8];
        seg_mean8(Phas, rp_has, cs_has, r, half, li, mh);
        seg_mean8(Pdesc, rp_desc, cs_desc, r, half, li, md);
        off = (size_t)r * HID + li * 8;
        float4 sa = ld4(Ss, off), sb = ld4(Ss, off + 4);
        v[0] = fmaxf((sa.x + mh[0] + md[0]) * 0.5f, 0.f);
        v[1] = fmaxf((sa.y + mh[1] + md[1]) * 0.5f, 0.f);
        v[2] = fmaxf((sa.z + mh[2] + md[2]) * 0.5f, 0.f);
        v[3] = fmaxf((sa.w + mh[3] + md[3]) * 0.5f, 0.f);
        v[4] = fmaxf((sb.x + mh[4] + md[4]) * 0.5f, 0.f);
        v[5] = fmaxf((sb.y + mh[5] + md[5]) * 0.5f, 0.f);
        v[6] = fmaxf((sb.z + mh[6] + md[6]) * 0.5f, 0.f);
        v[7] = fmaxf((sb.w + mh[7] + md[7]) * 0.5f, 0.f);
        pl = s1b; wl = wls; bl = bls; om = out0; od = out3;
    } else if (row < NSPOT + NCITY) {
        r = row - NSPOT;
        float mi[8];
        seg_mean8(Pin, rp_in, cs_in, r, half, li, mi);
        off = (size_t)r * HID + li * 8;
        float4 sa = ld4(Sc, off), sb = ld4(Sc, off + 4);
        v[0] = fmaxf(sa.x + mi[0], 0.f); v[1] = fmaxf(sa.y + mi[1], 0.f);
        v[2] = fmaxf(sa.z + mi[2], 0.f); v[3] = fmaxf(sa.w + mi[3], 0.f);
        v[4] = fmaxf(sb.x + mi[4], 0.f); v[5] = fmaxf(sb.y + mi[5], 0.f);
        v[6] = fmaxf(sb.z + mi[6], 0.f); v[7] = fmaxf(sb.w + mi[7], 0.f);
        pl = c1b; wl = wlc; bl = blc; om = out1; od = out4;
    } else {
        r = row - NSPOT - NCITY;
        float mr[8];
        seg_mean8(Prdesc, rp_rdesc, cs_rdesc, r, half, li, mr);
        off = (size_t)r * HID + li * 8;
        float4 sa = ld4(Sw, off), sb = ld4(Sw, off + 4);
        v[0] = fmaxf(sa.x + mr[0], 0.f); v[1] = fmaxf(sa.y + mr[1], 0.f);
        v[2] = fmaxf(sa.z + mr[2], 0.f); v[3] = fmaxf(sa.w + mr[3], 0.f);
        v[4] = fmaxf(sb.x + mr[4], 0.f); v[5] = fmaxf(sb.y + mr[5], 0.f);
        v[6] = fmaxf(sb.z + mr[6], 0.f); v[7] = fmaxf(sb.w + mr[7], 0.f);
        pl = wd1b; wl = wlw; bl = blw; om = out2; od = out5;
    }
    // mean with layer-1 output (bf16 source); stores on lanes 0..31 only
    ushortx8 up = *(const ushortx8*)((const unsigned short*)pl + off);
    if (half == 0) {
        *reinterpret_cast<float4*>(om + off) =
            make_float4((bf2f(up[0]) + v[0]) * 0.5f, (bf2f(up[1]) + v[1]) * 0.5f,
                        (bf2f(up[2]) + v[2]) * 0.5f, (bf2f(up[3]) + v[3]) * 0.5f);
        *reinterpret_cast<float4*>(om + off + 4) =
            make_float4((bf2f(up[4]) + v[4]) * 0.5f, (bf2f(up[5]) + v[5]) * 0.5f,
                        (bf2f(up[6]) + v[6]) * 0.5f, (bf2f(up[7]) + v[7]) * 0.5f);
    }
    // rowdot over 256 dims held 8-per-lane on lanes 0..31
    float4 wa = *reinterpret_cast<const float4*>(wl + li * 8);
    float4 wb = *reinterpret_cast<const float4*>(wl + li * 8 + 4);
    float s = v[0] * wa.x + v[1] * wa.y + v[2] * wa.z + v[3] * wa.w
            + v[4] * wb.x + v[5] * wb.y + v[6] * wb.z + v[7] * wb.w;
    s += __shfl_down(s, 16, 64);
    s += __shfl_down(s, 8, 64);
    s += __shfl_down(s, 4, 64);
    s += __shfl_down(s, 2, 64);
    s += __shfl_down(s, 1, 64);
    if (lane == 0) od[r] = s + bl[0];
}

// ---------------------------------------------------------------------------
extern "C" void kernel_launch(void* const* d_in, const int* in_sizes, int n_in,
                              void* d_out, int out_size, void* d_ws, size_t ws_size,
                              hipStream_t stream) {
    const float* x_spot   = (const float*)d_in[0];
    const float* x_city   = (const float*)d_in[1];
    const float* x_word   = (const float*)d_in[2];
    const float* W_att    = (const float*)d_in[3];
    const float* q_att    = (const float*)d_in[4];
    const float* w1[8] = { (const float*)d_in[5], (const float*)d_in[6], (const float*)d_in[7],
                           (const float*)d_in[8], (const float*)d_in[9], (const float*)d_in[10],
                           (const float*)d_in[11], (const float*)d_in[12] };
    const float* w2[8] = { (const float*)d_in[13], (const float*)d_in[14], (const float*)d_in[15],
                           (const float*)d_in[16], (const float*)d_in[17], (const float*)d_in[18],
                           (const float*)d_in[19], (const float*)d_in[20] };
    const float* wl_spot = (const float*)d_in[21];
    const float* wl_city = (const float*)d_in[22];
    const float* wl_word = (const float*)d_in[23];
    const float* bl_spot = (const float*)d_in[24];
    const float* bl_city = (const float*)d_in[25];
    const float* bl_word = (const float*)d_in[26];
    const int* e_has_src   = (const int*)d_in[27];
    const int* e_has_tgt   = (const int*)d_in[28];
    const int* e_in_src    = (const int*)d_in[29];
    const int* e_in_tgt    = (const int*)d_in[30];
    const int* e_desc_src  = (const int*)d_in[31];
    const int* e_desc_tgt  = (const int*)d_in[32];
    const int* e_rdesc_src = (const int*)d_in[33];
    const int* e_rdesc_tgt = (const int*)d_in[34];
    const int E_has   = in_sizes[27];
    const int E_in    = in_sizes[29];
    const int E_desc  = in_sizes[31];
    const int E_rdesc = in_sizes[33];

    float* out = (float*)d_out;
    float* wsf = (float*)d_ws;
    typedef __hip_bfloat16 bf;

    // ---- workspace layout (units of float; bf16 arrays use half) ----
    size_t o = 0;
    auto alloc = [&](size_t nfloats) { float* p = wsf + o; o += (nfloats + 15) & ~(size_t)15; return p; };
    float* wqb       = alloc(2048);
    bf* xs_bf        = (bf*)alloc((size_t)NSPOT * 512 / 2);
    bf* x_city_bf    = (bf*)alloc((size_t)NCITY * 128 / 2);
    bf* x_word_bf    = (bf*)alloc((size_t)NWORD * 320 / 2);
    bf* Wt_att       = (bf*)alloc((size_t)4 * 128 * 512 / 2);
    // L1 transposed weights [N=256][Kp]: 0:has_s 1:SUM(has_t+desc_t) 2:in_s
    // 3:in_t 4:desc_s 5:rdesc_s 6:rdesc_t
    int Kp1[7] = {128, 512, 512, 128, 320, 512, 320};
    bf* Wt1[7];
    for (int i = 0; i < 7; i++) Wt1[i] = (bf*)alloc((size_t)256 * Kp1[i] / 2);
    bf* Wt2[7];
    for (int i = 0; i < 7; i++) Wt2[i] = (bf*)alloc((size_t)256 * 256 / 2);
    float* Ss = alloc((size_t)NSPOT * HID);        // merged has_t+desc_t self term
    float* Sc = alloc((size_t)NCITY * HID);
    float* Sw = alloc((size_t)NWORD * HID);
    // region X: xbar (dead after projection GEMM) hosts P_* and the bf16 trio
    size_t regX = o;
    bf* xbar_bf = (bf*)(wsf + regX);                         // 4*NSPOT*512 bf16
    size_t ox = regX;
    auto allocX = [&](size_t nfloats) { float* p = wsf + ox; ox += (nfloats + 15) & ~(size_t)15; return p; };
    bf* P_has_bf   = (bf*)allocX((size_t)NCITY * HID / 2);
    bf* P_in_bf    = (bf*)allocX((size_t)NSPOT * HID / 2);
    bf* P_desc_bf  = (bf*)allocX((size_t)NWORD * HID / 2);
    bf* P_rdesc_bf = (bf*)allocX((size_t)NSPOT * HID / 2);
    bf* s1b = (bf*)allocX((size_t)NSPOT * HID / 2);
    bf* c1b = (bf*)allocX((size_t)NCITY * HID / 2);
    bf* wd1b = (bf*)allocX((size_t)NWORD * HID / 2);
    o = regX + (size_t)4 * NSPOT * 512 / 2;                  // past xbar end
    // CSR ints
    int* wsi = (int*)(wsf + o);
    size_t io = 0;
    int* deg_has    = wsi + io; io += NSPOT;
    int* deg_desc   = wsi + io; io += NSPOT;
    int* deg_in     = wsi + io; io += NCITY;
    int* deg_rdesc  = wsi + io; io += NWORD;
    size_t deg_bytes = io * sizeof(int);
    int* rp_has     = wsi + io; io += NSPOT + 1;
    int* rp_desc    = wsi + io; io += NSPOT + 1;
    int* rp_in      = wsi + io; io += NCITY + 1;
    int* rp_rdesc   = wsi + io; io += NWORD + 1;
    int* cur_has    = wsi + io; io += NSPOT + 1;
    int* cur_desc   = wsi + io; io += NSPOT + 1;
    int* cur_in     = wsi + io; io += NCITY + 1;
    int* cur_rdesc  = wsi + io; io += NWORD + 1;
    int* cs_has     = wsi + io; io += E_has;
    int* cs_desc    = wsi + io; io += E_desc;
    int* cs_in      = wsi + io; io += E_in;
    int* cs_rdesc   = wsi + io; io += E_rdesc;
    (void)ws_size; (void)n_in; (void)out_size;

    // ---- weight transpose-casts + input casts ----
    {
        TDesc8 t{};
        for (int i = 0; i < 4; i++)
            t.d[i] = TDesc{ W_att + (size_t)i * 512 * 128, nullptr,
                            Wt_att + (size_t)i * 128 * 512, 512, 128, 512 };
        hipLaunchKernelGGL(transpose_cast_kernel, dim3(16, 4, 4), dim3(256), 0, stream, t);
    }
    {
        TDesc8 t{};
        t.d[0] = TDesc{ w1[0], nullptr, Wt1[0], 128, 256, 128 };
        t.d[1] = TDesc{ w1[1], w1[5],   Wt1[1], 512, 256, 512 };   // has_t + desc_t
        t.d[2] = TDesc{ w1[2], nullptr, Wt1[2], 512, 256, 512 };
        t.d[3] = TDesc{ w1[3], nullptr, Wt1[3], 128, 256, 128 };
        t.d[4] = TDesc{ w1[4], nullptr, Wt1[4], 300, 256, 320 };
        t.d[5] = TDesc{ w1[6], nullptr, Wt1[5], 512, 256, 512 };
        t.d[6] = TDesc{ w1[7], nullptr, Wt1[6], 300, 256, 320 };
        hipLaunchKernelGGL(transpose_cast_kernel, dim3(16, 8, 8), dim3(256), 0, stream, t);
    }
    {
        TDesc8 t{};
        t.d[0] = TDesc{ w2[0], nullptr, Wt2[0], 256, 256, 256 };
        t.d[1] = TDesc{ w2[1], w2[5],   Wt2[1], 256, 256, 256 };   // has_t + desc_t
        t.d[2] = TDesc{ w2[2], nullptr, Wt2[2], 256, 256, 256 };
        t.d[3] = TDesc{ w2[3], nullptr, Wt2[3], 256, 256, 256 };
        t.d[4] = TDesc{ w2[4], nullptr, Wt2[4], 256, 256, 256 };
        t.d[5] = TDesc{ w2[6], nullptr, Wt2[5], 256, 256, 256 };
        t.d[6] = TDesc{ w2[7], nullptr, Wt2[6], 256, 256, 256 };
        hipLaunchKernelGGL(transpose_cast_kernel, dim3(8, 8, 8), dim3(256), 0, stream, t);
    }
    hipLaunchKernelGGL(cast_kernel, dim3((NCITY * 128 + 255) / 256), dim3(256), 0, stream,
                       x_city, x_city_bf, NCITY * 128);
    hipLaunchKernelGGL(cast_pad_kernel, dim3((NWORD * 320 + 255) / 256), dim3(256), 0, stream,
                       x_word, x_word_bf, NWORD, 300, 320);

    // ---- fused CSR build (reused by both layers) ----
    EdgeDesc4 ed;
    ed.d[0] = EdgeDesc{ e_has_src,   e_has_tgt,   E_has,   NSPOT, deg_has,   rp_has,   cur_has,   cs_has };
    ed.d[1] = EdgeDesc{ e_desc_src,  e_desc_tgt,  E_desc,  NSPOT, deg_desc,  rp_desc,  cur_desc,  cs_desc };
    ed.d[2] = EdgeDesc{ e_in_src,    e_in_tgt,    E_in,    NCITY, deg_in,    rp_in,    cur_in,    cs_in };
    ed.d[3] = EdgeDesc{ e_rdesc_src, e_rdesc_tgt, E_rdesc, NWORD, deg_rdesc, rp_rdesc, cur_rdesc, cs_rdesc };
    int Emax = E_has;
    if (E_desc > Emax) Emax = E_desc;
    if (E_in > Emax) Emax = E_in;
    if (E_rdesc > Emax) Emax = E_rdesc;
    hipMemsetAsync((void*)deg_has, 0, deg_bytes, stream);
    hipLaunchKernelGGL(hist4_kernel, dim3((Emax + 255) / 256, 4), dim3(256), 0, stream, ed);
    hipLaunchKernelGGL(scan4_kernel, dim3(4), dim3(256), 0, stream, ed);
    hipLaunchKernelGGL(fill4_kernel, dim3((Emax + 255) / 256, 4), dim3(256), 0, stream, ed);

    // ---- attention ----
    hipLaunchKernelGGL(wq_kernel, dim3(8), dim3(256), 0, stream, W_att, q_att, wqb);
    hipLaunchKernelGGL(attn_kernel, dim3(NSPOT), dim3(256), 0, stream, x_spot, wqb, xbar_bf);

    int gx = (NSPOT + 127) / 128;   // 157

    // projection: 4 heads as a grouped GEMM (N=128)
    {
        GemmDesc8 gd{};
        for (int h = 0; h < 4; h++)
            gd.d[h] = GemmDesc{ xbar_bf + (size_t)h * NSPOT * 512, Wt_att + (size_t)h * 128 * 512,
                                nullptr, xs_bf + h * 128, 512, 512, 0, 512, NSPOT, 512, 128 };
        hipLaunchKernelGGL(gemm_grouped, dim3(gx, 1, 4), dim3(256), 0, stream, gd);
    }

    // ---- layer 1 GEMMs (one grouped launch, 7 groups) ----
    {
        GemmDesc8 gd{};
        gd.d[0] = GemmDesc{ x_city_bf, Wt1[0], nullptr, P_has_bf,   128, 128, 0, HID, NCITY, 128, HID };
        gd.d[1] = GemmDesc{ xs_bf,     Wt1[1], Ss,      nullptr,    512, 512, HID, 0, NSPOT, 512, HID };
        gd.d[2] = GemmDesc{ xs_bf,     Wt1[2], nullptr, P_in_bf,    512, 512, 0, HID, NSPOT, 512, HID };
        gd.d[3] = GemmDesc{ x_city_bf, Wt1[3], Sc,      nullptr,    128, 128, HID, 0, NCITY, 128, HID };
        gd.d[4] = GemmDesc{ x_word_bf, Wt1[4], nullptr, P_desc_bf,  320, 320, 0, HID, NWORD, 320, HID };
        gd.d[5] = GemmDesc{ xs_bf,     Wt1[5], nullptr, P_rdesc_bf, 512, 512, 0, HID, NSPOT, 512, HID };
        gd.d[6] = GemmDesc{ x_word_bf, Wt1[6], Sw,      nullptr,    320, 320, HID, 0, NWORD, 320, HID };
        gd.d[7].M = 0; gd.d[7].N = 0;
        hipLaunchKernelGGL(gemm_grouped, dim3(gx, 2, 8), dim3(256), 0, stream, gd);
    }

    // ---- layer 1 fused aggregation + combine ----
    int rows3 = NSPOT + NCITY + NWORD;
    hipLaunchKernelGGL(fused_ac1_kernel, dim3((rows3 + 3) / 4), dim3(256), 0, stream,
                       P_has_bf, rp_has, cs_has, P_desc_bf, rp_desc, cs_desc,
                       P_in_bf, rp_in, cs_in, P_rdesc_bf, rp_rdesc, cs_rdesc,
                       Ss, Sc, Sw, s1b, c1b, wd1b);

    // ---- layer 2 GEMMs (one grouped launch, 7 groups) ----
    {
        GemmDesc8 gd{};
        gd.d[0] = GemmDesc{ c1b,  Wt2[0], nullptr, P_has_bf,   HID, HID, 0, HID, NCITY, HID, HID };
        gd.d[1] = GemmDesc{ s1b,  Wt2[1], Ss,      nullptr,    HID, HID, HID, 0, NSPOT, HID, HID };
        gd.d[2] = GemmDesc{ s1b,  Wt2[2], nullptr, P_in_bf,    HID, HID, 0, HID, NSPOT, HID, HID };
        gd.d[3] = GemmDesc{ c1b,  Wt2[3], Sc,      nullptr,    HID, HID, HID, 0, NCITY, HID, HID };
        gd.d[4] = GemmDesc{ wd1b, Wt2[4], nullptr, P_desc_bf,  HID, HID, 0, HID, NWORD, HID, HID };
        gd.d[5] = GemmDesc{ s1b,  Wt2[5], nullptr, P_rdesc_bf, HID, HID, 0, HID, NSPOT, HID, HID };
        gd.d[6] = GemmDesc{ wd1b, Wt2[6], Sw,      nullptr,    HID, HID, HID, 0, NWORD, HID, HID };
        gd.d[7].M = 0; gd.d[7].N = 0;
        hipLaunchKernelGGL(gemm_grouped, dim3(gx, 2, 8), dim3(256), 0, stream, gd);
    }

    // ---- layer 2 fused aggregation + combine + mean + rowdot ----
    float* out0 = out;
    float* out1 = out + (size_t)NSPOT * HID;
    float* out2 = out1 + (size_t)NCITY * HID;
    float* out3 = out2 + (size_t)NWORD * HID;
    float* out4 = out3 + NSPOT;
    float* out5 = out4 + NCITY;
    hipLaunchKernelGGL(fused_finale_kernel, dim3((rows3 + 3) / 4), dim3(256), 0, stream,
                       P_has_bf, rp_has, cs_has, P_desc_bf, rp_desc, cs_desc,
                       P_in_bf, rp_in, cs_in, P_rdesc_bf, rp_rdesc, cs_rdesc,
                       Ss, Sc, Sw, s1b, c1b, wd1b,
                       out0, wl_spot, bl_spot, out3,
                       out1, wl_city, bl_city, out4,
                       out2, wl_word, bl_word, out5);
}

// Round 11
// 819.364 us; speedup vs baseline: 1.5527x; 1.0192x over previous
//
#include <hip/hip_runtime.h>
#include <hip/hip_bf16.h>

#define HID 256
#define NSPOT 20000
#define NCITY 2000
#define NWORD 20000

typedef __attribute__((ext_vector_type(8))) short bhalf8;
typedef __attribute__((ext_vector_type(4))) float floatx4;
typedef __attribute__((ext_vector_type(8))) unsigned short ushortx8;

__device__ inline float bf2f(unsigned short u) {
    union { unsigned int i; float f; } v; v.i = (unsigned int)u << 16; return v.f;
}
__device__ inline unsigned short f2bf(float f) {
    __hip_bfloat16 b = __float2bfloat16(f);
    return *reinterpret_cast<unsigned short*>(&b);
}
__device__ inline float4 ld4(const float* p, size_t off) {
    return *reinterpret_cast<const float4*>(p + off);
}

// ---------------------------------------------------------------------------
// wq[h][i] = sum_o W_att[h][i][o] * q_att[h][o]
__global__ void wq_kernel(const float* __restrict__ W, const float* __restrict__ q,
                          float* __restrict__ wq) {
    int idx = blockIdx.x * 256 + threadIdx.x;   // 4*512 = 2048
    if (idx >= 2048) return;
    int h = idx >> 9, i = idx & 511;
    const float* Wr = W + ((size_t)h * 512 + i) * 128;
    const float* qr = q + h * 128;
    float s = 0.f;
    #pragma unroll 4
    for (int o = 0; o < 128; o++) s += Wr[o] * qr[o];
    wq[idx] = s;
}

// ---------------------------------------------------------------------------
// Per-node attention: scores via wave-reduction, softmax, blend -> xbar bf16.
__global__ __launch_bounds__(256) void attn_kernel(const float* __restrict__ x,
                                                   const float* __restrict__ wq,
                                                   __hip_bfloat16* __restrict__ xbar) {
    __shared__ float xl[2560];
    __shared__ float al[4][8];
    int n = blockIdx.x;
    int tid = threadIdx.x;
    int wave = tid >> 6, lane = tid & 63;
    const float4* xr4 = (const float4*)(x + (size_t)n * 2560);
    for (int i = tid; i < 640; i += 256) ((float4*)xl)[i] = xr4[i];
    __syncthreads();
    const float* wqh = wq + wave * 512;
    for (int s = 0; s < 5; s++) {
        float a = 0.f;
        #pragma unroll
        for (int j = 0; j < 8; j++)
            a += xl[s * 512 + lane + j * 64] * wqh[lane + j * 64];
        #pragma unroll
        for (int off = 32; off > 0; off >>= 1) a += __shfl_down(a, off, 64);
        if (lane == 0) al[wave][s] = a;
    }
    __syncthreads();
    if (tid < 4) {
        float z[5]; float m = -1e30f;
        #pragma unroll
        for (int s = 0; s < 5; s++) {
            float v = al[tid][s];
            v = (v >= 0.f) ? v : 0.2f * v;    // leaky_relu 0.2
            z[s] = v; m = fmaxf(m, v);
        }
        float e[5]; float sum = 0.f;
        #pragma unroll
        for (int s = 0; s < 5; s++) { e[s] = __expf(z[s] - m); sum += e[s]; }
        float r = 1.f / sum;
        #pragma unroll
        for (int s = 0; s < 5; s++) al[tid][s] = e[s] * r;
    }
    __syncthreads();
    float a0 = al[wave][0], a1 = al[wave][1], a2 = al[wave][2], a3 = al[wave][3], a4 = al[wave][4];
    __hip_bfloat16* xo = xbar + ((size_t)wave * NSPOT + n) * 512;
    #pragma unroll
    for (int j = 0; j < 8; j++) {
        int i = lane + j * 64;
        float v = a0 * xl[i] + a1 * xl[512 + i] + a2 * xl[1024 + i] + a3 * xl[1536 + i] + a4 * xl[2048 + i];
        xo[i] = __float2bfloat16(v);
    }
}

// ---------------------------------------------------------------------------
// Grouped bf16 MFMA GEMM: per-group C[M,N] = A[M,K] @ Bt[N,K]^T, N in {128,256}.
// 128x128 tile, 4 waves (64x64 each as 4x4 of 16x16), K%32==0.  Reg-staged
// LDS KP=40 (80B stride: 2-way bank aliasing = free).  OOB A rows CLAMP to
// M-1: A-row r feeds only C-row r in MFMA, and C rows >= M are never stored.
// This keeps K-loop staging addressing k-invariant (no per-load predicate).
#define KP 40
struct GemmDesc {
    const __hip_bfloat16* A;
    const __hip_bfloat16* Bt;
    float* C;
    __hip_bfloat16* Cb;
    int lda, ldb, ldc, ldcb, M, K, N;
};
struct GemmDesc8 { GemmDesc d[8]; };

__global__ __launch_bounds__(256) void gemm_grouped(GemmDesc8 descs) {
    GemmDesc g = descs.d[blockIdx.z];
    int rowbase = blockIdx.x * 128;
    int colbase = blockIdx.y * 128;
    if (rowbase >= g.M || colbase >= g.N) return;   // block-uniform early-exit
    __shared__ short As[128 * KP];
    __shared__ short Bs[128 * KP];
    int tid = threadIdx.x;
    int wave = tid >> 6, lane = tid & 63;
    int wr = wave & 1, wc = wave >> 1;
    int quad = lane >> 4, l16 = lane & 15;
    int srow = tid >> 2;            // 0..63
    int skoff = (tid & 3) * 8;      // 0,8,16,24
    const __hip_bfloat16* A = g.A;
    const __hip_bfloat16* Bt = g.Bt;
    int lda = g.lda, ldb = g.ldb, M = g.M, K = g.K;

    // k-invariant staging row pointers (A rows clamped for the tail block)
    int r0 = srow, r1 = srow + 64;
    int gra0 = rowbase + r0; gra0 = gra0 < M ? gra0 : M - 1;
    int gra1 = rowbase + r1; gra1 = gra1 < M ? gra1 : M - 1;
    const __hip_bfloat16* Arow0 = A + (size_t)gra0 * lda + skoff;
    const __hip_bfloat16* Arow1 = A + (size_t)gra1 * lda + skoff;
    const __hip_bfloat16* Brow0 = Bt + (size_t)(colbase + r0) * ldb + skoff;
    const __hip_bfloat16* Brow1 = Bt + (size_t)(colbase + r1) * ldb + skoff;
    short* sA0 = As + r0 * KP + skoff;
    short* sA1 = As + r1 * KP + skoff;
    short* sB0 = Bs + r0 * KP + skoff;
    short* sB1 = Bs + r1 * KP + skoff;

    floatx4 acc[4][4];
    #pragma unroll
    for (int i = 0; i < 4; i++)
        #pragma unroll
        for (int j = 0; j < 4; j++)
            acc[i][j] = (floatx4){0.f, 0.f, 0.f, 0.f};

    for (int k0 = 0; k0 < K; k0 += 32) {
        *(int4*)sA0 = *(const int4*)(Arow0 + k0);
        *(int4*)sA1 = *(const int4*)(Arow1 + k0);
        *(int4*)sB0 = *(const int4*)(Brow0 + k0);
        *(int4*)sB1 = *(const int4*)(Brow1 + k0);
        __syncthreads();
        bhalf8 af[4], bfr[4];
        #pragma unroll
        for (int rt = 0; rt < 4; rt++)
            af[rt] = *(const bhalf8*)(As + (wr * 64 + rt * 16 + l16) * KP + quad * 8);
        #pragma unroll
        for (int ct = 0; ct < 4; ct++)
            bfr[ct] = *(const bhalf8*)(Bs + (wc * 64 + ct * 16 + l16) * KP + quad * 8);
        #pragma unroll
        for (int rt = 0; rt < 4; rt++)
            #pragma unroll
            for (int ct = 0; ct < 4; ct++)
                acc[rt][ct] = __builtin_amdgcn_mfma_f32_16x16x32_bf16(af[rt], bfr[ct], acc[rt][ct], 0, 0, 0);
        __syncthreads();
    }
    #pragma unroll
    for (int rt = 0; rt < 4; rt++) {
        #pragma unroll
        for (int r = 0; r < 4; r++) {
            int grow = rowbase + wr * 64 + rt * 16 + quad * 4 + r;
            if (grow < M) {
                #pragma unroll
                for (int ct = 0; ct < 4; ct++) {
                    int gcol = colbase + wc * 64 + ct * 16 + l16;
                    float v = acc[rt][ct][r];
                    if (g.C)  g.C[(size_t)grow * g.ldc + gcol] = v;
                    if (g.Cb) g.Cb[(size_t)grow * g.ldcb + gcol] = __float2bfloat16(v);
                }
            }
        }
    }
}

// ---------------------------------------------------------------------------
// Batched transpose-cast: in fp32 [K][N] (+optional in2, summed) -> bf16
// [N][Kp], zero-pad K..Kp.  All 18 weight transposes in ONE launch.
struct TDesc { const float* in; const float* in2; __hip_bfloat16* out; int K; int N; int Kp; };
struct TDesc18 { TDesc d[18]; };
__global__ void transpose_cast_kernel(TDesc18 descs) {
    TDesc dsc = descs.d[blockIdx.z];
    __shared__ float tile[32][33];
    int k0 = blockIdx.x * 32, n0 = blockIdx.y * 32;
    if (k0 >= dsc.Kp || n0 >= dsc.N) return;
    int tn = threadIdx.x & 31, t8 = threadIdx.x >> 5;
    #pragma unroll
    for (int i = 0; i < 4; i++) {
        int k = k0 + t8 * 4 + i;
        float v = 0.f;
        if (k < dsc.K && n0 + tn < dsc.N) {
            v = dsc.in[(size_t)k * dsc.N + n0 + tn];
            if (dsc.in2) v += dsc.in2[(size_t)k * dsc.N + n0 + tn];
        }
        tile[t8 * 4 + i][tn] = v;
    }
    __syncthreads();
    int kk = threadIdx.x & 31, n8 = threadIdx.x >> 5;
    #pragma unroll
    for (int i = 0; i < 4; i++) {
        int n = n0 + n8 * 4 + i;
        int k = k0 + kk;
        if (n < dsc.N && k < dsc.Kp)
            dsc.out[(size_t)n * dsc.Kp + k] = __float2bfloat16(tile[kk][n8 * 4 + i]);
    }
}

// cast fp32 -> bf16 (flat)
__global__ void cast_kernel(const float* __restrict__ in, __hip_bfloat16* __restrict__ out, int n) {
    int i = blockIdx.x * 256 + threadIdx.x;
    if (i < n) out[i] = __float2bfloat16(in[i]);
}

// cast fp32 [rows][K] -> bf16 [rows][Kp] zero-padded
__global__ void cast_pad_kernel(const float* __restrict__ in, __hip_bfloat16* __restrict__ out,
                                int rows, int K, int Kp) {
    int idx = blockIdx.x * 256 + threadIdx.x;
    if (idx >= rows * Kp) return;
    int r = idx / Kp, k = idx - r * Kp;
    out[idx] = (k < K) ? __float2bfloat16(in[(size_t)r * K + k]) : __float2bfloat16(0.f);
}

// ---------------------------------------------------------------------------
// Fused CSR build for all 4 edge types: histogram -> scan(+cursor) -> fill
struct EdgeDesc { const int* src; const int* tgt; int E; int n;
                  int* deg; int* rp; int* cur; int* cs; };
struct EdgeDesc4 { EdgeDesc d[4]; };

__global__ void hist4_kernel(EdgeDesc4 ds) {
    EdgeDesc d = ds.d[blockIdx.y];
    int e = blockIdx.x * 256 + threadIdx.x;
    if (e < d.E) atomicAdd(&d.deg[d.tgt[e]], 1);
}

__global__ void scan4_kernel(EdgeDesc4 ds) {
    EdgeDesc dd = ds.d[blockIdx.x];
    __shared__ int partx[257];
    __shared__ int part[256];
    int tid = threadIdx.x;
    int n = dd.n;
    int chunk = (n + 255) / 256;
    int lo = tid * chunk;
    int hi = lo + chunk; if (hi > n) hi = n;
    int s = 0;
    for (int i = lo; i < hi; i++) s += dd.deg[i];
    part[tid] = s;
    __syncthreads();
    if (tid == 0) {
        int acc = 0;
        for (int i = 0; i < 256; i++) { partx[i] = acc; acc += part[i]; }
        partx[256] = acc;
    }
    __syncthreads();
    int acc = partx[tid];
    for (int i = lo; i < hi; i++) { dd.rp[i] = acc; dd.cur[i] = acc; acc += dd.deg[i]; }
    if (tid == 0) dd.rp[n] = partx[256];
}

__global__ void fill4_kernel(EdgeDesc4 ds) {
    EdgeDesc d = ds.d[blockIdx.y];
    int e = blockIdx.x * 256 + threadIdx.x;
    if (e >= d.E) return;
    int t = d.tgt[e];
    int pos = atomicAdd(&d.cur[t], 1);
    d.cs[pos] = d.src[e];
}

// ---------------------------------------------------------------------------
// Segment mean, half-wave-per-edge (round-6/8 proven structure, 4-deep unroll):
// 32 lanes x ushort8 (16B) cover one 512B message row; half=0 takes even CSR
// slots, half=1 odd.  4 independent row loads in flight per half (8/wave).
// shfl_down(32) merges halves; lanes 0..31 hold the 8-dims/lane result.
__device__ inline void seg_mean8(const __hip_bfloat16* __restrict__ msg,
                                 const int* __restrict__ rp, const int* __restrict__ cs,
                                 int t, int half, int li, float a[8]) {
    int lo = rp[t], hi = rp[t + 1];
    #pragma unroll
    for (int j = 0; j < 8; j++) a[j] = 0.f;
    int col = li * 8;
    int i = lo + half;
    for (; i + 6 < hi; i += 8) {
        int s0 = cs[i], s1 = cs[i + 2], s2 = cs[i + 4], s3 = cs[i + 6];
        ushortx8 u0 = *(const ushortx8*)(msg + (size_t)s0 * HID + col);
        ushortx8 u1 = *(const ushortx8*)(msg + (size_t)s1 * HID + col);
        ushortx8 u2 = *(const ushortx8*)(msg + (size_t)s2 * HID + col);
        ushortx8 u3 = *(const ushortx8*)(msg + (size_t)s3 * HID + col);
        #pragma unroll
        for (int k = 0; k < 8; k++)
            a[k] += (bf2f(u0[k]) + bf2f(u1[k])) + (bf2f(u2[k]) + bf2f(u3[k]));
    }
    for (; i < hi; i += 2) {
        int s0 = cs[i];
        ushortx8 u = *(const ushortx8*)(msg + (size_t)s0 * HID + col);
        #pragma unroll
        for (int k = 0; k < 8; k++) a[k] += bf2f(u[k]);
    }
    #pragma unroll
    for (int j = 0; j < 8; j++) a[j] += __shfl_down(a[j], 32, 64);
    float inv = 1.f / fmaxf((float)(hi - lo), 1.f);
    #pragma unroll
    for (int j = 0; j < 8; j++) a[j] *= inv;
}

// ---------------------------------------------------------------------------
// Layer-1 fused: segment-mean gathers + combine + ReLU + bf16 store only.
__global__ __launch_bounds__(256) void fused_ac1_kernel(
    const __hip_bfloat16* __restrict__ Phas,   const int* __restrict__ rp_has,   const int* __restrict__ cs_has,
    const __hip_bfloat16* __restrict__ Pdesc,  const int* __restrict__ rp_desc,  const int* __restrict__ cs_desc,
    const __hip_bfloat16* __restrict__ Pin,    const int* __restrict__ rp_in,    const int* __restrict__ cs_in,
    const __hip_bfloat16* __restrict__ Prdesc, const int* __restrict__ rp_rdesc, const int* __restrict__ cs_rdesc,
    const float* __restrict__ Ss, const float* __restrict__ Sc, const float* __restrict__ Sw,
    __hip_bfloat16* __restrict__ s1b, __hip_bfloat16* __restrict__ c1b,
    __hip_bfloat16* __restrict__ wd1b) {
    int row = blockIdx.x * 4 + (threadIdx.x >> 6);
    if (row >= NSPOT + NCITY + NWORD) return;
    int lane = threadIdx.x & 63;
    int half = lane >> 5, li = lane & 31;
    float v[8]; __hip_bfloat16* ob; size_t off;
    if (row < NSPOT) {
        float mh[8], md[8];
        seg_mean8(Phas, rp_has, cs_has, row, half, li, mh);
        seg_mean8(Pdesc, rp_desc, cs_desc, row, half, li, md);
        off = (size_t)row * HID + li * 8;
        float4 sa = ld4(Ss, off), sb = ld4(Ss, off + 4);
        v[0] = fmaxf((sa.x + mh[0] + md[0]) * 0.5f, 0.f);
        v[1] = fmaxf((sa.y + mh[1] + md[1]) * 0.5f, 0.f);
        v[2] = fmaxf((sa.z + mh[2] + md[2]) * 0.5f, 0.f);
        v[3] = fmaxf((sa.w + mh[3] + md[3]) * 0.5f, 0.f);
        v[4] = fmaxf((sb.x + mh[4] + md[4]) * 0.5f, 0.f);
        v[5] = fmaxf((sb.y + mh[5] + md[5]) * 0.5f, 0.f);
        v[6] = fmaxf((sb.z + mh[6] + md[6]) * 0.5f, 0.f);
        v[7] = fmaxf((sb.w + mh[7] + md[7]) * 0.5f, 0.f);
        ob = s1b;
    } else if (row < NSPOT + NCITY) {
        int r = row - NSPOT;
        float mi[8];
        seg_mean8(Pin, rp_in, cs_in, r, half, li, mi);
        off = (size_t)r * HID + li * 8;
        float4 sa = ld4(Sc, off), sb = ld4(Sc, off + 4);
        v[0] = fmaxf(sa.x + mi[0], 0.f); v[1] = fmaxf(sa.y + mi[1], 0.f);
        v[2] = fmaxf(sa.z + mi[2], 0.f); v[3] = fmaxf(sa.w + mi[3], 0.f);
        v[4] = fmaxf(sb.x + mi[4], 0.f); v[5] = fmaxf(sb.y + mi[5], 0.f);
        v[6] = fmaxf(sb.z + mi[6], 0.f); v[7] = fmaxf(sb.w + mi[7], 0.f);
        ob = c1b;
    } else {
        int r = row - NSPOT - NCITY;
        float mr[8];
        seg_mean8(Prdesc, rp_rdesc, cs_rdesc, r, half, li, mr);
        off = (size_t)r * HID + li * 8;
        float4 sa = ld4(Sw, off), sb = ld4(Sw, off + 4);
        v[0] = fmaxf(sa.x + mr[0], 0.f); v[1] = fmaxf(sa.y + mr[1], 0.f);
        v[2] = fmaxf(sa.z + mr[2], 0.f); v[3] = fmaxf(sa.w + mr[3], 0.f);
        v[4] = fmaxf(sb.x + mr[4], 0.f); v[5] = fmaxf(sb.y + mr[5], 0.f);
        v[6] = fmaxf(sb.z + mr[6], 0.f); v[7] = fmaxf(sb.w + mr[7], 0.f);
        ob = wd1b;
    }
    if (half == 0) {
        ushortx8 ub;
        #pragma unroll
        for (int j = 0; j < 8; j++) ub[j] = f2bf(v[j]);
        *reinterpret_cast<ushortx8*>((unsigned short*)ob + off) = ub;
    }
}

// ---------------------------------------------------------------------------
// Layer-2 fused finale: gathers + combine + (l1+l2)/2 mean + rowdot head.
__global__ __launch_bounds__(256) void fused_finale_kernel(
    const __hip_bfloat16* __restrict__ Phas,   const int* __restrict__ rp_has,   const int* __restrict__ cs_has,
    const __hip_bfloat16* __restrict__ Pdesc,  const int* __restrict__ rp_desc,  const int* __restrict__ cs_desc,
    const __hip_bfloat16* __restrict__ Pin,    const int* __restrict__ rp_in,    const int* __restrict__ cs_in,
    const __hip_bfloat16* __restrict__ Prdesc, const int* __restrict__ rp_rdesc, const int* __restrict__ cs_rdesc,
    const float* __restrict__ Ss, const float* __restrict__ Sc, const float* __restrict__ Sw,
    const __hip_bfloat16* __restrict__ s1b, const __hip_bfloat16* __restrict__ c1b,
    const __hip_bfloat16* __restrict__ wd1b,
    float* __restrict__ out0, const float* __restrict__ wls, const float* __restrict__ bls, float* __restrict__ out3,
    float* __restrict__ out1, const float* __restrict__ wlc, const float* __restrict__ blc, float* __restrict__ out4,
    float* __restrict__ out2, const float* __restrict__ wlw, const float* __restrict__ blw, float* __restrict__ out5) {
    int row = blockIdx.x * 4 + (threadIdx.x >> 6);
    if (row >= NSPOT + NCITY + NWORD) return;
    int lane = threadIdx.x & 63;
    int half = lane >> 5, li = lane & 31;
    float v[8]; const __hip_bfloat16* pl; const float* wl; const float* bl;
    float* om; float* od;
    int r; size_t off;
    if (row < NSPOT) {
        r = row;
        float mh[8], md[8];
        seg_mean8(Phas, rp_has, cs_has, r, half, li, mh);
        seg_mean8(Pdesc, rp_desc, cs_desc, r, half, li, md);
        off = (size_t)r * HID + li * 8;
        float4 sa = ld4(Ss, off), sb = ld4(Ss, off + 4);
        v[0] = fmaxf((sa.x + mh[0] + md[0]) * 0.5f, 0.f);
        v[1] = fmaxf((sa.y + mh[1] + md[1]) * 0.5f, 0.f);
        v[2] = fmaxf((sa.z + mh[2] + md[2]) * 0.5f, 0.f);
        v[3] = fmaxf((sa.w + mh[3] + md[3]) * 0.5f, 0.f);
        v[4] = fmaxf((sb.x + mh[4] + md[4]) * 0.5f, 0.f);
        v[5] = fmaxf((sb.y + mh[5] + md[5]) * 0.5f, 0.f);
        v[6] = fmaxf((sb.z + mh[6] + md[6]) * 0.5f, 0.f);
        v[7] = fmaxf((sb.w + mh[7] + md[7]) * 0.5f, 0.f);
        pl = s1b; wl = wls; bl = bls; om = out0; od = out3;
    } else if (row < NSPOT + NCITY) {
        r = row - NSPOT;
        float mi[8];
        seg_mean8(Pin, rp_in, cs_in, r, half, li, mi);
        off = (size_t)r * HID + li * 8;
        float4 sa = ld4(Sc, off), sb = ld4(Sc, off + 4);
        v[0] = fmaxf(sa.x + mi[0], 0.f); v[1] = fmaxf(sa.y + mi[1], 0.f);
        v[2] = fmaxf(sa.z + mi[2], 0.f); v[3] = fmaxf(sa.w + mi[3], 0.f);
        v[4] = fmaxf(sb.x + mi[4], 0.f); v[5] = fmaxf(sb.y + mi[5], 0.f);
        v[6] = fmaxf(sb.z + mi[6], 0.f); v[7] = fmaxf(sb.w + mi[7], 0.f);
        pl = c1b; wl = wlc; bl = blc; om = out1; od = out4;
    } else {
        r = row - NSPOT - NCITY;
        float mr[8];
        seg_mean8(Prdesc, rp_rdesc, cs_rdesc, r, half, li, mr);
        off = (size_t)r * HID + li * 8;
        float4 sa = ld4(Sw, off), sb = ld4(Sw, off + 4);
        v[0] = fmaxf(sa.x + mr[0], 0.f); v[1] = fmaxf(sa.y + mr[1], 0.f);
        v[2] = fmaxf(sa.z + mr[2], 0.f); v[3] = fmaxf(sa.w + mr[3], 0.f);
        v[4] = fmaxf(sb.x + mr[4], 0.f); v[5] = fmaxf(sb.y + mr[5], 0.f);
        v[6] = fmaxf(sb.z + mr[6], 0.f); v[7] = fmaxf(sb.w + mr[7], 0.f);
        pl = wd1b; wl = wlw; bl = blw; om = out2; od = out5;
    }
    // mean with layer-1 output (bf16 source); stores on lanes 0..31 only
    ushortx8 up = *(const ushortx8*)((const unsigned short*)pl + off);
    if (half == 0) {
        *reinterpret_cast<float4*>(om + off) =
            make_float4((bf2f(up[0]) + v[0]) * 0.5f, (bf2f(up[1]) + v[1]) * 0.5f,
                        (bf2f(up[2]) + v[2]) * 0.5f, (bf2f(up[3]) + v[3]) * 0.5f);
        *reinterpret_cast<float4*>(om + off + 4) =
            make_float4((bf2f(up[4]) + v[4]) * 0.5f, (bf2f(up[5]) + v[5]) * 0.5f,
                        (bf2f(up[6]) + v[6]) * 0.5f, (bf2f(up[7]) + v[7]) * 0.5f);
    }
    // rowdot over 256 dims held 8-per-lane on lanes 0..31
    float4 wa = *reinterpret_cast<const float4*>(wl + li * 8);
    float4 wb = *reinterpret_cast<const float4*>(wl + li * 8 + 4);
    float s = v[0] * wa.x + v[1] * wa.y + v[2] * wa.z + v[3] * wa.w
            + v[4] * wb.x + v[5] * wb.y + v[6] * wb.z + v[7] * wb.w;
    s += __shfl_down(s, 16, 64);
    s += __shfl_down(s, 8, 64);
    s += __shfl_down(s, 4, 64);
    s += __shfl_down(s, 2, 64);
    s += __shfl_down(s, 1, 64);
    if (lane == 0) od[r] = s + bl[0];
}

// ---------------------------------------------------------------------------
extern "C" void kernel_launch(void* const* d_in, const int* in_sizes, int n_in,
                              void* d_out, int out_size, void* d_ws, size_t ws_size,
                              hipStream_t stream) {
    const float* x_spot   = (const float*)d_in[0];
    const float* x_city   = (const float*)d_in[1];
    const float* x_word   = (const float*)d_in[2];
    const float* W_att    = (const float*)d_in[3];
    const float* q_att    = (const float*)d_in[4];
    const float* w1[8] = { (const float*)d_in[5], (const float*)d_in[6], (const float*)d_in[7],
                           (const float*)d_in[8], (const float*)d_in[9], (const float*)d_in[10],
                           (const float*)d_in[11], (const float*)d_in[12] };
    const float* w2[8] = { (const float*)d_in[13], (const float*)d_in[14], (const float*)d_in[15],
                           (const float*)d_in[16], (const float*)d_in[17], (const float*)d_in[18],
                           (const float*)d_in[19], (const float*)d_in[20] };
    const float* wl_spot = (const float*)d_in[21];
    const float* wl_city = (const float*)d_in[22];
    const float* wl_word = (const float*)d_in[23];
    const float* bl_spot = (const float*)d_in[24];
    const float* bl_city = (const float*)d_in[25];
    const float* bl_word = (const float*)d_in[26];
    const int* e_has_src   = (const int*)d_in[27];
    const int* e_has_tgt   = (const int*)d_in[28];
    const int* e_in_src    = (const int*)d_in[29];
    const int* e_in_tgt    = (const int*)d_in[30];
    const int* e_desc_src  = (const int*)d_in[31];
    const int* e_desc_tgt  = (const int*)d_in[32];
    const int* e_rdesc_src = (const int*)d_in[33];
    const int* e_rdesc_tgt = (const int*)d_in[34];
    const int E_has   = in_sizes[27];
    const int E_in    = in_sizes[29];
    const int E_desc  = in_sizes[31];
    const int E_rdesc = in_sizes[33];

    float* out = (float*)d_out;
    float* wsf = (float*)d_ws;
    typedef __hip_bfloat16 bf;

    // ---- workspace layout (units of float; bf16 arrays use half) ----
    size_t o = 0;
    auto alloc = [&](size_t nfloats) { float* p = wsf + o; o += (nfloats + 15) & ~(size_t)15; return p; };
    float* wqb       = alloc(2048);
    bf* xs_bf        = (bf*)alloc((size_t)NSPOT * 512 / 2);
    bf* x_city_bf    = (bf*)alloc((size_t)NCITY * 128 / 2);
    bf* x_word_bf    = (bf*)alloc((size_t)NWORD * 320 / 2);
    bf* Wt_att       = (bf*)alloc((size_t)4 * 128 * 512 / 2);
    // L1 transposed weights [N=256][Kp]: 0:has_s 1:SUM(has_t+desc_t) 2:in_s
    // 3:in_t 4:desc_s 5:rdesc_s 6:rdesc_t
    int Kp1[7] = {128, 512, 512, 128, 320, 512, 320};
    bf* Wt1[7];
    for (int i = 0; i < 7; i++) Wt1[i] = (bf*)alloc((size_t)256 * Kp1[i] / 2);
    bf* Wt2[7];
    for (int i = 0; i < 7; i++) Wt2[i] = (bf*)alloc((size_t)256 * 256 / 2);
    float* Ss = alloc((size_t)NSPOT * HID);        // merged has_t+desc_t self term
    float* Sc = alloc((size_t)NCITY * HID);
    float* Sw = alloc((size_t)NWORD * HID);
    // P_has / P_desc must NOT alias xbar: they are written in the same launch
    // that reads xbar (GEMM launch A).  Dedicated workspace.
    bf* P_has_bf  = (bf*)alloc((size_t)NCITY * HID / 2);
    bf* P_desc_bf = (bf*)alloc((size_t)NWORD * HID / 2);
    // region X: xbar (dead after GEMM launch A) hosts P_in/P_rdesc + bf16 trio
    // (all written in LATER launches; stream order makes this safe)
    size_t regX = o;
    bf* xbar_bf = (bf*)(wsf + regX);                         // 4*NSPOT*512 bf16
    size_t ox = regX;
    auto allocX = [&](size_t nfloats) { float* p = wsf + ox; ox += (nfloats + 15) & ~(size_t)15; return p; };
    bf* P_in_bf    = (bf*)allocX((size_t)NSPOT * HID / 2);
    bf* P_rdesc_bf = (bf*)allocX((size_t)NSPOT * HID / 2);
    bf* s1b = (bf*)allocX((size_t)NSPOT * HID / 2);
    bf* c1b = (bf*)allocX((size_t)NCITY * HID / 2);
    bf* wd1b = (bf*)allocX((size_t)NWORD * HID / 2);
    o = regX + (size_t)4 * NSPOT * 512 / 2;                  // past xbar end
    // CSR ints
    int* wsi = (int*)(wsf + o);
    size_t io = 0;
    int* deg_has    = wsi + io; io += NSPOT;
    int* deg_desc   = wsi + io; io += NSPOT;
    int* deg_in     = wsi + io; io += NCITY;
    int* deg_rdesc  = wsi + io; io += NWORD;
    size_t deg_bytes = io * sizeof(int);
    int* rp_has     = wsi + io; io += NSPOT + 1;
    int* rp_desc    = wsi + io; io += NSPOT + 1;
    int* rp_in      = wsi + io; io += NCITY + 1;
    int* rp_rdesc   = wsi + io; io += NWORD + 1;
    int* cur_has    = wsi + io; io += NSPOT + 1;
    int* cur_desc   = wsi + io; io += NSPOT + 1;
    int* cur_in     = wsi + io; io += NCITY + 1;
    int* cur_rdesc  = wsi + io; io += NWORD + 1;
    int* cs_has     = wsi + io; io += E_has;
    int* cs_desc    = wsi + io; io += E_desc;
    int* cs_in      = wsi + io; io += E_in;
    int* cs_rdesc   = wsi + io; io += E_rdesc;
    (void)ws_size; (void)n_in; (void)out_size;

    // ---- all weight transpose-casts in one launch ----
    {
        TDesc18 t{};
        for (int i = 0; i < 4; i++)
            t.d[i] = TDesc{ W_att + (size_t)i * 512 * 128, nullptr,
                            Wt_att + (size_t)i * 128 * 512, 512, 128, 512 };
        t.d[4]  = TDesc{ w1[0], nullptr, Wt1[0], 128, 256, 128 };
        t.d[5]  = TDesc{ w1[1], w1[5],   Wt1[1], 512, 256, 512 };   // has_t + desc_t
        t.d[6]  = TDesc{ w1[2], nullptr, Wt1[2], 512, 256, 512 };
        t.d[7]  = TDesc{ w1[3], nullptr, Wt1[3], 128, 256, 128 };
        t.d[8]  = TDesc{ w1[4], nullptr, Wt1[4], 300, 256, 320 };
        t.d[9]  = TDesc{ w1[6], nullptr, Wt1[5], 512, 256, 512 };
        t.d[10] = TDesc{ w1[7], nullptr, Wt1[6], 300, 256, 320 };
        t.d[11] = TDesc{ w2[0], nullptr, Wt2[0], 256, 256, 256 };
        t.d[12] = TDesc{ w2[1], w2[5],   Wt2[1], 256, 256, 256 };   // has_t + desc_t
        t.d[13] = TDesc{ w2[2], nullptr, Wt2[2], 256, 256, 256 };
        t.d[14] = TDesc{ w2[3], nullptr, Wt2[3], 256, 256, 256 };
        t.d[15] = TDesc{ w2[4], nullptr, Wt2[4], 256, 256, 256 };
        t.d[16] = TDesc{ w2[6], nullptr, Wt2[5], 256, 256, 256 };
        t.d[17] = TDesc{ w2[7], nullptr, Wt2[6], 256, 256, 256 };
        hipLaunchKernelGGL(transpose_cast_kernel, dim3(16, 8, 18), dim3(256), 0, stream, t);
    }
    hipLaunchKernelGGL(cast_kernel, dim3((NCITY * 128 + 255) / 256), dim3(256), 0, stream,
                       x_city, x_city_bf, NCITY * 128);
    hipLaunchKernelGGL(cast_pad_kernel, dim3((NWORD * 320 + 255) / 256), dim3(256), 0, stream,
                       x_word, x_word_bf, NWORD, 300, 320);

    // ---- fused CSR build (reused by both layers) ----
    EdgeDesc4 ed;
    ed.d[0] = EdgeDesc{ e_has_src,   e_has_tgt,   E_has,   NSPOT, deg_has,   rp_has,   cur_has,   cs_has };
    ed.d[1] = EdgeDesc{ e_desc_src,  e_desc_tgt,  E_desc,  NSPOT, deg_desc,  rp_desc,  cur_desc,  cs_desc };
    ed.d[2] = EdgeDesc{ e_in_src,    e_in_tgt,    E_in,    NCITY, deg_in,    rp_in,    cur_in,    cs_in };
    ed.d[3] = EdgeDesc{ e_rdesc_src, e_rdesc_tgt, E_rdesc, NWORD, deg_rdesc, rp_rdesc, cur_rdesc, cs_rdesc };
    int Emax = E_has;
    if (E_desc > Emax) Emax = E_desc;
    if (E_in > Emax) Emax = E_in;
    if (E_rdesc > Emax) Emax = E_rdesc;
    hipMemsetAsync((void*)deg_has, 0, deg_bytes, stream);
    hipLaunchKernelGGL(hist4_kernel, dim3((Emax + 255) / 256, 4), dim3(256), 0, stream, ed);
    hipLaunchKernelGGL(scan4_kernel, dim3(4), dim3(256), 0, stream, ed);
    hipLaunchKernelGGL(fill4_kernel, dim3((Emax + 255) / 256, 4), dim3(256), 0, stream, ed);

    // ---- attention ----
    hipLaunchKernelGGL(wq_kernel, dim3(8), dim3(256), 0, stream, W_att, q_att, wqb);
    hipLaunchKernelGGL(attn_kernel, dim3(NSPOT), dim3(256), 0, stream, x_spot, wqb, xbar_bf);

    int gx = (NSPOT + 127) / 128;   // 157

    // ---- GEMM launch A: attention projection (reads xbar) + the L1 groups
    // that do NOT depend on xs (city, word).  P_has/P_desc are outside the
    // xbar-aliased region, so intra-launch concurrency is safe. ----
    {
        GemmDesc8 gd{};
        for (int h = 0; h < 4; h++)
            gd.d[h] = GemmDesc{ xbar_bf + (size_t)h * NSPOT * 512, Wt_att + (size_t)h * 128 * 512,
                                nullptr, xs_bf + h * 128, 512, 512, 0, 512, NSPOT, 512, 128 };
        gd.d[4] = GemmDesc{ x_city_bf, Wt1[0], nullptr, P_has_bf,  128, 128, 0, HID, NCITY, 128, HID };
        gd.d[5] = GemmDesc{ x_city_bf, Wt1[3], Sc,      nullptr,   128, 128, HID, 0, NCITY, 128, HID };
        gd.d[6] = GemmDesc{ x_word_bf, Wt1[4], nullptr, P_desc_bf, 320, 320, 0, HID, NWORD, 320, HID };
        gd.d[7] = GemmDesc{ x_word_bf, Wt1[6], Sw,      nullptr,   320, 320, HID, 0, NWORD, 320, HID };
        hipLaunchKernelGGL(gemm_grouped, dim3(gx, 2, 8), dim3(256), 0, stream, gd);
    }

    // ---- GEMM launch B: the 3 xs-dependent spot groups (xbar now dead;
    // P_in/P_rdesc may reuse its memory — stream order guarantees safety) ----
    {
        GemmDesc8 gd{};
        gd.d[0] = GemmDesc{ xs_bf, Wt1[1], Ss,      nullptr,    512, 512, HID, 0, NSPOT, 512, HID };
        gd.d[1] = GemmDesc{ xs_bf, Wt1[2], nullptr, P_in_bf,    512, 512, 0, HID, NSPOT, 512, HID };
        gd.d[2] = GemmDesc{ xs_bf, Wt1[5], nullptr, P_rdesc_bf, 512, 512, 0, HID, NSPOT, 512, HID };
        for (int i = 3; i < 8; i++) { gd.d[i].M = 0; gd.d[i].N = 0; }
        hipLaunchKernelGGL(gemm_grouped, dim3(gx, 2, 3), dim3(256), 0, stream, gd);
    }

    // ---- layer 1 fused aggregation + combine ----
    int rows3 = NSPOT + NCITY + NWORD;
    hipLaunchKernelGGL(fused_ac1_kernel, dim3((rows3 + 3) / 4), dim3(256), 0, stream,
                       P_has_bf, rp_has, cs_has, P_desc_bf, rp_desc, cs_desc,
                       P_in_bf, rp_in, cs_in, P_rdesc_bf, rp_rdesc, cs_rdesc,
                       Ss, Sc, Sw, s1b, c1b, wd1b);

    // ---- layer 2 GEMMs (one grouped launch, 7 groups) ----
    {
        GemmDesc8 gd{};
        gd.d[0] = GemmDesc{ c1b,  Wt2[0], nullptr, P_has_bf,   HID, HID, 0, HID, NCITY, HID, HID };
        gd.d[1] = GemmDesc{ s1b,  Wt2[1], Ss,      nullptr,    HID, HID, HID, 0, NSPOT, HID, HID };
        gd.d[2] = GemmDesc{ s1b,  Wt2[2], nullptr, P_in_bf,    HID, HID, 0, HID, NSPOT, HID, HID };
        gd.d[3] = GemmDesc{ c1b,  Wt2[3], Sc,      nullptr,    HID, HID, HID, 0, NCITY, HID, HID };
        gd.d[4] = GemmDesc{ wd1b, Wt2[4], nullptr, P_desc_bf,  HID, HID, 0, HID, NWORD, HID, HID };
        gd.d[5] = GemmDesc{ s1b,  Wt2[5], nullptr, P_rdesc_bf, HID, HID, 0, HID, NSPOT, HID, HID };
        gd.d[6] = GemmDesc{ wd1b, Wt2[6], Sw,      nullptr,    HID, HID, HID, 0, NWORD, HID, HID };
        gd.d[7].M = 0; gd.d[7].N = 0;
        hipLaunchKernelGGL(gemm_grouped, dim3(gx, 2, 8), dim3(256), 0, stream, gd);
    }

    // ---- layer 2 fused aggregation + combine + mean + rowdot ----
    float* out0 = out;
    float* out1 = out + (size_t)NSPOT * HID;
    float* out2 = out1 + (size_t)NCITY * HID;
    float* out3 = out2 + (size_t)NWORD * HID;
    float* out4 = out3 + NSPOT;
    float* out5 = out4 + NCITY;
    hipLaunchKernelGGL(fused_finale_kernel, dim3((rows3 + 3) / 4), dim3(256), 0, stream,
                       P_has_bf, rp_has, cs_has, P_desc_bf, rp_desc, cs_desc,
                       P_in_bf, rp_in, cs_in, P_rdesc_bf, rp_rdesc, cs_rdesc,
                       Ss, Sc, Sw, s1b, c1b, wd1b,
                       out0, wl_spot, bl_spot, out3,
                       out1, wl_city, bl_city, out4,
                       out2, wl_word, bl_word, out5);
}